// Round 1
// baseline (3452.116 us; speedup 1.0000x reference)
//
#include <hip/hip_runtime.h>
#include <math.h>

#define BATCH 64
#define NPG 1024
#define NT (BATCH*NPG)        // 65536 nodes
#define EPER 32768
#define ETOT (BATCH*EPER)     // 2097152 edges
#define IND 128
#define HIDDIM 128
#define KC 64

__device__ __forceinline__ float lky(float x){ return x > 0.f ? x : 0.01f*x; }

// ---------------- CSR build ----------------
__global__ void k_count(const int* __restrict__ src, const int* __restrict__ dst,
                        int* cnt_d, int* cnt_s){
    int e = blockIdx.x*256 + threadIdx.x;
    if (e < ETOT){
        atomicAdd(&cnt_d[dst[e]], 1);
        atomicAdd(&cnt_s[src[e]], 1);
    }
}

__global__ void k_scan(const int* __restrict__ cnt, int* __restrict__ indptr){
    __shared__ int buf[1024];
    int tid = threadIdx.x;
    int carry = 0;
    for (int base = 0; base < NT; base += 1024){
        int v = cnt[base + tid];
        int x = v;
        buf[tid] = x; __syncthreads();
        for (int off = 1; off < 1024; off <<= 1){
            int t = (tid >= off) ? buf[tid - off] : 0;
            __syncthreads();
            x += t; buf[tid] = x; __syncthreads();
        }
        indptr[base + tid] = carry + x - v;
        int tot = buf[1023];
        __syncthreads();
        carry += tot;
    }
    if (tid == 0) indptr[NT] = carry;
}

__global__ void k_fill(const int* __restrict__ src, const int* __restrict__ dst,
                       const int* __restrict__ ipd, const int* __restrict__ ips,
                       int* cur_d, int* cur_s, int* lst_d, int* lst_s){
    int e = blockIdx.x*256 + threadIdx.x;
    if (e < ETOT){
        int s = src[e], d = dst[e];
        int p = atomicAdd(&cur_d[d], 1); lst_d[ipd[d] + p] = s;
        int q = atomicAdd(&cur_s[s], 1); lst_s[ips[s] + q] = d;
    }
}

// ---------------- segment gather-sum (per node), dim = blockDim ----------------
__global__ void k_agg(const float* __restrict__ X, const int* __restrict__ indptr,
                      const int* __restrict__ lst, float* __restrict__ out,
                      int dim, int do_mean){
    int n = blockIdx.x, t = threadIdx.x;
    int st = indptr[n], en = indptr[n+1];
    float acc = 0.f;
    for (int e = st; e < en; e++) acc += X[(size_t)lst[e]*dim + t];
    if (do_mean){ int dg = en - st; acc /= (float)(dg > 1 ? dg : 1); }
    out[(size_t)n*dim + t] = acc;
}

// ---------------- fused dual GEMM: C = act(A1@W1 [+ A2@W2] + bias) ----------------
// 64x64 tile, 256 threads, 4x4 micro-tile, K-step 16
__global__ void __launch_bounds__(256) k_gemm(
        const float* __restrict__ A1, const float* __restrict__ A2,
        const float* __restrict__ W1, const float* __restrict__ W2,
        const float* __restrict__ bias, float* __restrict__ C,
        int M, int Nn, int Kd, int dual, int act){
    __shared__ float sA1[16*68], sB1[16*68], sA2[16*68], sB2[16*68];
    int tid = threadIdx.x;
    int m0 = blockIdx.x*64, n0 = blockIdx.y*64;
    int tx = tid & 15, ty = tid >> 4;
    int lr = tid >> 2, lk = (tid & 3)*4;     // A tile load: row lr, k-offset lk
    int wk = tid >> 4, wn = (tid & 15)*4;    // W tile load: k-row wk, n-offset wn
    float acc[4][4] = {};
    for (int k0 = 0; k0 < Kd; k0 += 16){
        float4 a1 = *(const float4*)&A1[(size_t)(m0+lr)*Kd + k0 + lk];
        float4 w1 = *(const float4*)&W1[(size_t)(k0+wk)*Nn + n0 + wn];
        sA1[(lk+0)*68+lr] = a1.x; sA1[(lk+1)*68+lr] = a1.y;
        sA1[(lk+2)*68+lr] = a1.z; sA1[(lk+3)*68+lr] = a1.w;
        *(float4*)&sB1[wk*68+wn] = w1;
        if (dual){
            float4 a2 = *(const float4*)&A2[(size_t)(m0+lr)*Kd + k0 + lk];
            float4 w2 = *(const float4*)&W2[(size_t)(k0+wk)*Nn + n0 + wn];
            sA2[(lk+0)*68+lr] = a2.x; sA2[(lk+1)*68+lr] = a2.y;
            sA2[(lk+2)*68+lr] = a2.z; sA2[(lk+3)*68+lr] = a2.w;
            *(float4*)&sB2[wk*68+wn] = w2;
        }
        __syncthreads();
        #pragma unroll
        for (int kk = 0; kk < 16; kk++){
            float4 av = *(const float4*)&sA1[kk*68 + ty*4];
            float4 bv = *(const float4*)&sB1[kk*68 + tx*4];
            float a[4] = {av.x, av.y, av.z, av.w};
            float b[4] = {bv.x, bv.y, bv.z, bv.w};
            #pragma unroll
            for (int i = 0; i < 4; i++)
                #pragma unroll
                for (int j = 0; j < 4; j++) acc[i][j] += a[i]*b[j];
            if (dual){
                float4 av2 = *(const float4*)&sA2[kk*68 + ty*4];
                float4 bv2 = *(const float4*)&sB2[kk*68 + tx*4];
                float a2[4] = {av2.x, av2.y, av2.z, av2.w};
                float b2[4] = {bv2.x, bv2.y, bv2.z, bv2.w};
                #pragma unroll
                for (int i = 0; i < 4; i++)
                    #pragma unroll
                    for (int j = 0; j < 4; j++) acc[i][j] += a2[i]*b2[j];
            }
        }
        __syncthreads();
    }
    float bb[4];
    #pragma unroll
    for (int j = 0; j < 4; j++) bb[j] = bias[n0 + tx*4 + j];
    #pragma unroll
    for (int i = 0; i < 4; i++){
        float4 o;
        float v0 = acc[i][0]+bb[0], v1 = acc[i][1]+bb[1], v2 = acc[i][2]+bb[2], v3 = acc[i][3]+bb[3];
        if (act){ v0 = lky(v0); v1 = lky(v1); v2 = lky(v2); v3 = lky(v3); }
        o.x = v0; o.y = v1; o.z = v2; o.w = v3;
        *(float4*)&C[(size_t)(m0 + ty*4 + i)*Nn + n0 + tx*4] = o;
    }
}

// ---------------- softmax over K=64 per row + entropy accumulation ----------------
__global__ void k_softmax_ent(float* __restrict__ S, float* __restrict__ ent_acc){
    int tid = threadIdx.x;
    int row = blockIdx.x*4 + (tid >> 6);
    int lane = tid & 63;
    float v = S[(size_t)row*64 + lane];
    float m = v;
    for (int o = 32; o; o >>= 1) m = fmaxf(m, __shfl_xor(m, o));
    float e = __expf(v - m);
    float sm = e;
    for (int o = 32; o; o >>= 1) sm += __shfl_xor(sm, o);
    float p = e / sm;
    S[(size_t)row*64 + lane] = p;
    float w = -p*__logf(p + 1e-15f);
    for (int o = 32; o; o >>= 1) w += __shfl_xor(w, o);
    __shared__ float red[4];
    if (lane == 0) red[tid >> 6] = w;
    __syncthreads();
    if (tid == 0) atomicAdd(ent_acc, red[0]+red[1]+red[2]+red[3]);
}

// ---------------- pooled[b] = s[b]^T z[b]  (64x128, inner 1024), 4-way n-split ----------------
__global__ void k_pooled(const float* __restrict__ S, const float* __restrict__ Z,
                         float* __restrict__ P){
    __shared__ float sS[8*64], sZ[8*128];
    int b = blockIdx.x >> 2, part = blockIdx.x & 3;
    int tid = threadIdx.x;
    int kk = (tid & 31)*2, fg = tid >> 5;
    float acc[2][16] = {};
    int nbase = b*NPG + part*256;
    for (int n0 = 0; n0 < 256; n0 += 8){
        for (int i = tid; i < 512; i += 256){ int r = i >> 6, c = i & 63; sS[i] = S[(size_t)(nbase+n0+r)*64 + c]; }
        for (int i = tid; i < 1024; i += 256){ int r = i >> 7, c = i & 127; sZ[i] = Z[(size_t)(nbase+n0+r)*128 + c]; }
        __syncthreads();
        for (int nn = 0; nn < 8; nn++){
            float a0 = sS[nn*64+kk], a1 = sS[nn*64+kk+1];
            #pragma unroll
            for (int j = 0; j < 16; j++){
                float zz = sZ[nn*128 + fg*16 + j];
                acc[0][j] += a0*zz; acc[1][j] += a1*zz;
            }
        }
        __syncthreads();
    }
    for (int c = 0; c < 2; c++)
        for (int j = 0; j < 16; j++)
            atomicAdd(&P[((size_t)b*64 + kk + c)*128 + fg*16 + j], acc[c][j]);
}

// ---------------- adjp[b] = s[b]^T t[b]  (64x64), 4-way n-split ----------------
__global__ void k_adjp(const float* __restrict__ S, const float* __restrict__ T,
                       float* __restrict__ AP){
    __shared__ float sS[8*64], sT[8*64];
    int b = blockIdx.x >> 2, part = blockIdx.x & 3;
    int tid = threadIdx.x;
    int kk = (tid & 31)*2, lg = tid >> 5;
    float acc[2][8] = {};
    int nbase = b*NPG + part*256;
    for (int n0 = 0; n0 < 256; n0 += 8){
        for (int i = tid; i < 512; i += 256){
            int r = i >> 6, c = i & 63;
            sS[i] = S[(size_t)(nbase+n0+r)*64 + c];
            sT[i] = T[(size_t)(nbase+n0+r)*64 + c];
        }
        __syncthreads();
        for (int nn = 0; nn < 8; nn++){
            float a0 = sS[nn*64+kk], a1 = sS[nn*64+kk+1];
            #pragma unroll
            for (int j = 0; j < 8; j++){
                float tt = sT[nn*64 + lg*8 + j];
                acc[0][j] += a0*tt; acc[1][j] += a1*tt;
            }
        }
        __syncthreads();
    }
    for (int c = 0; c < 2; c++)
        for (int j = 0; j < 8; j++)
            atomicAdd(&AP[((size_t)b*64 + kk + c)*64 + lg*8 + j], acc[c][j]);
}

// ---------------- ||s^T s||_F^2 accumulated over graphs ----------------
__global__ void k_normG(const float* __restrict__ S, float* __restrict__ acc_out){
    __shared__ float sS[8*64];
    __shared__ float red[256];
    int b = blockIdx.x, tid = threadIdx.x;
    int kk = (tid & 31)*2, lg = tid >> 5;
    float acc[2][8] = {};
    for (int n0 = 0; n0 < NPG; n0 += 8){
        for (int i = tid; i < 512; i += 256){ int r = i >> 6, c = i & 63; sS[i] = S[(size_t)(b*NPG+n0+r)*64 + c]; }
        __syncthreads();
        for (int nn = 0; nn < 8; nn++){
            float a0 = sS[nn*64+kk], a1 = sS[nn*64+kk+1];
            #pragma unroll
            for (int j = 0; j < 8; j++){
                float tt = sS[nn*64 + lg*8 + j];
                acc[0][j] += a0*tt; acc[1][j] += a1*tt;
            }
        }
        __syncthreads();
    }
    float ss = 0.f;
    for (int c = 0; c < 2; c++) for (int j = 0; j < 8; j++) ss += acc[c][j]*acc[c][j];
    red[tid] = ss; __syncthreads();
    for (int o = 128; o; o >>= 1){ if (tid < o) red[tid] += red[tid+o]; __syncthreads(); }
    if (tid == 0) atomicAdd(acc_out, red[0]);
}

// ---------------- sum_e dot(s[src], s[dst]) ----------------
__global__ void k_cross(const int* __restrict__ src, const int* __restrict__ dst,
                        const float* __restrict__ S, float* __restrict__ acc_out){
    int tid = threadIdx.x;
    int lane = tid & 63;
    int wid = (blockIdx.x*256 + tid) >> 6;
    int nw = gridDim.x*4;
    float local = 0.f;
    for (int e = wid; e < ETOT; e += nw){
        int s = src[e], d = dst[e];
        local += S[(size_t)s*64 + lane]*S[(size_t)d*64 + lane];
    }
    for (int o = 32; o; o >>= 1) local += __shfl_xor(local, o);
    __shared__ float red[4];
    if (lane == 0) red[tid >> 6] = local;
    __syncthreads();
    if (tid == 0) atomicAdd(acc_out, red[0]+red[1]+red[2]+red[3]);
}

// ---------------- sum(a^2) via per-graph LDS bitonic sort of (src,dst) keys ----------------
__global__ void __launch_bounds__(1024) k_a2(const int* __restrict__ src, const int* __restrict__ dst,
                                             unsigned int* __restrict__ acc_out){
    __shared__ unsigned int keys[32768];   // 128 KB
    __shared__ unsigned int red[1024];
    int b = blockIdx.x, tid = threadIdx.x;
    int base = b*EPER;
    for (int i = tid; i < EPER; i += 1024){
        unsigned sl = (unsigned)src[base+i] & 1023u;
        unsigned dl = (unsigned)dst[base+i] & 1023u;
        keys[i] = (sl << 10) | dl;
    }
    __syncthreads();
    for (unsigned k = 2; k <= 32768u; k <<= 1){
        for (unsigned j = k >> 1; j > 0; j >>= 1){
            for (unsigned i = tid; i < 32768u; i += 1024){
                unsigned ixj = i ^ j;
                if (ixj > i){
                    unsigned a = keys[i], c = keys[ixj];
                    bool up = ((i & k) == 0);
                    if (up ? (a > c) : (a < c)){ keys[i] = c; keys[ixj] = a; }
                }
            }
            __syncthreads();
        }
    }
    unsigned local = 0;
    for (int i = tid; i < EPER; i += 1024){
        unsigned key = keys[i]; unsigned r = 0; int j = i;
        while (j > 0 && keys[j-1] == key){ r++; j--; }
        local += 2u*r + 1u;   // sum over cells of c^2 == sum over entries of (2*rank+1)
    }
    red[tid] = local; __syncthreads();
    for (int o = 512; o; o >>= 1){ if (tid < o) red[tid] += red[tid+o]; __syncthreads(); }
    if (tid == 0) atomicAdd(acc_out, red[0]);
}

// ---------------- dense SAGE + classifier head, one block per graph ----------------
__global__ void __launch_bounds__(256) k_head(
        const float* __restrict__ AP, const float* __restrict__ P,
        const float* __restrict__ Wrel, const float* __restrict__ Wroot,
        const float* __restrict__ broot, const float* __restrict__ Wc1,
        const float* __restrict__ bc1, const float* __restrict__ Wc2,
        const float* __restrict__ bc2, float* __restrict__ out){
    __shared__ float smem[37312];
    float* sadj  = smem;            // 4096
    float* spool = smem + 4096;     // 8192
    float* saggv = smem + 12288;    // 8192
    float* sw    = smem + 20480;    // 8192 (Wrel chunk | Wroot chunk)
    float* sh    = smem + 28672;    // 8192
    float* srs   = smem + 36864;    // 64
    float* shc   = smem + 36928;    // 128
    float* sred  = smem + 37056;    // 256
    int b = blockIdx.x, tid = threadIdx.x;
    for (int i = tid; i < 4096; i += 256) sadj[i] = AP[(size_t)b*4096 + i];
    for (int i = tid; i < 8192; i += 256) spool[i] = P[(size_t)b*8192 + i];
    __syncthreads();
    if (tid < 64){
        float s = 0.f;
        for (int l = 0; l < 64; l++) s += sadj[tid*64 + l];
        srs[tid] = fmaxf(s, 1.f);
    }
    __syncthreads();
    int k = tid >> 2, f0 = (tid & 3)*32;
    {   // agg = (adjp @ pooled) / rowsum
        float acc[32] = {};
        for (int l = 0; l < 64; l++){
            float a = sadj[k*64 + l];
            #pragma unroll
            for (int j = 0; j < 32; j++) acc[j] += a*spool[l*128 + f0 + j];
        }
        float inv = 1.f/srs[k];
        for (int j = 0; j < 32; j++) saggv[k*128 + f0 + j] = acc[j]*inv;
    }
    __syncthreads();
    {   // h = leaky(agg@Wrel + pooled@Wroot + broot)
        float acc[32] = {};
        for (int c = 0; c < 4; c++){
            for (int i = tid; i < 4096; i += 256){
                sw[i]        = Wrel[c*4096 + i];
                sw[4096 + i] = Wroot[c*4096 + i];
            }
            __syncthreads();
            for (int g = 0; g < 32; g++){
                float a = saggv[k*128 + c*32 + g];
                float p = spool[k*128 + c*32 + g];
                #pragma unroll
                for (int j = 0; j < 32; j++)
                    acc[j] += a*sw[g*128 + f0 + j] + p*sw[4096 + g*128 + f0 + j];
            }
            __syncthreads();
        }
        for (int j = 0; j < 32; j++) sh[k*128 + f0 + j] = lky(acc[j] + broot[f0 + j]);
    }
    __syncthreads();
    {   // hc = leaky(h_flat @ Wc1 + bc1)
        int j = tid & 127, half = tid >> 7;
        float acc = 0.f;
        for (int i = half*4096; i < half*4096 + 4096; i++)
            acc += sh[i]*Wc1[(size_t)i*128 + j];
        sred[tid] = acc; __syncthreads();
        if (tid < 128) shc[tid] = lky(sred[tid] + sred[tid+128] + bc1[tid]);
        __syncthreads();
    }
    if (tid < 64){
        float p = shc[tid]*Wc2[tid] + shc[tid+64]*Wc2[tid+64];
        for (int o = 32; o; o >>= 1) p += __shfl_xor(p, o);
        if (tid == 0) out[b] = p + bc2[0];
    }
}

__global__ void k_finalize(const unsigned int* __restrict__ a2,
                           const float* __restrict__ cross,
                           const float* __restrict__ normg,
                           const float* __restrict__ ent,
                           float* __restrict__ out){
    float ss = (float)(*a2) - 2.f*(*cross) + (*normg);
    if (ss < 0.f) ss = 0.f;
    float link = sqrtf(ss) / 67108864.f;     // a.size = 64*1024*1024
    out[64] = link + (*ent)/(float)NT;
}

extern "C" void kernel_launch(void* const* d_in, const int* in_sizes, int n_in,
                              void* d_out, int out_size, void* d_ws, size_t ws_size,
                              hipStream_t stream){
    const float* x    = (const float*)d_in[0];
    const int*   ei   = (const int*)d_in[1];
    const int*   src  = ei;
    const int*   dst  = ei + ETOT;
    const float* W1l  = (const float*)d_in[5];
    const float* b1l  = (const float*)d_in[6];
    const float* W1r  = (const float*)d_in[7];
    const float* W2l  = (const float*)d_in[8];
    const float* b2l  = (const float*)d_in[9];
    const float* W2r  = (const float*)d_in[10];
    const float* Wm   = (const float*)d_in[11];
    const float* bm   = (const float*)d_in[12];
    const float* Wrel = (const float*)d_in[13];
    const float* Wroot= (const float*)d_in[14];
    const float* broot= (const float*)d_in[15];
    const float* Wc1  = (const float*)d_in[16];
    const float* bc1  = (const float*)d_in[17];
    const float* Wc2  = (const float*)d_in[18];
    const float* bc2  = (const float*)d_in[19];
    float* out = (float*)d_out;

    char* w = (char*)d_ws;
    size_t off = 0;
    auto take = [&](size_t bytes)->void*{
        void* p = w + off; off = (off + bytes + 255) & ~(size_t)255; return p;
    };
    // --- zeroed zone (one memset) ---
    int*   cnt_d  = (int*)take((size_t)NT*4);
    int*   cnt_s  = (int*)take((size_t)NT*4);
    int*   cur_d  = (int*)take((size_t)NT*4);
    int*   cur_s  = (int*)take((size_t)NT*4);
    float* pooled = (float*)take((size_t)BATCH*64*128*4);
    float* adjp   = (float*)take((size_t)BATCH*64*64*4);
    float* accb   = (float*)take(64);
    size_t zero_bytes = off;
    // --- non-zeroed ---
    int*   ipd   = (int*)take((size_t)(NT+1)*4);
    int*   ips   = (int*)take((size_t)(NT+1)*4);
    int*   lst_d = (int*)take((size_t)ETOT*4);
    int*   lst_s = (int*)take((size_t)ETOT*4);
    float* agg   = (float*)take((size_t)NT*128*4);   // reused as s2 later
    float* zb    = (float*)take((size_t)NT*128*4);
    float* spre  = (float*)take((size_t)NT*64*4);    // reused as t later
    float* s2    = agg;
    float* tbuf  = spre;

    float* crossp = accb + 0;
    float* normgp = accb + 1;
    float* entp   = accb + 2;
    unsigned int* a2p = (unsigned int*)(accb + 3);

    hipMemsetAsync(d_ws, 0, zero_bytes, stream);

    k_count<<<ETOT/256, 256, 0, stream>>>(src, dst, cnt_d, cnt_s);
    k_scan<<<1, 1024, 0, stream>>>(cnt_d, ipd);
    k_scan<<<1, 1024, 0, stream>>>(cnt_s, ips);
    k_fill<<<ETOT/256, 256, 0, stream>>>(src, dst, ipd, ips, cur_d, cur_s, lst_d, lst_s);

    // SAGE layer 1: z = leaky(mean_agg(x)@W1l + b1l + x@W1r)
    k_agg<<<NT, 128, 0, stream>>>(x, ipd, lst_d, agg, 128, 1);
    k_gemm<<<dim3(NT/64, 2), 256, 0, stream>>>(agg, x, W1l, W1r, b1l, zb, NT, 128, 128, 1, 1);

    // SAGE layer 2 + Wm: s2 = (leaky(mean_agg(z)@W2l + b2l + z@W2r))@Wm + bm
    k_agg<<<NT, 128, 0, stream>>>(zb, ipd, lst_d, agg, 128, 1);
    k_gemm<<<dim3(NT/64, 1), 256, 0, stream>>>(agg, zb, W2l, W2r, b2l, spre, NT, 64, 128, 1, 1);
    k_gemm<<<dim3(NT/64, 1), 256, 0, stream>>>(spre, nullptr, Wm, nullptr, bm, s2, NT, 64, 64, 0, 0);

    // softmax + entropy
    k_softmax_ent<<<NT/4, 256, 0, stream>>>(s2, entp);

    // t = A @ s  (sum of s[dst] over out-edges)
    k_agg<<<NT, 64, 0, stream>>>(s2, ips, lst_s, tbuf, 64, 0);

    // pooled, adj_p, loss pieces
    k_pooled<<<BATCH*4, 256, 0, stream>>>(s2, zb, pooled);
    k_adjp<<<BATCH*4, 256, 0, stream>>>(s2, tbuf, adjp);
    k_normG<<<BATCH, 256, 0, stream>>>(s2, normgp);
    k_cross<<<2048, 256, 0, stream>>>(src, dst, s2, crossp);
    k_a2<<<BATCH, 1024, 0, stream>>>(src, dst, a2p);

    // head + finalize
    k_head<<<BATCH, 256, 0, stream>>>(adjp, pooled, Wrel, Wroot, broot, Wc1, bc1, Wc2, bc2, out);
    k_finalize<<<1, 1, 0, stream>>>(a2p, crossp, normgp, entp, out);
}

// Round 2
// 2391.622 us; speedup vs baseline: 1.4434x; 1.4434x over previous
//
#include <hip/hip_runtime.h>
#include <math.h>

#define BATCH 64
#define NPG 1024
#define NT (BATCH*NPG)        // 65536 nodes
#define EPER 32768
#define ETOT (BATCH*EPER)     // 2097152 edges
#define IND 128
#define HIDDIM 128
#define KC 64

__device__ __forceinline__ float lky(float x){ return x > 0.f ? x : 0.01f*x; }

// ---------------- CSR build ----------------
__global__ void k_count(const int* __restrict__ src, const int* __restrict__ dst,
                        int* cnt_d, int* cnt_s){
    int e = blockIdx.x*256 + threadIdx.x;
    if (e < ETOT){
        atomicAdd(&cnt_d[dst[e]], 1);
        atomicAdd(&cnt_s[src[e]], 1);
    }
}

__global__ void k_scan(const int* __restrict__ cnt, int* __restrict__ indptr){
    __shared__ int buf[1024];
    int tid = threadIdx.x;
    int carry = 0;
    for (int base = 0; base < NT; base += 1024){
        int v = cnt[base + tid];
        int x = v;
        buf[tid] = x; __syncthreads();
        for (int off = 1; off < 1024; off <<= 1){
            int t = (tid >= off) ? buf[tid - off] : 0;
            __syncthreads();
            x += t; buf[tid] = x; __syncthreads();
        }
        indptr[base + tid] = carry + x - v;
        int tot = buf[1023];
        __syncthreads();
        carry += tot;
    }
    if (tid == 0) indptr[NT] = carry;
}

__global__ void k_fill(const int* __restrict__ src, const int* __restrict__ dst,
                       const int* __restrict__ ipd, const int* __restrict__ ips,
                       int* cur_d, int* cur_s, int* lst_d, int* lst_s){
    int e = blockIdx.x*256 + threadIdx.x;
    if (e < ETOT){
        int s = src[e], d = dst[e];
        int p = atomicAdd(&cur_d[d], 1); lst_d[ipd[d] + p] = s;
        int q = atomicAdd(&cur_s[s], 1); lst_s[ips[s] + q] = d;
    }
}

// ---------------- segment gather-sum (per node), dim = blockDim ----------------
__global__ void k_agg(const float* __restrict__ X, const int* __restrict__ indptr,
                      const int* __restrict__ lst, float* __restrict__ out,
                      int dim, int do_mean){
    int n = blockIdx.x, t = threadIdx.x;
    int st = indptr[n], en = indptr[n+1];
    float acc = 0.f;
    for (int e = st; e < en; e++) acc += X[(size_t)lst[e]*dim + t];
    if (do_mean){ int dg = en - st; acc /= (float)(dg > 1 ? dg : 1); }
    out[(size_t)n*dim + t] = acc;
}

// ---------------- fused dual GEMM: C = act(A1@W1 [+ A2@W2] + bias) ----------------
__global__ void __launch_bounds__(256) k_gemm(
        const float* __restrict__ A1, const float* __restrict__ A2,
        const float* __restrict__ W1, const float* __restrict__ W2,
        const float* __restrict__ bias, float* __restrict__ C,
        int M, int Nn, int Kd, int dual, int act){
    __shared__ float sA1[16*68], sB1[16*68], sA2[16*68], sB2[16*68];
    int tid = threadIdx.x;
    int m0 = blockIdx.x*64, n0 = blockIdx.y*64;
    int tx = tid & 15, ty = tid >> 4;
    int lr = tid >> 2, lk = (tid & 3)*4;
    int wk = tid >> 4, wn = (tid & 15)*4;
    float acc[4][4] = {};
    for (int k0 = 0; k0 < Kd; k0 += 16){
        float4 a1 = *(const float4*)&A1[(size_t)(m0+lr)*Kd + k0 + lk];
        float4 w1 = *(const float4*)&W1[(size_t)(k0+wk)*Nn + n0 + wn];
        sA1[(lk+0)*68+lr] = a1.x; sA1[(lk+1)*68+lr] = a1.y;
        sA1[(lk+2)*68+lr] = a1.z; sA1[(lk+3)*68+lr] = a1.w;
        *(float4*)&sB1[wk*68+wn] = w1;
        if (dual){
            float4 a2 = *(const float4*)&A2[(size_t)(m0+lr)*Kd + k0 + lk];
            float4 w2 = *(const float4*)&W2[(size_t)(k0+wk)*Nn + n0 + wn];
            sA2[(lk+0)*68+lr] = a2.x; sA2[(lk+1)*68+lr] = a2.y;
            sA2[(lk+2)*68+lr] = a2.z; sA2[(lk+3)*68+lr] = a2.w;
            *(float4*)&sB2[wk*68+wn] = w2;
        }
        __syncthreads();
        #pragma unroll
        for (int kk = 0; kk < 16; kk++){
            float4 av = *(const float4*)&sA1[kk*68 + ty*4];
            float4 bv = *(const float4*)&sB1[kk*68 + tx*4];
            float a[4] = {av.x, av.y, av.z, av.w};
            float b[4] = {bv.x, bv.y, bv.z, bv.w};
            #pragma unroll
            for (int i = 0; i < 4; i++)
                #pragma unroll
                for (int j = 0; j < 4; j++) acc[i][j] += a[i]*b[j];
            if (dual){
                float4 av2 = *(const float4*)&sA2[kk*68 + ty*4];
                float4 bv2 = *(const float4*)&sB2[kk*68 + tx*4];
                float a2[4] = {av2.x, av2.y, av2.z, av2.w};
                float b2[4] = {bv2.x, bv2.y, bv2.z, bv2.w};
                #pragma unroll
                for (int i = 0; i < 4; i++)
                    #pragma unroll
                    for (int j = 0; j < 4; j++) acc[i][j] += a2[i]*b2[j];
            }
        }
        __syncthreads();
    }
    float bb[4];
    #pragma unroll
    for (int j = 0; j < 4; j++) bb[j] = bias[n0 + tx*4 + j];
    #pragma unroll
    for (int i = 0; i < 4; i++){
        float4 o;
        float v0 = acc[i][0]+bb[0], v1 = acc[i][1]+bb[1], v2 = acc[i][2]+bb[2], v3 = acc[i][3]+bb[3];
        if (act){ v0 = lky(v0); v1 = lky(v1); v2 = lky(v2); v3 = lky(v3); }
        o.x = v0; o.y = v1; o.z = v2; o.w = v3;
        *(float4*)&C[(size_t)(m0 + ty*4 + i)*Nn + n0 + tx*4] = o;
    }
}

// ---------------- softmax over K=64 per row + entropy accumulation ----------------
__global__ void k_softmax_ent(float* __restrict__ S, float* __restrict__ ent_acc){
    int tid = threadIdx.x;
    int row = blockIdx.x*4 + (tid >> 6);
    int lane = tid & 63;
    float v = S[(size_t)row*64 + lane];
    float m = v;
    for (int o = 32; o; o >>= 1) m = fmaxf(m, __shfl_xor(m, o));
    float e = __expf(v - m);
    float sm = e;
    for (int o = 32; o; o >>= 1) sm += __shfl_xor(sm, o);
    float p = e / sm;
    S[(size_t)row*64 + lane] = p;
    float w = -p*__logf(p + 1e-15f);
    for (int o = 32; o; o >>= 1) w += __shfl_xor(w, o);
    __shared__ float red[4];
    if (lane == 0) red[tid >> 6] = w;
    __syncthreads();
    if (tid == 0) atomicAdd(ent_acc, red[0]+red[1]+red[2]+red[3]);
}

// ---------------- pooled[b] = s[b]^T z[b], 4-way n-split ----------------
__global__ void k_pooled(const float* __restrict__ S, const float* __restrict__ Z,
                         float* __restrict__ P){
    __shared__ float sS[8*64], sZ[8*128];
    int b = blockIdx.x >> 2, part = blockIdx.x & 3;
    int tid = threadIdx.x;
    int kk = (tid & 31)*2, fg = tid >> 5;
    float acc[2][16] = {};
    int nbase = b*NPG + part*256;
    for (int n0 = 0; n0 < 256; n0 += 8){
        for (int i = tid; i < 512; i += 256){ int r = i >> 6, c = i & 63; sS[i] = S[(size_t)(nbase+n0+r)*64 + c]; }
        for (int i = tid; i < 1024; i += 256){ int r = i >> 7, c = i & 127; sZ[i] = Z[(size_t)(nbase+n0+r)*128 + c]; }
        __syncthreads();
        for (int nn = 0; nn < 8; nn++){
            float a0 = sS[nn*64+kk], a1 = sS[nn*64+kk+1];
            #pragma unroll
            for (int j = 0; j < 16; j++){
                float zz = sZ[nn*128 + fg*16 + j];
                acc[0][j] += a0*zz; acc[1][j] += a1*zz;
            }
        }
        __syncthreads();
    }
    for (int c = 0; c < 2; c++)
        for (int j = 0; j < 16; j++)
            atomicAdd(&P[((size_t)b*64 + kk + c)*128 + fg*16 + j], acc[c][j]);
}

// ---------------- adjp[b] = s[b]^T t[b], 4-way n-split ----------------
__global__ void k_adjp(const float* __restrict__ S, const float* __restrict__ T,
                       float* __restrict__ AP){
    __shared__ float sS[8*64], sT[8*64];
    int b = blockIdx.x >> 2, part = blockIdx.x & 3;
    int tid = threadIdx.x;
    int kk = (tid & 31)*2, lg = tid >> 5;
    float acc[2][8] = {};
    int nbase = b*NPG + part*256;
    for (int n0 = 0; n0 < 256; n0 += 8){
        for (int i = tid; i < 512; i += 256){
            int r = i >> 6, c = i & 63;
            sS[i] = S[(size_t)(nbase+n0+r)*64 + c];
            sT[i] = T[(size_t)(nbase+n0+r)*64 + c];
        }
        __syncthreads();
        for (int nn = 0; nn < 8; nn++){
            float a0 = sS[nn*64+kk], a1 = sS[nn*64+kk+1];
            #pragma unroll
            for (int j = 0; j < 8; j++){
                float tt = sT[nn*64 + lg*8 + j];
                acc[0][j] += a0*tt; acc[1][j] += a1*tt;
            }
        }
        __syncthreads();
    }
    for (int c = 0; c < 2; c++)
        for (int j = 0; j < 8; j++)
            atomicAdd(&AP[((size_t)b*64 + kk + c)*64 + lg*8 + j], acc[c][j]);
}

// ---------------- ||s^T s||_F^2 accumulated over graphs ----------------
__global__ void k_normG(const float* __restrict__ S, float* __restrict__ acc_out){
    __shared__ float sS[8*64];
    __shared__ float red[256];
    int b = blockIdx.x, tid = threadIdx.x;
    int kk = (tid & 31)*2, lg = tid >> 5;
    float acc[2][8] = {};
    for (int n0 = 0; n0 < NPG; n0 += 8){
        for (int i = tid; i < 512; i += 256){ int r = i >> 6, c = i & 63; sS[i] = S[(size_t)(b*NPG+n0+r)*64 + c]; }
        __syncthreads();
        for (int nn = 0; nn < 8; nn++){
            float a0 = sS[nn*64+kk], a1 = sS[nn*64+kk+1];
            #pragma unroll
            for (int j = 0; j < 8; j++){
                float tt = sS[nn*64 + lg*8 + j];
                acc[0][j] += a0*tt; acc[1][j] += a1*tt;
            }
        }
        __syncthreads();
    }
    float ss = 0.f;
    for (int c = 0; c < 2; c++) for (int j = 0; j < 8; j++) ss += acc[c][j]*acc[c][j];
    red[tid] = ss; __syncthreads();
    for (int o = 128; o; o >>= 1){ if (tid < o) red[tid] += red[tid+o]; __syncthreads(); }
    if (tid == 0) atomicAdd(acc_out, red[0]);
}

// ---------------- cross = sum_n dot(s[n], t[n])  (replaces per-edge gather) ----------------
__global__ void k_dot(const float* __restrict__ A, const float* __restrict__ B,
                      float* __restrict__ acc_out){
    int tid = threadIdx.x;
    size_t i = (size_t)blockIdx.x*256 + tid;
    size_t stride = (size_t)gridDim.x*256;
    float local = 0.f;
    for (; i < (size_t)NT*16; i += stride){   // float4 granules: NT*64/4
        float4 a = ((const float4*)A)[i];
        float4 b = ((const float4*)B)[i];
        local += a.x*b.x + a.y*b.y + a.z*b.z + a.w*b.w;
    }
    for (int o = 32; o; o >>= 1) local += __shfl_xor(local, o);
    __shared__ float red[4];
    if ((tid & 63) == 0) red[tid >> 6] = local;
    __syncthreads();
    if (tid == 0) atomicAdd(acc_out, red[0]+red[1]+red[2]+red[3]);
}

// ---------------- sum(a^2) via per-graph LDS bitonic sort of (src,dst) keys ----------------
__global__ void __launch_bounds__(1024) k_a2(const int* __restrict__ src, const int* __restrict__ dst,
                                             unsigned int* __restrict__ acc_out){
    __shared__ unsigned int keys[32768];   // 128 KB
    __shared__ unsigned int red[1024];
    int b = blockIdx.x, tid = threadIdx.x;
    int base = b*EPER;
    for (int i = tid; i < EPER; i += 1024){
        unsigned sl = (unsigned)src[base+i] & 1023u;
        unsigned dl = (unsigned)dst[base+i] & 1023u;
        keys[i] = (sl << 10) | dl;
    }
    __syncthreads();
    for (unsigned k = 2; k <= 32768u; k <<= 1){
        for (unsigned j = k >> 1; j > 0; j >>= 1){
            for (unsigned i = tid; i < 32768u; i += 1024){
                unsigned ixj = i ^ j;
                if (ixj > i){
                    unsigned a = keys[i], c = keys[ixj];
                    bool up = ((i & k) == 0);
                    if (up ? (a > c) : (a < c)){ keys[i] = c; keys[ixj] = a; }
                }
            }
            __syncthreads();
        }
    }
    unsigned local = 0;
    for (int i = tid; i < EPER; i += 1024){
        unsigned key = keys[i]; unsigned r = 0; int j = i;
        while (j > 0 && keys[j-1] == key){ r++; j--; }
        local += 2u*r + 1u;
    }
    red[tid] = local; __syncthreads();
    for (int o = 512; o; o >>= 1){ if (tid < o) red[tid] += red[tid+o]; __syncthreads(); }
    if (tid == 0) atomicAdd(acc_out, red[0]);
}

// ---------------- head stage 1: per-graph agg + h (64x128), write h to global ----------------
__global__ void __launch_bounds__(256) k_head1(
        const float* __restrict__ AP, const float* __restrict__ P,
        const float* __restrict__ Wrel, const float* __restrict__ Wroot,
        const float* __restrict__ broot, float* __restrict__ hbuf){
    __shared__ float spool[64*130];   // stride 130 kills same-bank row reads
    __shared__ float sagg[64*130];
    __shared__ float srs[64];
    int b = blockIdx.x, tid = threadIdx.x;
    for (int i = tid; i < 8192; i += 256){
        int r = i >> 7, c = i & 127;
        spool[r*130 + c] = P[(size_t)b*8192 + i];
    }
    if (tid < 64){
        float s = 0.f;
        const float* ap = AP + (size_t)b*4096 + tid*64;
        for (int l = 0; l < 64; l++) s += ap[l];
        srs[tid] = fmaxf(s, 1.f);
    }
    __syncthreads();
    int k = tid >> 2, c0 = (tid & 3)*32;
    // agg[k, c0..c0+31] = (adjp[k,:] @ pooled[:, c0..]) / rowsum
    {
        float acc[32] = {};
        const float* ap = AP + (size_t)b*4096 + k*64;
        for (int l = 0; l < 64; l++){
            float a = ap[l];
            #pragma unroll
            for (int jj = 0; jj < 32; jj++) acc[jj] += a*spool[l*130 + c0 + jj];
        }
        float inv = 1.f/srs[k];
        #pragma unroll
        for (int jj = 0; jj < 32; jj++) sagg[k*130 + c0 + jj] = acc[jj]*inv;
    }
    __syncthreads();
    // h[k, c0..] = leaky(agg[k,:]@Wrel[:,c0..] + pooled[k,:]@Wroot[:,c0..] + broot)
    {
        float acc[32] = {};
        for (int g = 0; g < 128; g++){
            float a = sagg[k*130 + g];
            float p = spool[k*130 + g];
            const float4* wr = (const float4*)&Wrel[(size_t)g*128 + c0];
            const float4* wo = (const float4*)&Wroot[(size_t)g*128 + c0];
            #pragma unroll
            for (int q = 0; q < 8; q++){
                float4 r4 = wr[q], o4 = wo[q];
                acc[q*4+0] += a*r4.x + p*o4.x;
                acc[q*4+1] += a*r4.y + p*o4.y;
                acc[q*4+2] += a*r4.z + p*o4.z;
                acc[q*4+3] += a*r4.w + p*o4.w;
            }
        }
        #pragma unroll
        for (int jj = 0; jj < 32; jj++)
            hbuf[(size_t)b*8192 + k*128 + c0 + jj] = lky(acc[jj] + broot[c0 + jj]);
    }
}

// ---------------- head stage 2: hcacc[b,:] += h[b, chunk] @ Wc1[chunk, :] ----------------
__global__ void __launch_bounds__(256) k_head2(
        const float* __restrict__ hbuf, const float* __restrict__ Wc1,
        float* __restrict__ hcacc){
    __shared__ float sh[512];
    __shared__ float sred[256];
    int b = blockIdx.x >> 4, ch = blockIdx.x & 15;
    int tid = threadIdx.x;
    for (int i = tid; i < 512; i += 256) sh[i] = hbuf[(size_t)b*8192 + ch*512 + i];
    __syncthreads();
    int j = tid & 127, half = tid >> 7;
    float acc = 0.f;
    const float* W = Wc1 + (size_t)(ch*512 + half*256)*128;
    const float* hh = sh + half*256;
    for (int r = 0; r < 256; r++) acc += hh[r]*W[(size_t)r*128 + j];
    sred[tid] = acc; __syncthreads();
    if (tid < 128) atomicAdd(&hcacc[(size_t)b*128 + tid], sred[tid] + sred[tid+128]);
}

// ---------------- head stage 3: logits ----------------
__global__ void k_head3(const float* __restrict__ hcacc, const float* __restrict__ bc1,
                        const float* __restrict__ Wc2, const float* __restrict__ bc2,
                        float* __restrict__ out){
    int b = blockIdx.x, t = threadIdx.x;   // 128 threads
    float hc = lky(hcacc[(size_t)b*128 + t] + bc1[t]);
    float p = hc*Wc2[t];
    for (int o = 32; o; o >>= 1) p += __shfl_xor(p, o);
    __shared__ float r2[2];
    if ((t & 63) == 0) r2[t >> 6] = p;
    __syncthreads();
    if (t == 0) out[b] = r2[0] + r2[1] + bc2[0];
}

__global__ void k_finalize(const unsigned int* __restrict__ a2,
                           const float* __restrict__ cross,
                           const float* __restrict__ normg,
                           const float* __restrict__ ent,
                           float* __restrict__ out){
    float ss = (float)(*a2) - 2.f*(*cross) + (*normg);
    if (ss < 0.f) ss = 0.f;
    float link = sqrtf(ss) / 67108864.f;     // a.size = 64*1024*1024
    out[64] = link + (*ent)/(float)NT;
}

extern "C" void kernel_launch(void* const* d_in, const int* in_sizes, int n_in,
                              void* d_out, int out_size, void* d_ws, size_t ws_size,
                              hipStream_t stream){
    const float* x    = (const float*)d_in[0];
    const int*   ei   = (const int*)d_in[1];
    const int*   src  = ei;
    const int*   dst  = ei + ETOT;
    const float* W1l  = (const float*)d_in[5];
    const float* b1l  = (const float*)d_in[6];
    const float* W1r  = (const float*)d_in[7];
    const float* W2l  = (const float*)d_in[8];
    const float* b2l  = (const float*)d_in[9];
    const float* W2r  = (const float*)d_in[10];
    const float* Wm   = (const float*)d_in[11];
    const float* bm   = (const float*)d_in[12];
    const float* Wrel = (const float*)d_in[13];
    const float* Wroot= (const float*)d_in[14];
    const float* broot= (const float*)d_in[15];
    const float* Wc1  = (const float*)d_in[16];
    const float* bc1  = (const float*)d_in[17];
    const float* Wc2  = (const float*)d_in[18];
    const float* bc2  = (const float*)d_in[19];
    float* out = (float*)d_out;

    char* w = (char*)d_ws;
    size_t off = 0;
    auto take = [&](size_t bytes)->void*{
        void* p = w + off; off = (off + bytes + 255) & ~(size_t)255; return p;
    };
    // --- zeroed zone (one memset) ---
    int*   cnt_d  = (int*)take((size_t)NT*4);
    int*   cnt_s  = (int*)take((size_t)NT*4);
    int*   cur_d  = (int*)take((size_t)NT*4);
    int*   cur_s  = (int*)take((size_t)NT*4);
    float* pooled = (float*)take((size_t)BATCH*64*128*4);
    float* adjp   = (float*)take((size_t)BATCH*64*64*4);
    float* hcacc  = (float*)take((size_t)BATCH*128*4);
    float* accb   = (float*)take(64);
    size_t zero_bytes = off;
    // --- non-zeroed ---
    int*   ipd   = (int*)take((size_t)(NT+1)*4);
    int*   ips   = (int*)take((size_t)(NT+1)*4);
    int*   lst_d = (int*)take((size_t)ETOT*4);
    int*   lst_s = (int*)take((size_t)ETOT*4);
    float* agg   = (float*)take((size_t)NT*128*4);   // reused as s2 later
    float* zb    = (float*)take((size_t)NT*128*4);
    float* spre  = (float*)take((size_t)NT*64*4);    // reused as t later
    float* hbuf  = (float*)take((size_t)BATCH*8192*4);
    float* s2    = agg;
    float* tbuf  = spre;

    float* crossp = accb + 0;
    float* normgp = accb + 1;
    float* entp   = accb + 2;
    unsigned int* a2p = (unsigned int*)(accb + 3);

    hipMemsetAsync(d_ws, 0, zero_bytes, stream);

    k_count<<<ETOT/256, 256, 0, stream>>>(src, dst, cnt_d, cnt_s);
    k_scan<<<1, 1024, 0, stream>>>(cnt_d, ipd);
    k_scan<<<1, 1024, 0, stream>>>(cnt_s, ips);
    k_fill<<<ETOT/256, 256, 0, stream>>>(src, dst, ipd, ips, cur_d, cur_s, lst_d, lst_s);

    // SAGE layer 1: z = leaky(mean_agg(x)@W1l + b1l + x@W1r)
    k_agg<<<NT, 128, 0, stream>>>(x, ipd, lst_d, agg, 128, 1);
    k_gemm<<<dim3(NT/64, 2), 256, 0, stream>>>(agg, x, W1l, W1r, b1l, zb, NT, 128, 128, 1, 1);

    // SAGE layer 2 + Wm
    k_agg<<<NT, 128, 0, stream>>>(zb, ipd, lst_d, agg, 128, 1);
    k_gemm<<<dim3(NT/64, 1), 256, 0, stream>>>(agg, zb, W2l, W2r, b2l, spre, NT, 64, 128, 1, 1);
    k_gemm<<<dim3(NT/64, 1), 256, 0, stream>>>(spre, nullptr, Wm, nullptr, bm, s2, NT, 64, 64, 0, 0);

    // softmax + entropy
    k_softmax_ent<<<NT/4, 256, 0, stream>>>(s2, entp);

    // t = A @ s  (sum of s[dst] over out-edges)
    k_agg<<<NT, 64, 0, stream>>>(s2, ips, lst_s, tbuf, 64, 0);

    // pooled, adj_p, loss pieces
    k_pooled<<<BATCH*4, 256, 0, stream>>>(s2, zb, pooled);
    k_adjp<<<BATCH*4, 256, 0, stream>>>(s2, tbuf, adjp);
    k_normG<<<BATCH, 256, 0, stream>>>(s2, normgp);
    k_dot<<<1024, 256, 0, stream>>>(s2, tbuf, crossp);   // cross = sum_n s[n].t[n]
    k_a2<<<BATCH, 1024, 0, stream>>>(src, dst, a2p);

    // head + finalize
    k_head1<<<BATCH, 256, 0, stream>>>(adjp, pooled, Wrel, Wroot, broot, hbuf);
    k_head2<<<BATCH*16, 256, 0, stream>>>(hbuf, Wc1, hcacc);
    k_head3<<<BATCH, 128, 0, stream>>>(hcacc, bc1, Wc2, bc2, out);
    k_finalize<<<1, 1, 0, stream>>>(a2p, crossp, normgp, entp, out);
}

// Round 3
// 1595.676 us; speedup vs baseline: 2.1634x; 1.4988x over previous
//
#include <hip/hip_runtime.h>
#include <math.h>

#define BATCH 64
#define NPG 1024
#define NT (BATCH*NPG)        // 65536 nodes
#define EPER 32768
#define ETOT (BATCH*EPER)     // 2097152 edges

__device__ __forceinline__ float lky(float x){ return x > 0.f ? x : 0.01f*x; }
__device__ __forceinline__ unsigned short f2bf(float f){
    unsigned u = __float_as_uint(f);
    u = u + 0x7FFFu + ((u >> 16) & 1u);      // RNE
    return (unsigned short)(u >> 16);
}

// ---------------- fp32 -> bf16 cast (vectorized) ----------------
__global__ void k_castx(const float* __restrict__ in, unsigned short* __restrict__ out, int n4){
    int i = blockIdx.x*256 + threadIdx.x;
    if (i < n4){
        float4 v = ((const float4*)in)[i];
        ushort4 o = { f2bf(v.x), f2bf(v.y), f2bf(v.z), f2bf(v.w) };
        ((ushort4*)out)[i] = o;
    }
}

// ---------------- sum(a^2) via byte-packed histogram ----------------
__global__ void k_hist(const int* __restrict__ src, const int* __restrict__ dst,
                       unsigned* __restrict__ hist){
    int e = blockIdx.x*256 + threadIdx.x;
    if (e < ETOT){
        unsigned s = (unsigned)src[e], d = (unsigned)dst[e];
        unsigned b = s >> 10;
        unsigned key = (b << 20) | ((s & 1023u) << 10) | (d & 1023u);
        atomicAdd(&hist[key >> 2], 1u << ((key & 3u)*8));
    }
}

__device__ __forceinline__ unsigned sqbytes(unsigned w){
    unsigned s = 0;
    #pragma unroll
    for (int k = 0; k < 4; k++){ unsigned c = (w >> (8*k)) & 255u; s += c*c; }
    return s;
}

__global__ void k_sumsq(const uint4* __restrict__ hist, unsigned* __restrict__ acc_out){
    unsigned local = 0;
    for (size_t i = (size_t)blockIdx.x*256 + threadIdx.x; i < (size_t)4*1024*1024;
         i += (size_t)gridDim.x*256){
        uint4 w = hist[i];
        local += sqbytes(w.x) + sqbytes(w.y) + sqbytes(w.z) + sqbytes(w.w);
    }
    for (int o = 32; o; o >>= 1) local += __shfl_xor(local, o);
    __shared__ unsigned red[4];
    if ((threadIdx.x & 63) == 0) red[threadIdx.x >> 6] = local;
    __syncthreads();
    if (threadIdx.x == 0) atomicAdd(acc_out, red[0]+red[1]+red[2]+red[3]);
}

// ---------------- CSR build ----------------
__global__ void k_count(const int* __restrict__ src, const int* __restrict__ dst,
                        int* cnt_d, int* cnt_s){
    int e = blockIdx.x*256 + threadIdx.x;
    if (e < ETOT){
        atomicAdd(&cnt_d[dst[e]], 1);
        atomicAdd(&cnt_s[src[e]], 1);
    }
}

__global__ void k_scan_local(const int* __restrict__ cnt_d, const int* __restrict__ cnt_s,
                             int* __restrict__ ipd, int* __restrict__ ips, int* __restrict__ tots){
    __shared__ int buf[1024];
    int which = blockIdx.y;
    const int* cnt = which ? cnt_s : cnt_d;
    int* ip = which ? ips : ipd;
    int base = blockIdx.x*1024;
    int tid = threadIdx.x;
    int v = cnt[base + tid];
    int x = v;
    buf[tid] = x; __syncthreads();
    for (int off = 1; off < 1024; off <<= 1){
        int t = (tid >= off) ? buf[tid - off] : 0;
        __syncthreads();
        x += t; buf[tid] = x; __syncthreads();
    }
    ip[base + tid] = x - v;                      // block-local exclusive
    if (tid == 1023) tots[which*64 + blockIdx.x] = x;
}

__global__ void k_scan_add(const int* __restrict__ tots, int* __restrict__ ipd, int* __restrict__ ips){
    int which = blockIdx.y;
    int* ip = which ? ips : ipd;
    const int* t = tots + which*64;
    __shared__ int soff;
    if (threadIdx.x == 0){
        int s = 0;
        for (int i = 0; i < (int)blockIdx.x; i++) s += t[i];
        soff = s;
    }
    __syncthreads();
    ip[blockIdx.x*1024 + threadIdx.x] += soff;
    if (blockIdx.x == 0 && threadIdx.x == 0) ip[NT] = ETOT;
}

__global__ void k_fill(const int* __restrict__ src, const int* __restrict__ dst,
                       const int* __restrict__ ipd, const int* __restrict__ ips,
                       int* cur_d, int* cur_s, int* lst_d, int* lst_s){
    int e = blockIdx.x*256 + threadIdx.x;
    if (e < ETOT){
        int s = src[e], d = dst[e];
        int p = atomicAdd(&cur_d[d], 1); lst_d[ipd[d] + p] = s;
        int q = atomicAdd(&cur_s[s], 1); lst_s[ips[s] + q] = d;
    }
}

// ---------------- bf16 segment gather (G threads per node, 2 feats/thread) ----------------
template<int G>
__global__ void k_aggh(const unsigned short* __restrict__ X, const int* __restrict__ indptr,
                       const int* __restrict__ lst, float* __restrict__ out, int do_mean){
    int node = blockIdx.x*(256/G) + threadIdx.x/G;
    int g = threadIdx.x % G;
    int st = indptr[node], en = indptr[node+1];
    float a0 = 0.f, a1 = 0.f;
    for (int e = st; e < en; e++){
        int nb = lst[e];
        unsigned v = *(const unsigned*)&X[(size_t)nb*(2*G) + 2*g];
        a0 += __uint_as_float((v & 0xFFFFu) << 16);
        a1 += __uint_as_float(v & 0xFFFF0000u);
    }
    if (do_mean){
        int dg = en - st;
        float inv = 1.f/(float)(dg > 1 ? dg : 1);
        a0 *= inv; a1 *= inv;
    }
    out[(size_t)node*(2*G) + 2*g]     = a0;
    out[(size_t)node*(2*G) + 2*g + 1] = a1;
}

// ---------------- fused dual GEMM: C = act(A1@W1 [+ A2@W2] + bias), optional bf16 out ----------------
__global__ void __launch_bounds__(256) k_gemm(
        const float* __restrict__ A1, const float* __restrict__ A2,
        const float* __restrict__ W1, const float* __restrict__ W2,
        const float* __restrict__ bias, void* __restrict__ C,
        int M, int Nn, int Kd, int dual, int act, int obf){
    __shared__ float sA1[16*68], sB1[16*68], sA2[16*68], sB2[16*68];
    int tid = threadIdx.x;
    int m0 = blockIdx.x*64, n0 = blockIdx.y*64;
    int tx = tid & 15, ty = tid >> 4;
    int lr = tid >> 2, lk = (tid & 3)*4;
    int wk = tid >> 4, wn = (tid & 15)*4;
    float acc[4][4] = {};
    for (int k0 = 0; k0 < Kd; k0 += 16){
        float4 a1 = *(const float4*)&A1[(size_t)(m0+lr)*Kd + k0 + lk];
        float4 w1 = *(const float4*)&W1[(size_t)(k0+wk)*Nn + n0 + wn];
        sA1[(lk+0)*68+lr] = a1.x; sA1[(lk+1)*68+lr] = a1.y;
        sA1[(lk+2)*68+lr] = a1.z; sA1[(lk+3)*68+lr] = a1.w;
        *(float4*)&sB1[wk*68+wn] = w1;
        if (dual){
            float4 a2 = *(const float4*)&A2[(size_t)(m0+lr)*Kd + k0 + lk];
            float4 w2 = *(const float4*)&W2[(size_t)(k0+wk)*Nn + n0 + wn];
            sA2[(lk+0)*68+lr] = a2.x; sA2[(lk+1)*68+lr] = a2.y;
            sA2[(lk+2)*68+lr] = a2.z; sA2[(lk+3)*68+lr] = a2.w;
            *(float4*)&sB2[wk*68+wn] = w2;
        }
        __syncthreads();
        #pragma unroll
        for (int kk = 0; kk < 16; kk++){
            float4 av = *(const float4*)&sA1[kk*68 + ty*4];
            float4 bv = *(const float4*)&sB1[kk*68 + tx*4];
            float a[4] = {av.x, av.y, av.z, av.w};
            float b[4] = {bv.x, bv.y, bv.z, bv.w};
            #pragma unroll
            for (int i = 0; i < 4; i++)
                #pragma unroll
                for (int j = 0; j < 4; j++) acc[i][j] += a[i]*b[j];
            if (dual){
                float4 av2 = *(const float4*)&sA2[kk*68 + ty*4];
                float4 bv2 = *(const float4*)&sB2[kk*68 + tx*4];
                float a2[4] = {av2.x, av2.y, av2.z, av2.w};
                float b2[4] = {bv2.x, bv2.y, bv2.z, bv2.w};
                #pragma unroll
                for (int i = 0; i < 4; i++)
                    #pragma unroll
                    for (int j = 0; j < 4; j++) acc[i][j] += a2[i]*b2[j];
            }
        }
        __syncthreads();
    }
    float bb[4] = {0.f, 0.f, 0.f, 0.f};
    if (bias){
        #pragma unroll
        for (int j = 0; j < 4; j++) bb[j] = bias[n0 + tx*4 + j];
    }
    #pragma unroll
    for (int i = 0; i < 4; i++){
        float v0 = acc[i][0]+bb[0], v1 = acc[i][1]+bb[1], v2 = acc[i][2]+bb[2], v3 = acc[i][3]+bb[3];
        if (act){ v0 = lky(v0); v1 = lky(v1); v2 = lky(v2); v3 = lky(v3); }
        size_t idx = (size_t)(m0 + ty*4 + i)*Nn + n0 + tx*4;
        if (obf){
            ushort4 o = { f2bf(v0), f2bf(v1), f2bf(v2), f2bf(v3) };
            *(ushort4*)&((unsigned short*)C)[idx] = o;
        } else {
            float4 o = { v0, v1, v2, v3 };
            *(float4*)&((float*)C)[idx] = o;
        }
    }
}

// ---------------- spre = lky(agg2 + r2 + b2l) in-place over r2 ----------------
__global__ void k_fin2(const float* __restrict__ agg2, float* __restrict__ r2,
                       const float* __restrict__ b2l){
    size_t i = (size_t)blockIdx.x*256 + threadIdx.x;   // NT*16 float4s
    float4 a = ((const float4*)agg2)[i];
    float4 r = ((float4*)r2)[i];
    int c0 = ((int)(i & 15))*4;
    r.x = lky(a.x + r.x + b2l[c0+0]);
    r.y = lky(a.y + r.y + b2l[c0+1]);
    r.z = lky(a.z + r.z + b2l[c0+2]);
    r.w = lky(a.w + r.w + b2l[c0+3]);
    ((float4*)r2)[i] = r;
}

// ---------------- softmax over K=64 per row + entropy + bf16 copy ----------------
__global__ void k_softmax_ent(float* __restrict__ S, unsigned short* __restrict__ Sh,
                              float* __restrict__ ent_acc){
    int tid = threadIdx.x;
    int row = blockIdx.x*4 + (tid >> 6);
    int lane = tid & 63;
    float v = S[(size_t)row*64 + lane];
    float m = v;
    for (int o = 32; o; o >>= 1) m = fmaxf(m, __shfl_xor(m, o));
    float e = __expf(v - m);
    float sm = e;
    for (int o = 32; o; o >>= 1) sm += __shfl_xor(sm, o);
    float p = e / sm;
    S[(size_t)row*64 + lane] = p;
    Sh[(size_t)row*64 + lane] = f2bf(p);
    float w = -p*__logf(p + 1e-15f);
    for (int o = 32; o; o >>= 1) w += __shfl_xor(w, o);
    __shared__ float red[4];
    if (lane == 0) red[tid >> 6] = w;
    __syncthreads();
    if (tid == 0) atomicAdd(ent_acc, red[0]+red[1]+red[2]+red[3]);
}

// ---------------- pooled[b] = s[b]^T z[b], 4-way n-split ----------------
__global__ void k_pooled(const float* __restrict__ S, const float* __restrict__ Z,
                         float* __restrict__ P){
    __shared__ float sS[8*64], sZ[8*128];
    int b = blockIdx.x >> 2, part = blockIdx.x & 3;
    int tid = threadIdx.x;
    int kk = (tid & 31)*2, fg = tid >> 5;
    float acc[2][16] = {};
    int nbase = b*NPG + part*256;
    for (int n0 = 0; n0 < 256; n0 += 8){
        for (int i = tid; i < 512; i += 256){ int r = i >> 6, c = i & 63; sS[i] = S[(size_t)(nbase+n0+r)*64 + c]; }
        for (int i = tid; i < 1024; i += 256){ int r = i >> 7, c = i & 127; sZ[i] = Z[(size_t)(nbase+n0+r)*128 + c]; }
        __syncthreads();
        for (int nn = 0; nn < 8; nn++){
            float a0 = sS[nn*64+kk], a1 = sS[nn*64+kk+1];
            #pragma unroll
            for (int j = 0; j < 16; j++){
                float zz = sZ[nn*128 + fg*16 + j];
                acc[0][j] += a0*zz; acc[1][j] += a1*zz;
            }
        }
        __syncthreads();
    }
    for (int c = 0; c < 2; c++)
        for (int j = 0; j < 16; j++)
            atomicAdd(&P[((size_t)b*64 + kk + c)*128 + fg*16 + j], acc[c][j]);
}

// ---------------- AP[b] += s[b]^T T[b] (64x64), 4-way n-split; also used for Gram ----------------
__global__ void k_adjp(const float* __restrict__ S, const float* __restrict__ T,
                       float* __restrict__ AP){
    __shared__ float sS[8*64], sT[8*64];
    int b = blockIdx.x >> 2, part = blockIdx.x & 3;
    int tid = threadIdx.x;
    int kk = (tid & 31)*2, lg = tid >> 5;
    float acc[2][8] = {};
    int nbase = b*NPG + part*256;
    for (int n0 = 0; n0 < 256; n0 += 8){
        for (int i = tid; i < 512; i += 256){
            int r = i >> 6, c = i & 63;
            sS[i] = S[(size_t)(nbase+n0+r)*64 + c];
            sT[i] = T[(size_t)(nbase+n0+r)*64 + c];
        }
        __syncthreads();
        for (int nn = 0; nn < 8; nn++){
            float a0 = sS[nn*64+kk], a1 = sS[nn*64+kk+1];
            #pragma unroll
            for (int j = 0; j < 8; j++){
                float tt = sT[nn*64 + lg*8 + j];
                acc[0][j] += a0*tt; acc[1][j] += a1*tt;
            }
        }
        __syncthreads();
    }
    for (int c = 0; c < 2; c++)
        for (int j = 0; j < 8; j++)
            atomicAdd(&AP[((size_t)b*64 + kk + c)*64 + lg*8 + j], acc[c][j]);
}

// ---------------- sum of squares of gram (64*4096 floats) ----------------
__global__ void k_gramsq(const float* __restrict__ gram, float* __restrict__ acc_out){
    int i = blockIdx.x*256 + threadIdx.x;
    float v = gram[i];
    float s = v*v;
    for (int o = 32; o; o >>= 1) s += __shfl_xor(s, o);
    __shared__ float red[4];
    if ((threadIdx.x & 63) == 0) red[threadIdx.x >> 6] = s;
    __syncthreads();
    if (threadIdx.x == 0) atomicAdd(acc_out, red[0]+red[1]+red[2]+red[3]);
}

// ---------------- cross = sum_n dot(s[n], t[n]) ----------------
__global__ void k_dot(const float* __restrict__ A, const float* __restrict__ B,
                      float* __restrict__ acc_out){
    int tid = threadIdx.x;
    size_t i = (size_t)blockIdx.x*256 + tid;
    size_t stride = (size_t)gridDim.x*256;
    float local = 0.f;
    for (; i < (size_t)NT*16; i += stride){
        float4 a = ((const float4*)A)[i];
        float4 b = ((const float4*)B)[i];
        local += a.x*b.x + a.y*b.y + a.z*b.z + a.w*b.w;
    }
    for (int o = 32; o; o >>= 1) local += __shfl_xor(local, o);
    __shared__ float red[4];
    if ((tid & 63) == 0) red[tid >> 6] = local;
    __syncthreads();
    if (tid == 0) atomicAdd(acc_out, red[0]+red[1]+red[2]+red[3]);
}

// ---------------- head stage 1 ----------------
__global__ void __launch_bounds__(256) k_head1(
        const float* __restrict__ AP, const float* __restrict__ P,
        const float* __restrict__ Wrel, const float* __restrict__ Wroot,
        const float* __restrict__ broot, float* __restrict__ hbuf){
    __shared__ float spool[64*130];
    __shared__ float sagg[64*130];
    __shared__ float srs[64];
    int b = blockIdx.x, tid = threadIdx.x;
    for (int i = tid; i < 8192; i += 256){
        int r = i >> 7, c = i & 127;
        spool[r*130 + c] = P[(size_t)b*8192 + i];
    }
    if (tid < 64){
        float s = 0.f;
        const float* ap = AP + (size_t)b*4096 + tid*64;
        for (int l = 0; l < 64; l++) s += ap[l];
        srs[tid] = fmaxf(s, 1.f);
    }
    __syncthreads();
    int k = tid >> 2, c0 = (tid & 3)*32;
    {
        float acc[32] = {};
        const float* ap = AP + (size_t)b*4096 + k*64;
        for (int l = 0; l < 64; l++){
            float a = ap[l];
            #pragma unroll
            for (int jj = 0; jj < 32; jj++) acc[jj] += a*spool[l*130 + c0 + jj];
        }
        float inv = 1.f/srs[k];
        #pragma unroll
        for (int jj = 0; jj < 32; jj++) sagg[k*130 + c0 + jj] = acc[jj]*inv;
    }
    __syncthreads();
    {
        float acc[32] = {};
        for (int g = 0; g < 128; g++){
            float a = sagg[k*130 + g];
            float p = spool[k*130 + g];
            const float4* wr = (const float4*)&Wrel[(size_t)g*128 + c0];
            const float4* wo = (const float4*)&Wroot[(size_t)g*128 + c0];
            #pragma unroll
            for (int q = 0; q < 8; q++){
                float4 r4 = wr[q], o4 = wo[q];
                acc[q*4+0] += a*r4.x + p*o4.x;
                acc[q*4+1] += a*r4.y + p*o4.y;
                acc[q*4+2] += a*r4.z + p*o4.z;
                acc[q*4+3] += a*r4.w + p*o4.w;
            }
        }
        #pragma unroll
        for (int jj = 0; jj < 32; jj++)
            hbuf[(size_t)b*8192 + k*128 + c0 + jj] = lky(acc[jj] + broot[c0 + jj]);
    }
}

// ---------------- head stage 2 ----------------
__global__ void __launch_bounds__(256) k_head2(
        const float* __restrict__ hbuf, const float* __restrict__ Wc1,
        float* __restrict__ hcacc){
    __shared__ float sh[512];
    __shared__ float sred[256];
    int b = blockIdx.x >> 4, ch = blockIdx.x & 15;
    int tid = threadIdx.x;
    for (int i = tid; i < 512; i += 256) sh[i] = hbuf[(size_t)b*8192 + ch*512 + i];
    __syncthreads();
    int j = tid & 127, half = tid >> 7;
    float acc = 0.f;
    const float* W = Wc1 + (size_t)(ch*512 + half*256)*128;
    const float* hh = sh + half*256;
    for (int r = 0; r < 256; r++) acc += hh[r]*W[(size_t)r*128 + j];
    sred[tid] = acc; __syncthreads();
    if (tid < 128) atomicAdd(&hcacc[(size_t)b*128 + tid], sred[tid] + sred[tid+128]);
}

// ---------------- head stage 3 ----------------
__global__ void k_head3(const float* __restrict__ hcacc, const float* __restrict__ bc1,
                        const float* __restrict__ Wc2, const float* __restrict__ bc2,
                        float* __restrict__ out){
    int b = blockIdx.x, t = threadIdx.x;   // 128 threads
    float hc = lky(hcacc[(size_t)b*128 + t] + bc1[t]);
    float p = hc*Wc2[t];
    for (int o = 32; o; o >>= 1) p += __shfl_xor(p, o);
    __shared__ float r2[2];
    if ((t & 63) == 0) r2[t >> 6] = p;
    __syncthreads();
    if (t == 0) out[b] = r2[0] + r2[1] + bc2[0];
}

__global__ void k_finalize(const unsigned int* __restrict__ a2,
                           const float* __restrict__ cross,
                           const float* __restrict__ normg,
                           const float* __restrict__ ent,
                           float* __restrict__ out){
    float ss = (float)(*a2) - 2.f*(*cross) + (*normg);
    if (ss < 0.f) ss = 0.f;
    float link = sqrtf(ss) / 67108864.f;     // a.size
    out[64] = link + (*ent)/(float)NT;
}

extern "C" void kernel_launch(void* const* d_in, const int* in_sizes, int n_in,
                              void* d_out, int out_size, void* d_ws, size_t ws_size,
                              hipStream_t stream){
    const float* x    = (const float*)d_in[0];
    const int*   ei   = (const int*)d_in[1];
    const int*   src  = ei;
    const int*   dst  = ei + ETOT;
    const float* W1l  = (const float*)d_in[5];
    const float* b1l  = (const float*)d_in[6];
    const float* W1r  = (const float*)d_in[7];
    const float* W2l  = (const float*)d_in[8];
    const float* b2l  = (const float*)d_in[9];
    const float* W2r  = (const float*)d_in[10];
    const float* Wm   = (const float*)d_in[11];
    const float* bm   = (const float*)d_in[12];
    const float* Wrel = (const float*)d_in[13];
    const float* Wroot= (const float*)d_in[14];
    const float* broot= (const float*)d_in[15];
    const float* Wc1  = (const float*)d_in[16];
    const float* bc1  = (const float*)d_in[17];
    const float* Wc2  = (const float*)d_in[18];
    const float* bc2  = (const float*)d_in[19];
    float* out = (float*)d_out;

    char* w = (char*)d_ws;
    size_t off = 0;
    auto take = [&](size_t bytes)->void*{
        void* p = w + off; off = (off + bytes + 255) & ~(size_t)255; return p;
    };
    // --- small zeroed zone ---
    int*   cnt_d  = (int*)take((size_t)NT*4);
    int*   cnt_s  = (int*)take((size_t)NT*4);
    int*   cur_d  = (int*)take((size_t)NT*4);
    int*   cur_s  = (int*)take((size_t)NT*4);
    float* pooled = (float*)take((size_t)BATCH*64*128*4);
    float* adjp   = (float*)take((size_t)BATCH*64*64*4);
    float* gram   = (float*)take((size_t)BATCH*64*64*4);
    float* hcacc  = (float*)take((size_t)BATCH*128*4);
    int*   tots   = (int*)take(2*64*4);
    float* accb   = (float*)take(64);
    size_t zero_small = off;
    // --- non-zeroed ---
    int*   ipd   = (int*)take((size_t)(NT+1)*4);
    int*   ips   = (int*)take((size_t)(NT+1)*4);
    int*   lst_d = (int*)take((size_t)ETOT*4);
    int*   lst_s = (int*)take((size_t)ETOT*4);
    // 16 MB region: xh -> r2/spre -> tbuf
    char*  reg16 = (char*)take((size_t)16*1024*1024);
    // 64 MB region: hist -> [aggbuf 32MB | zbuf 32MB]; agg2/s2 in first 16 MB
    char*  reg64 = (char*)take((size_t)64*1024*1024);
    // 8 MB region: y2h -> s2h
    char*  reg8  = (char*)take((size_t)8*1024*1024);
    float* hbuf  = (float*)take((size_t)BATCH*8192*4);

    unsigned short* xh   = (unsigned short*)reg16;
    float*          r2   = (float*)reg16;          // spre in-place
    float*          tbuf = (float*)reg16;
    unsigned*       hist = (unsigned*)reg64;
    float*          aggbuf = (float*)reg64;        // NT*128 f32
    float*          zbuf   = (float*)(reg64 + (size_t)32*1024*1024);
    float*          agg2   = (float*)reg64;        // NT*64 f32 (after aggbuf dead)
    float*          s2     = (float*)reg64;        // NT*64 f32 (after agg2 dead)
    unsigned short* y2h  = (unsigned short*)reg8;
    unsigned short* s2h  = (unsigned short*)reg8;

    float* crossp = accb + 0;
    float* normgp = accb + 1;
    float* entp   = accb + 2;
    unsigned int* a2p = (unsigned int*)(accb + 3);

    hipMemsetAsync(d_ws, 0, zero_small, stream);
    hipMemsetAsync(hist, 0, (size_t)64*1024*1024, stream);

    // sum(a^2) histogram — uses only src/dst + hist region, runs first so reg64 frees up
    k_hist<<<ETOT/256, 256, 0, stream>>>(src, dst, hist);
    k_sumsq<<<2048, 256, 0, stream>>>((const uint4*)hist, a2p);

    // x -> bf16
    k_castx<<<NT*128/4/256, 256, 0, stream>>>(x, xh, NT*128/4);

    // CSR build
    k_count<<<ETOT/256, 256, 0, stream>>>(src, dst, cnt_d, cnt_s);
    k_scan_local<<<dim3(64,2), 1024, 0, stream>>>(cnt_d, cnt_s, ipd, ips, tots);
    k_scan_add<<<dim3(64,2), 1024, 0, stream>>>(tots, ipd, ips);
    k_fill<<<ETOT/256, 256, 0, stream>>>(src, dst, ipd, ips, cur_d, cur_s, lst_d, lst_s);

    // SAGE layer 1: z = leaky(mean_agg(x)@W1l + b1l + x@W1r)
    k_aggh<64><<<NT/4, 256, 0, stream>>>(xh, ipd, lst_d, aggbuf, 1);
    k_gemm<<<dim3(NT/64, 2), 256, 0, stream>>>(aggbuf, x, W1l, W1r, b1l, zbuf, NT, 128, 128, 1, 1, 0);

    // SAGE layer 2 (GEMM-before-gather): y2 = z@W2l (bf16), r2 = z@W2r
    k_gemm<<<dim3(NT/64, 1), 256, 0, stream>>>(zbuf, nullptr, W2l, nullptr, nullptr, y2h, NT, 64, 128, 0, 0, 1);
    k_gemm<<<dim3(NT/64, 1), 256, 0, stream>>>(zbuf, nullptr, W2r, nullptr, nullptr, r2, NT, 64, 128, 0, 0, 0);
    k_aggh<32><<<NT/8, 256, 0, stream>>>(y2h, ipd, lst_d, agg2, 1);
    k_fin2<<<NT*16/256, 256, 0, stream>>>(agg2, r2, b2l);           // spre in r2
    k_gemm<<<dim3(NT/64, 1), 256, 0, stream>>>(r2, nullptr, Wm, nullptr, bm, s2, NT, 64, 64, 0, 0, 0);

    // softmax + entropy (+ bf16 copy of s)
    k_softmax_ent<<<NT/4, 256, 0, stream>>>(s2, s2h, entp);

    // t = A @ s
    k_aggh<32><<<NT/8, 256, 0, stream>>>(s2h, ips, lst_s, tbuf, 0);

    // pooled, adj_p, gram, cross
    k_pooled<<<BATCH*4, 256, 0, stream>>>(s2, zbuf, pooled);
    k_adjp<<<BATCH*4, 256, 0, stream>>>(s2, tbuf, adjp);
    k_adjp<<<BATCH*4, 256, 0, stream>>>(s2, s2, gram);
    k_gramsq<<<BATCH*4096/256, 256, 0, stream>>>(gram, normgp);
    k_dot<<<1024, 256, 0, stream>>>(s2, tbuf, crossp);

    // head + finalize
    k_head1<<<BATCH, 256, 0, stream>>>(adjp, pooled, Wrel, Wroot, broot, hbuf);
    k_head2<<<BATCH*16, 256, 0, stream>>>(hbuf, Wc1, hcacc);
    k_head3<<<BATCH, 128, 0, stream>>>(hcacc, bc1, Wc2, bc2, out);
    k_finalize<<<1, 1, 0, stream>>>(a2p, crossp, normgp, entp, out);
}

// Round 4
// 1355.468 us; speedup vs baseline: 2.5468x; 1.1772x over previous
//
#include <hip/hip_runtime.h>
#include <math.h>

#define BATCH 64
#define NPG 1024
#define NT (BATCH*NPG)        // 65536 nodes
#define EPER 32768
#define ETOT (BATCH*EPER)     // 2097152 edges

__device__ __forceinline__ float lky(float x){ return x > 0.f ? x : 0.01f*x; }
__device__ __forceinline__ unsigned short f2bf(float f){
    unsigned u = __float_as_uint(f);
    u = u + 0x7FFFu + ((u >> 16) & 1u);      // RNE
    return (unsigned short)(u >> 16);
}

// ---------------- fp32 -> bf16 cast (vectorized) ----------------
__global__ void k_castx(const float* __restrict__ in, unsigned short* __restrict__ out, int n4){
    int i = blockIdx.x*256 + threadIdx.x;
    if (i < n4){
        float4 v = ((const float4*)in)[i];
        ushort4 o = { f2bf(v.x), f2bf(v.y), f2bf(v.z), f2bf(v.w) };
        ((ushort4*)out)[i] = o;
    }
}

// ---------------- hist (sum(a^2) bytes) + CSR degree counts, one edge pass ----------------
__global__ void k_hist(const int* __restrict__ src, const int* __restrict__ dst,
                       unsigned* __restrict__ hist, int* cnt_d, int* cnt_s){
    int e = blockIdx.x*256 + threadIdx.x;
    if (e < ETOT){
        unsigned s = (unsigned)src[e], d = (unsigned)dst[e];
        unsigned b = s >> 10;
        unsigned key = (b << 20) | ((s & 1023u) << 10) | (d & 1023u);
        atomicAdd(&hist[key >> 2], 1u << ((key & 3u)*8));
        atomicAdd(&cnt_d[d], 1);
        atomicAdd(&cnt_s[s], 1);
    }
}

__device__ __forceinline__ unsigned sqbytes(unsigned w){
    unsigned s = 0;
    #pragma unroll
    for (int k = 0; k < 4; k++){ unsigned c = (w >> (8*k)) & 255u; s += c*c; }
    return s;
}

__global__ void k_sumsq(const uint4* __restrict__ hist, unsigned* __restrict__ acc_out){
    unsigned local = 0;
    for (size_t i = (size_t)blockIdx.x*256 + threadIdx.x; i < (size_t)4*1024*1024;
         i += (size_t)gridDim.x*256){
        uint4 w = hist[i];
        local += sqbytes(w.x) + sqbytes(w.y) + sqbytes(w.z) + sqbytes(w.w);
    }
    for (int o = 32; o; o >>= 1) local += __shfl_xor(local, o);
    __shared__ unsigned red[4];
    if ((threadIdx.x & 63) == 0) red[threadIdx.x >> 6] = local;
    __syncthreads();
    if (threadIdx.x == 0) atomicAdd(acc_out, red[0]+red[1]+red[2]+red[3]);
}

// ---------------- CSR scans + fill ----------------
__global__ void k_scan_local(const int* __restrict__ cnt_d, const int* __restrict__ cnt_s,
                             int* __restrict__ ipd, int* __restrict__ ips, int* __restrict__ tots){
    __shared__ int buf[1024];
    int which = blockIdx.y;
    const int* cnt = which ? cnt_s : cnt_d;
    int* ip = which ? ips : ipd;
    int base = blockIdx.x*1024;
    int tid = threadIdx.x;
    int v = cnt[base + tid];
    int x = v;
    buf[tid] = x; __syncthreads();
    for (int off = 1; off < 1024; off <<= 1){
        int t = (tid >= off) ? buf[tid - off] : 0;
        __syncthreads();
        x += t; buf[tid] = x; __syncthreads();
    }
    ip[base + tid] = x - v;                      // block-local exclusive
    if (tid == 1023) tots[which*64 + blockIdx.x] = x;
}

__global__ void k_scan_add(const int* __restrict__ tots, int* __restrict__ ipd, int* __restrict__ ips){
    int which = blockIdx.y;
    int* ip = which ? ips : ipd;
    const int* t = tots + which*64;
    __shared__ int soff;
    if (threadIdx.x == 0){
        int s = 0;
        for (int i = 0; i < (int)blockIdx.x; i++) s += t[i];
        soff = s;
    }
    __syncthreads();
    ip[blockIdx.x*1024 + threadIdx.x] += soff;
    if (blockIdx.x == 0 && threadIdx.x == 0) ip[NT] = ETOT;
}

__global__ void k_fill(const int* __restrict__ src, const int* __restrict__ dst,
                       const int* __restrict__ ipd, const int* __restrict__ ips,
                       int* cur_d, int* cur_s, int* lst_d, int* lst_s){
    int e = blockIdx.x*256 + threadIdx.x;
    if (e < ETOT){
        int s = src[e], d = dst[e];
        int p = atomicAdd(&cur_d[d], 1); lst_d[ipd[d] + p] = s;
        int q = atomicAdd(&cur_s[s], 1); lst_s[ips[s] + q] = d;
    }
}

// ---------------- bf16 segment gather (G threads per node, 2 feats/thread) ----------------
template<int G>
__global__ void k_aggh(const unsigned short* __restrict__ X, const int* __restrict__ indptr,
                       const int* __restrict__ lst, float* __restrict__ out, int do_mean){
    int node = blockIdx.x*(256/G) + threadIdx.x/G;
    int g = threadIdx.x % G;
    int st = indptr[node], en = indptr[node+1];
    float a0 = 0.f, a1 = 0.f;
    for (int e = st; e < en; e++){
        int nb = lst[e];
        unsigned v = *(const unsigned*)&X[(size_t)nb*(2*G) + 2*g];
        a0 += __uint_as_float((v & 0xFFFFu) << 16);
        a1 += __uint_as_float(v & 0xFFFF0000u);
    }
    if (do_mean){
        int dg = en - st;
        float inv = 1.f/(float)(dg > 1 ? dg : 1);
        a0 *= inv; a1 *= inv;
    }
    out[(size_t)node*(2*G) + 2*g]     = a0;
    out[(size_t)node*(2*G) + 2*g + 1] = a1;
}

// ---------------- fused dual GEMM: C = act(A1@W1 [+ A2@W2] + bias), optional bf16 out ----------------
__global__ void __launch_bounds__(256) k_gemm(
        const float* __restrict__ A1, const float* __restrict__ A2,
        const float* __restrict__ W1, const float* __restrict__ W2,
        const float* __restrict__ bias, void* __restrict__ C,
        int M, int Nn, int Kd, int dual, int act, int obf){
    __shared__ float sA1[16*68], sB1[16*68], sA2[16*68], sB2[16*68];
    int tid = threadIdx.x;
    int m0 = blockIdx.x*64, n0 = blockIdx.y*64;
    int tx = tid & 15, ty = tid >> 4;
    int lr = tid >> 2, lk = (tid & 3)*4;
    int wk = tid >> 4, wn = (tid & 15)*4;
    float acc[4][4] = {};
    for (int k0 = 0; k0 < Kd; k0 += 16){
        float4 a1 = *(const float4*)&A1[(size_t)(m0+lr)*Kd + k0 + lk];
        float4 w1 = *(const float4*)&W1[(size_t)(k0+wk)*Nn + n0 + wn];
        sA1[(lk+0)*68+lr] = a1.x; sA1[(lk+1)*68+lr] = a1.y;
        sA1[(lk+2)*68+lr] = a1.z; sA1[(lk+3)*68+lr] = a1.w;
        *(float4*)&sB1[wk*68+wn] = w1;
        if (dual){
            float4 a2 = *(const float4*)&A2[(size_t)(m0+lr)*Kd + k0 + lk];
            float4 w2 = *(const float4*)&W2[(size_t)(k0+wk)*Nn + n0 + wn];
            sA2[(lk+0)*68+lr] = a2.x; sA2[(lk+1)*68+lr] = a2.y;
            sA2[(lk+2)*68+lr] = a2.z; sA2[(lk+3)*68+lr] = a2.w;
            *(float4*)&sB2[wk*68+wn] = w2;
        }
        __syncthreads();
        #pragma unroll
        for (int kk = 0; kk < 16; kk++){
            float4 av = *(const float4*)&sA1[kk*68 + ty*4];
            float4 bv = *(const float4*)&sB1[kk*68 + tx*4];
            float a[4] = {av.x, av.y, av.z, av.w};
            float b[4] = {bv.x, bv.y, bv.z, bv.w};
            #pragma unroll
            for (int i = 0; i < 4; i++)
                #pragma unroll
                for (int j = 0; j < 4; j++) acc[i][j] += a[i]*b[j];
            if (dual){
                float4 av2 = *(const float4*)&sA2[kk*68 + ty*4];
                float4 bv2 = *(const float4*)&sB2[kk*68 + tx*4];
                float a2[4] = {av2.x, av2.y, av2.z, av2.w};
                float b2[4] = {bv2.x, bv2.y, bv2.z, bv2.w};
                #pragma unroll
                for (int i = 0; i < 4; i++)
                    #pragma unroll
                    for (int j = 0; j < 4; j++) acc[i][j] += a2[i]*b2[j];
            }
        }
        __syncthreads();
    }
    float bb[4] = {0.f, 0.f, 0.f, 0.f};
    if (bias){
        #pragma unroll
        for (int j = 0; j < 4; j++) bb[j] = bias[n0 + tx*4 + j];
    }
    #pragma unroll
    for (int i = 0; i < 4; i++){
        float v0 = acc[i][0]+bb[0], v1 = acc[i][1]+bb[1], v2 = acc[i][2]+bb[2], v3 = acc[i][3]+bb[3];
        if (act){ v0 = lky(v0); v1 = lky(v1); v2 = lky(v2); v3 = lky(v3); }
        size_t idx = (size_t)(m0 + ty*4 + i)*Nn + n0 + tx*4;
        if (obf){
            ushort4 o = { f2bf(v0), f2bf(v1), f2bf(v2), f2bf(v3) };
            *(ushort4*)&((unsigned short*)C)[idx] = o;
        } else {
            float4 o = { v0, v1, v2, v3 };
            *(float4*)&((float*)C)[idx] = o;
        }
    }
}

// ---------------- spre = lky(agg2 + r2 + b2l) in-place over r2 ----------------
__global__ void k_fin2(const float* __restrict__ agg2, float* __restrict__ r2,
                       const float* __restrict__ b2l){
    size_t i = (size_t)blockIdx.x*256 + threadIdx.x;   // NT*16 float4s
    float4 a = ((const float4*)agg2)[i];
    float4 r = ((float4*)r2)[i];
    int c0 = ((int)(i & 15))*4;
    r.x = lky(a.x + r.x + b2l[c0+0]);
    r.y = lky(a.y + r.y + b2l[c0+1]);
    r.z = lky(a.z + r.z + b2l[c0+2]);
    r.w = lky(a.w + r.w + b2l[c0+3]);
    ((float4*)r2)[i] = r;
}

// ---------------- softmax over K=64 per row + entropy + bf16 copy ----------------
__global__ void k_softmax_ent(float* __restrict__ S, unsigned short* __restrict__ Sh,
                              float* __restrict__ ent_acc){
    int tid = threadIdx.x;
    int row = blockIdx.x*4 + (tid >> 6);
    int lane = tid & 63;
    float v = S[(size_t)row*64 + lane];
    float m = v;
    for (int o = 32; o; o >>= 1) m = fmaxf(m, __shfl_xor(m, o));
    float e = __expf(v - m);
    float sm = e;
    for (int o = 32; o; o >>= 1) sm += __shfl_xor(sm, o);
    float p = e / sm;
    S[(size_t)row*64 + lane] = p;
    Sh[(size_t)row*64 + lane] = f2bf(p);
    float w = -p*__logf(p + 1e-15f);
    for (int o = 32; o; o >>= 1) w += __shfl_xor(w, o);
    __shared__ float red[4];
    if (lane == 0) red[tid >> 6] = w;
    __syncthreads();
    if (tid == 0) atomicAdd(ent_acc, red[0]+red[1]+red[2]+red[3]);
}

// ---------------- pooled[b] = s[b]^T z[b], 4-way n-split ----------------
__global__ void k_pooled(const float* __restrict__ S, const float* __restrict__ Z,
                         float* __restrict__ P){
    __shared__ float sS[8*64], sZ[8*128];
    int b = blockIdx.x >> 2, part = blockIdx.x & 3;
    int tid = threadIdx.x;
    int kk = (tid & 31)*2, fg = tid >> 5;
    float acc[2][16] = {};
    int nbase = b*NPG + part*256;
    for (int n0 = 0; n0 < 256; n0 += 8){
        for (int i = tid; i < 512; i += 256){ int r = i >> 6, c = i & 63; sS[i] = S[(size_t)(nbase+n0+r)*64 + c]; }
        for (int i = tid; i < 1024; i += 256){ int r = i >> 7, c = i & 127; sZ[i] = Z[(size_t)(nbase+n0+r)*128 + c]; }
        __syncthreads();
        for (int nn = 0; nn < 8; nn++){
            float a0 = sS[nn*64+kk], a1 = sS[nn*64+kk+1];
            #pragma unroll
            for (int j = 0; j < 16; j++){
                float zz = sZ[nn*128 + fg*16 + j];
                acc[0][j] += a0*zz; acc[1][j] += a1*zz;
            }
        }
        __syncthreads();
    }
    for (int c = 0; c < 2; c++)
        for (int j = 0; j < 16; j++)
            atomicAdd(&P[((size_t)b*64 + kk + c)*128 + fg*16 + j], acc[c][j]);
}

// ---------------- AP[b] += s^T t AND GR[b] += s^T s in one pass ----------------
__global__ void k_adjp2(const float* __restrict__ S, const float* __restrict__ T,
                        float* __restrict__ AP, float* __restrict__ GR){
    __shared__ float sS[8*64], sT[8*64];
    int b = blockIdx.x >> 2, part = blockIdx.x & 3;
    int tid = threadIdx.x;
    int kk = (tid & 31)*2, lg = tid >> 5;
    float acc[2][8] = {};
    float acg[2][8] = {};
    int nbase = b*NPG + part*256;
    for (int n0 = 0; n0 < 256; n0 += 8){
        for (int i = tid; i < 512; i += 256){
            int r = i >> 6, c = i & 63;
            sS[i] = S[(size_t)(nbase+n0+r)*64 + c];
            sT[i] = T[(size_t)(nbase+n0+r)*64 + c];
        }
        __syncthreads();
        for (int nn = 0; nn < 8; nn++){
            float a0 = sS[nn*64+kk], a1 = sS[nn*64+kk+1];
            #pragma unroll
            for (int j = 0; j < 8; j++){
                float tt = sT[nn*64 + lg*8 + j];
                float ss = sS[nn*64 + lg*8 + j];
                acc[0][j] += a0*tt; acc[1][j] += a1*tt;
                acg[0][j] += a0*ss; acg[1][j] += a1*ss;
            }
        }
        __syncthreads();
    }
    for (int c = 0; c < 2; c++)
        for (int j = 0; j < 8; j++){
            atomicAdd(&AP[((size_t)b*64 + kk + c)*64 + lg*8 + j], acc[c][j]);
            atomicAdd(&GR[((size_t)b*64 + kk + c)*64 + lg*8 + j], acg[c][j]);
        }
}

// ---------------- sum of squares of gram ----------------
__global__ void k_gramsq(const float* __restrict__ gram, float* __restrict__ acc_out){
    int i = blockIdx.x*256 + threadIdx.x;
    float v = gram[i];
    float s = v*v;
    for (int o = 32; o; o >>= 1) s += __shfl_xor(s, o);
    __shared__ float red[4];
    if ((threadIdx.x & 63) == 0) red[threadIdx.x >> 6] = s;
    __syncthreads();
    if (threadIdx.x == 0) atomicAdd(acc_out, red[0]+red[1]+red[2]+red[3]);
}

// ---------------- cross = sum_b trace(adjp[b])  (= sum_n dot(s[n],t[n])) ----------------
__global__ void k_trace(const float* __restrict__ AP, float* __restrict__ acc_out){
    int i = blockIdx.x*256 + threadIdx.x;      // 4096 diag entries
    float s = AP[(size_t)(i >> 6)*4096 + (i & 63)*65];
    for (int o = 32; o; o >>= 1) s += __shfl_xor(s, o);
    __shared__ float red[4];
    if ((threadIdx.x & 63) == 0) red[threadIdx.x >> 6] = s;
    __syncthreads();
    if (threadIdx.x == 0) atomicAdd(acc_out, red[0]+red[1]+red[2]+red[3]);
}

// ---------------- head stage A: aggout[b] = (adjp[b] @ pooled[b]) / rowsum ----------------
__global__ void __launch_bounds__(256) k_heada(
        const float* __restrict__ AP, const float* __restrict__ P,
        float* __restrict__ aggout){
    __shared__ float sapT[64*65];   // transposed adjp, padded
    __shared__ float sp[64*33];     // pooled column chunk
    __shared__ float srs[64];
    int b = blockIdx.x, c0 = blockIdx.y*32;
    int tid = threadIdx.x;
    for (int i = tid; i < 4096; i += 256){
        int k = i >> 6, l = i & 63;
        sapT[l*65 + k] = AP[(size_t)b*4096 + i];
    }
    for (int i = tid; i < 2048; i += 256){
        int l = i >> 5, j = i & 31;
        sp[l*33 + j] = P[(size_t)b*8192 + l*128 + c0 + j];
    }
    __syncthreads();
    if (tid < 64){
        float s = 0.f;
        for (int l = 0; l < 64; l++) s += sapT[l*65 + tid];
        srs[tid] = fmaxf(s, 1.f);
    }
    __syncthreads();
    int k = tid & 63, jg = (tid >> 6)*8;
    float acc[8] = {};
    for (int l = 0; l < 64; l++){
        float a = sapT[l*65 + k];
        #pragma unroll
        for (int j = 0; j < 8; j++) acc[j] += a*sp[l*33 + jg + j];
    }
    float inv = 1.f/srs[k];
    #pragma unroll
    for (int j = 0; j < 8; j++)
        aggout[(size_t)b*8192 + k*128 + c0 + jg + j] = acc[j]*inv;
}

// ---------------- head stage C: hcacc[b,:] += h[b, chunk] @ Wc1[chunk, :] ----------------
__global__ void __launch_bounds__(256) k_head2(
        const float* __restrict__ hbuf, const float* __restrict__ Wc1,
        float* __restrict__ hcacc){
    __shared__ float sh[512];
    __shared__ float sred[256];
    int b = blockIdx.x >> 4, ch = blockIdx.x & 15;
    int tid = threadIdx.x;
    for (int i = tid; i < 512; i += 256) sh[i] = hbuf[(size_t)b*8192 + ch*512 + i];
    __syncthreads();
    int j = tid & 127, half = tid >> 7;
    float acc = 0.f;
    const float* W = Wc1 + (size_t)(ch*512 + half*256)*128;
    const float* hh = sh + half*256;
    for (int r = 0; r < 256; r++) acc += hh[r]*W[(size_t)r*128 + j];
    sred[tid] = acc; __syncthreads();
    if (tid < 128) atomicAdd(&hcacc[(size_t)b*128 + tid], sred[tid] + sred[tid+128]);
}

// ---------------- head stage D: logits ----------------
__global__ void k_head3(const float* __restrict__ hcacc, const float* __restrict__ bc1,
                        const float* __restrict__ Wc2, const float* __restrict__ bc2,
                        float* __restrict__ out){
    int b = blockIdx.x, t = threadIdx.x;   // 128 threads
    float hc = lky(hcacc[(size_t)b*128 + t] + bc1[t]);
    float p = hc*Wc2[t];
    for (int o = 32; o; o >>= 1) p += __shfl_xor(p, o);
    __shared__ float r2[2];
    if ((t & 63) == 0) r2[t >> 6] = p;
    __syncthreads();
    if (t == 0) out[b] = r2[0] + r2[1] + bc2[0];
}

__global__ void k_finalize(const unsigned int* __restrict__ a2,
                           const float* __restrict__ cross,
                           const float* __restrict__ normg,
                           const float* __restrict__ ent,
                           float* __restrict__ out){
    float ss = (float)(*a2) - 2.f*(*cross) + (*normg);
    if (ss < 0.f) ss = 0.f;
    float link = sqrtf(ss) / 67108864.f;     // a.size
    out[64] = link + (*ent)/(float)NT;
}

extern "C" void kernel_launch(void* const* d_in, const int* in_sizes, int n_in,
                              void* d_out, int out_size, void* d_ws, size_t ws_size,
                              hipStream_t stream){
    const float* x    = (const float*)d_in[0];
    const int*   ei   = (const int*)d_in[1];
    const int*   src  = ei;
    const int*   dst  = ei + ETOT;
    const float* W1l  = (const float*)d_in[5];
    const float* b1l  = (const float*)d_in[6];
    const float* W1r  = (const float*)d_in[7];
    const float* W2l  = (const float*)d_in[8];
    const float* b2l  = (const float*)d_in[9];
    const float* W2r  = (const float*)d_in[10];
    const float* Wm   = (const float*)d_in[11];
    const float* bm   = (const float*)d_in[12];
    const float* Wrel = (const float*)d_in[13];
    const float* Wroot= (const float*)d_in[14];
    const float* broot= (const float*)d_in[15];
    const float* Wc1  = (const float*)d_in[16];
    const float* bc1  = (const float*)d_in[17];
    const float* Wc2  = (const float*)d_in[18];
    const float* bc2  = (const float*)d_in[19];
    float* out = (float*)d_out;

    char* w = (char*)d_ws;
    size_t off = 0;
    auto take = [&](size_t bytes)->void*{
        void* p = w + off; off = (off + bytes + 255) & ~(size_t)255; return p;
    };
    // --- small zeroed zone ---
    int*   cnt_d  = (int*)take((size_t)NT*4);
    int*   cnt_s  = (int*)take((size_t)NT*4);
    int*   cur_d  = (int*)take((size_t)NT*4);
    int*   cur_s  = (int*)take((size_t)NT*4);
    float* pooled = (float*)take((size_t)BATCH*64*128*4);
    float* adjp   = (float*)take((size_t)BATCH*64*64*4);
    float* gram   = (float*)take((size_t)BATCH*64*64*4);
    float* hcacc  = (float*)take((size_t)BATCH*128*4);
    int*   tots   = (int*)take(2*64*4);
    float* accb   = (float*)take(64);
    size_t zero_small = off;
    // --- non-zeroed ---
    int*   ipd   = (int*)take((size_t)(NT+1)*4);
    int*   ips   = (int*)take((size_t)(NT+1)*4);
    int*   lst_d = (int*)take((size_t)ETOT*4);
    int*   lst_s = (int*)take((size_t)ETOT*4);
    // 16 MB region: xh -> r2/spre -> tbuf
    char*  reg16 = (char*)take((size_t)16*1024*1024);
    // 64 MB region: hist -> [aggbuf 32MB | zbuf 32MB]; agg2/s2 in first 16 MB
    char*  reg64 = (char*)take((size_t)64*1024*1024);
    // 8 MB region: y2h -> s2h
    char*  reg8  = (char*)take((size_t)8*1024*1024);
    float* hbuf  = (float*)take((size_t)BATCH*8192*4);
    float* aggo  = (float*)take((size_t)BATCH*8192*4);

    unsigned short* xh   = (unsigned short*)reg16;
    float*          r2   = (float*)reg16;          // spre in-place
    float*          tbuf = (float*)reg16;
    unsigned*       hist = (unsigned*)reg64;
    float*          aggbuf = (float*)reg64;        // NT*128 f32
    float*          zbuf   = (float*)(reg64 + (size_t)32*1024*1024);
    float*          agg2   = (float*)reg64;        // NT*64 f32 (after aggbuf dead)
    float*          s2     = (float*)reg64;        // NT*64 f32 (after agg2 dead)
    unsigned short* y2h  = (unsigned short*)reg8;
    unsigned short* s2h  = (unsigned short*)reg8;

    float* crossp = accb + 0;
    float* normgp = accb + 1;
    float* entp   = accb + 2;
    unsigned int* a2p = (unsigned int*)(accb + 3);

    hipMemsetAsync(d_ws, 0, zero_small, stream);
    hipMemsetAsync(hist, 0, (size_t)64*1024*1024, stream);

    // hist (sum a^2) + CSR degree counts in one edge pass; reg64 frees after sumsq
    k_hist<<<ETOT/256, 256, 0, stream>>>(src, dst, hist, cnt_d, cnt_s);
    k_sumsq<<<2048, 256, 0, stream>>>((const uint4*)hist, a2p);

    // x -> bf16
    k_castx<<<NT*128/4/256, 256, 0, stream>>>(x, xh, NT*128/4);

    // CSR build
    k_scan_local<<<dim3(64,2), 1024, 0, stream>>>(cnt_d, cnt_s, ipd, ips, tots);
    k_scan_add<<<dim3(64,2), 1024, 0, stream>>>(tots, ipd, ips);
    k_fill<<<ETOT/256, 256, 0, stream>>>(src, dst, ipd, ips, cur_d, cur_s, lst_d, lst_s);

    // SAGE layer 1: z = leaky(mean_agg(x)@W1l + b1l + x@W1r)
    k_aggh<64><<<NT/4, 256, 0, stream>>>(xh, ipd, lst_d, aggbuf, 1);
    k_gemm<<<dim3(NT/64, 2), 256, 0, stream>>>(aggbuf, x, W1l, W1r, b1l, zbuf, NT, 128, 128, 1, 1, 0);

    // SAGE layer 2 (GEMM-before-gather): y2 = z@W2l (bf16), r2 = z@W2r
    k_gemm<<<dim3(NT/64, 1), 256, 0, stream>>>(zbuf, nullptr, W2l, nullptr, nullptr, y2h, NT, 64, 128, 0, 0, 1);
    k_gemm<<<dim3(NT/64, 1), 256, 0, stream>>>(zbuf, nullptr, W2r, nullptr, nullptr, r2, NT, 64, 128, 0, 0, 0);
    k_aggh<32><<<NT/8, 256, 0, stream>>>(y2h, ipd, lst_d, agg2, 1);
    k_fin2<<<NT*16/256, 256, 0, stream>>>(agg2, r2, b2l);           // spre in r2
    k_gemm<<<dim3(NT/64, 1), 256, 0, stream>>>(r2, nullptr, Wm, nullptr, bm, s2, NT, 64, 64, 0, 0, 0);

    // softmax + entropy (+ bf16 copy of s)
    k_softmax_ent<<<NT/4, 256, 0, stream>>>(s2, s2h, entp);

    // t = A @ s
    k_aggh<32><<<NT/8, 256, 0, stream>>>(s2h, ips, lst_s, tbuf, 0);

    // pooled, adj_p + gram (fused), normg, cross = trace(adjp)
    k_pooled<<<BATCH*4, 256, 0, stream>>>(s2, zbuf, pooled);
    k_adjp2<<<BATCH*4, 256, 0, stream>>>(s2, tbuf, adjp, gram);
    k_gramsq<<<BATCH*4096/256, 256, 0, stream>>>(gram, normgp);
    k_trace<<<16, 256, 0, stream>>>(adjp, crossp);

    // head: A (agg), B (dual GEMM), C (split-K), D (logits)
    k_heada<<<dim3(BATCH, 4), 256, 0, stream>>>(adjp, pooled, aggo);
    k_gemm<<<dim3(BATCH*64/64, 2), 256, 0, stream>>>(aggo, pooled, Wrel, Wroot, broot, hbuf, BATCH*64, 128, 128, 1, 1, 0);
    k_head2<<<BATCH*16, 256, 0, stream>>>(hbuf, Wc1, hcacc);
    k_head3<<<BATCH, 128, 0, stream>>>(hcacc, bc1, Wc2, bc2, out);
    k_finalize<<<1, 1, 0, stream>>>(a2p, crossp, normgp, entp, out);
}

// Round 5
// 1141.101 us; speedup vs baseline: 3.0253x; 1.1879x over previous
//
#include <hip/hip_runtime.h>
#include <math.h>

#define BATCH 64
#define NPG 1024
#define NT (BATCH*NPG)        // 65536 nodes
#define EPER 32768
#define ETOT (BATCH*EPER)     // 2097152 edges

__device__ __forceinline__ float lky(float x){ return x > 0.f ? x : 0.01f*x; }
__device__ __forceinline__ unsigned short f2bf(float f){
    unsigned u = __float_as_uint(f);
    u = u + 0x7FFFu + ((u >> 16) & 1u);      // RNE
    return (unsigned short)(u >> 16);
}

// ---------------- fp32 -> bf16 cast (vectorized) ----------------
__global__ void k_castx(const float* __restrict__ in, unsigned short* __restrict__ out, int n4){
    int i = blockIdx.x*256 + threadIdx.x;
    if (i < n4){
        float4 v = ((const float4*)in)[i];
        ushort4 o = { f2bf(v.x), f2bf(v.y), f2bf(v.z), f2bf(v.w) };
        ((ushort4*)out)[i] = o;
    }
}

// ---------------- hist (sum(a^2) bytes) + CSR degree counts, one edge pass ----------------
__global__ void k_hist(const int* __restrict__ src, const int* __restrict__ dst,
                       unsigned* __restrict__ hist, int* cnt_d, int* cnt_s){
    int e = blockIdx.x*256 + threadIdx.x;
    if (e < ETOT){
        unsigned s = (unsigned)src[e], d = (unsigned)dst[e];
        unsigned b = s >> 10;
        unsigned key = (b << 20) | ((s & 1023u) << 10) | (d & 1023u);
        atomicAdd(&hist[key >> 2], 1u << ((key & 3u)*8));
        atomicAdd(&cnt_d[d], 1);
        atomicAdd(&cnt_s[s], 1);
    }
}

__device__ __forceinline__ unsigned sqbytes(unsigned w){
    unsigned s = 0;
    #pragma unroll
    for (int k = 0; k < 4; k++){ unsigned c = (w >> (8*k)) & 255u; s += c*c; }
    return s;
}

__global__ void k_sumsq(const uint4* __restrict__ hist, unsigned* __restrict__ acc_out){
    unsigned local = 0;
    for (size_t i = (size_t)blockIdx.x*256 + threadIdx.x; i < (size_t)4*1024*1024;
         i += (size_t)gridDim.x*256){
        uint4 w = hist[i];
        local += sqbytes(w.x) + sqbytes(w.y) + sqbytes(w.z) + sqbytes(w.w);
    }
    for (int o = 32; o; o >>= 1) local += __shfl_xor(local, o);
    __shared__ unsigned red[4];
    if ((threadIdx.x & 63) == 0) red[threadIdx.x >> 6] = local;
    __syncthreads();
    if (threadIdx.x == 0) atomicAdd(acc_out, red[0]+red[1]+red[2]+red[3]);
}

// ---------------- CSR scans + fill ----------------
__global__ void k_scan_local(const int* __restrict__ cnt_d, const int* __restrict__ cnt_s,
                             int* __restrict__ ipd, int* __restrict__ ips, int* __restrict__ tots){
    __shared__ int buf[1024];
    int which = blockIdx.y;
    const int* cnt = which ? cnt_s : cnt_d;
    int* ip = which ? ips : ipd;
    int base = blockIdx.x*1024;
    int tid = threadIdx.x;
    int v = cnt[base + tid];
    int x = v;
    buf[tid] = x; __syncthreads();
    for (int off = 1; off < 1024; off <<= 1){
        int t = (tid >= off) ? buf[tid - off] : 0;
        __syncthreads();
        x += t; buf[tid] = x; __syncthreads();
    }
    ip[base + tid] = x - v;                      // block-local exclusive
    if (tid == 1023) tots[which*64 + blockIdx.x] = x;
}

__global__ void k_scan_add(const int* __restrict__ tots, int* __restrict__ ipd, int* __restrict__ ips){
    int which = blockIdx.y;
    int* ip = which ? ips : ipd;
    const int* t = tots + which*64;
    __shared__ int soff;
    if (threadIdx.x == 0){
        int s = 0;
        for (int i = 0; i < (int)blockIdx.x; i++) s += t[i];
        soff = s;
    }
    __syncthreads();
    ip[blockIdx.x*1024 + threadIdx.x] += soff;
    if (blockIdx.x == 0 && threadIdx.x == 0) ip[NT] = ETOT;
}

__global__ void k_fill(const int* __restrict__ src, const int* __restrict__ dst,
                       const int* __restrict__ ipd, const int* __restrict__ ips,
                       int* cur_d, int* cur_s, int* lst_d, int* lst_s){
    int e = blockIdx.x*256 + threadIdx.x;
    if (e < ETOT){
        int s = src[e], d = dst[e];
        int p = atomicAdd(&cur_d[d], 1); lst_d[ipd[d] + p] = s;
        int q = atomicAdd(&cur_s[s], 1); lst_s[ips[s] + q] = d;
    }
}

// ---------------- bf16 segment gather (G threads per node, 2 feats/thread) ----------------
template<int G>
__global__ void k_aggh(const unsigned short* __restrict__ X, const int* __restrict__ indptr,
                       const int* __restrict__ lst, float* __restrict__ out, int do_mean){
    int node = blockIdx.x*(256/G) + threadIdx.x/G;
    int g = threadIdx.x % G;
    int st = indptr[node], en = indptr[node+1];
    float a0 = 0.f, a1 = 0.f;
    for (int e = st; e < en; e++){
        int nb = lst[e];
        unsigned v = *(const unsigned*)&X[(size_t)nb*(2*G) + 2*g];
        a0 += __uint_as_float((v & 0xFFFFu) << 16);
        a1 += __uint_as_float(v & 0xFFFF0000u);
    }
    if (do_mean){
        int dg = en - st;
        float inv = 1.f/(float)(dg > 1 ? dg : 1);
        a0 *= inv; a1 *= inv;
    }
    out[(size_t)node*(2*G) + 2*g]     = a0;
    out[(size_t)node*(2*G) + 2*g + 1] = a1;
}

// ---------------- fused dual GEMM: C = act(A1@W1 [+ A2@W2] + bias), optional bf16 out ----------------
__global__ void __launch_bounds__(256) k_gemm(
        const float* __restrict__ A1, const float* __restrict__ A2,
        const float* __restrict__ W1, const float* __restrict__ W2,
        const float* __restrict__ bias, void* __restrict__ C,
        int M, int Nn, int Kd, int dual, int act, int obf){
    __shared__ float sA1[16*68], sB1[16*68], sA2[16*68], sB2[16*68];
    int tid = threadIdx.x;
    int m0 = blockIdx.x*64, n0 = blockIdx.y*64;
    int tx = tid & 15, ty = tid >> 4;
    int lr = tid >> 2, lk = (tid & 3)*4;
    int wk = tid >> 4, wn = (tid & 15)*4;
    float acc[4][4] = {};
    for (int k0 = 0; k0 < Kd; k0 += 16){
        float4 a1 = *(const float4*)&A1[(size_t)(m0+lr)*Kd + k0 + lk];
        float4 w1 = *(const float4*)&W1[(size_t)(k0+wk)*Nn + n0 + wn];
        sA1[(lk+0)*68+lr] = a1.x; sA1[(lk+1)*68+lr] = a1.y;
        sA1[(lk+2)*68+lr] = a1.z; sA1[(lk+3)*68+lr] = a1.w;
        *(float4*)&sB1[wk*68+wn] = w1;
        if (dual){
            float4 a2 = *(const float4*)&A2[(size_t)(m0+lr)*Kd + k0 + lk];
            float4 w2 = *(const float4*)&W2[(size_t)(k0+wk)*Nn + n0 + wn];
            sA2[(lk+0)*68+lr] = a2.x; sA2[(lk+1)*68+lr] = a2.y;
            sA2[(lk+2)*68+lr] = a2.z; sA2[(lk+3)*68+lr] = a2.w;
            *(float4*)&sB2[wk*68+wn] = w2;
        }
        __syncthreads();
        #pragma unroll
        for (int kk = 0; kk < 16; kk++){
            float4 av = *(const float4*)&sA1[kk*68 + ty*4];
            float4 bv = *(const float4*)&sB1[kk*68 + tx*4];
            float a[4] = {av.x, av.y, av.z, av.w};
            float b[4] = {bv.x, bv.y, bv.z, bv.w};
            #pragma unroll
            for (int i = 0; i < 4; i++)
                #pragma unroll
                for (int j = 0; j < 4; j++) acc[i][j] += a[i]*b[j];
            if (dual){
                float4 av2 = *(const float4*)&sA2[kk*68 + ty*4];
                float4 bv2 = *(const float4*)&sB2[kk*68 + tx*4];
                float a2[4] = {av2.x, av2.y, av2.z, av2.w};
                float b2[4] = {bv2.x, bv2.y, bv2.z, bv2.w};
                #pragma unroll
                for (int i = 0; i < 4; i++)
                    #pragma unroll
                    for (int j = 0; j < 4; j++) acc[i][j] += a2[i]*b2[j];
            }
        }
        __syncthreads();
    }
    float bb[4] = {0.f, 0.f, 0.f, 0.f};
    if (bias){
        #pragma unroll
        for (int j = 0; j < 4; j++) bb[j] = bias[n0 + tx*4 + j];
    }
    #pragma unroll
    for (int i = 0; i < 4; i++){
        float v0 = acc[i][0]+bb[0], v1 = acc[i][1]+bb[1], v2 = acc[i][2]+bb[2], v3 = acc[i][3]+bb[3];
        if (act){ v0 = lky(v0); v1 = lky(v1); v2 = lky(v2); v3 = lky(v3); }
        size_t idx = (size_t)(m0 + ty*4 + i)*Nn + n0 + tx*4;
        if (obf){
            ushort4 o = { f2bf(v0), f2bf(v1), f2bf(v2), f2bf(v3) };
            *(ushort4*)&((unsigned short*)C)[idx] = o;
        } else {
            float4 o = { v0, v1, v2, v3 };
            *(float4*)&((float*)C)[idx] = o;
        }
    }
}

// ---------------- dual-B GEMM: one A pass, two outputs: C1 = A@W1 (bf16), C2 = A@W2 (f32) ----------------
// M x 64 outputs, Kd = 128
__global__ void __launch_bounds__(256) k_gemm2b(
        const float* __restrict__ A, const float* __restrict__ W1,
        const float* __restrict__ W2, unsigned short* __restrict__ C1,
        float* __restrict__ C2, int Kd){
    __shared__ float sA[16*68], sB1[16*68], sB2[16*68];
    int tid = threadIdx.x;
    int m0 = blockIdx.x*64;
    int tx = tid & 15, ty = tid >> 4;
    int lr = tid >> 2, lk = (tid & 3)*4;
    int wk = tid >> 4, wn = (tid & 15)*4;
    float acc1[4][4] = {}, acc2[4][4] = {};
    for (int k0 = 0; k0 < Kd; k0 += 16){
        float4 a = *(const float4*)&A[(size_t)(m0+lr)*Kd + k0 + lk];
        sA[(lk+0)*68+lr] = a.x; sA[(lk+1)*68+lr] = a.y;
        sA[(lk+2)*68+lr] = a.z; sA[(lk+3)*68+lr] = a.w;
        *(float4*)&sB1[wk*68+wn] = *(const float4*)&W1[(size_t)(k0+wk)*64 + wn];
        *(float4*)&sB2[wk*68+wn] = *(const float4*)&W2[(size_t)(k0+wk)*64 + wn];
        __syncthreads();
        #pragma unroll
        for (int kk = 0; kk < 16; kk++){
            float4 av = *(const float4*)&sA[kk*68 + ty*4];
            float4 b1 = *(const float4*)&sB1[kk*68 + tx*4];
            float4 b2 = *(const float4*)&sB2[kk*68 + tx*4];
            float a4[4] = {av.x, av.y, av.z, av.w};
            float v1[4] = {b1.x, b1.y, b1.z, b1.w};
            float v2[4] = {b2.x, b2.y, b2.z, b2.w};
            #pragma unroll
            for (int i = 0; i < 4; i++)
                #pragma unroll
                for (int j = 0; j < 4; j++){
                    acc1[i][j] += a4[i]*v1[j];
                    acc2[i][j] += a4[i]*v2[j];
                }
        }
        __syncthreads();
    }
    #pragma unroll
    for (int i = 0; i < 4; i++){
        size_t idx = (size_t)(m0 + ty*4 + i)*64 + tx*4;
        ushort4 o1 = { f2bf(acc1[i][0]), f2bf(acc1[i][1]), f2bf(acc1[i][2]), f2bf(acc1[i][3]) };
        *(ushort4*)&C1[idx] = o1;
        float4 o2 = { acc2[i][0], acc2[i][1], acc2[i][2], acc2[i][3] };
        *(float4*)&C2[idx] = o2;
    }
}

// ---------------- fused: spre = lky(agg2 + r2 + b2l); s = softmax(spre@Wm + bm); ent ----------------
// M x 64, Kd = 64; one block = 64 full rows -> row softmax in epilogue
__global__ void __launch_bounds__(256) k_gemm_wm(
        const float* __restrict__ agg2, const float* __restrict__ r2,
        const float* __restrict__ b2l, const float* __restrict__ Wm,
        const float* __restrict__ bm, float* __restrict__ S,
        unsigned short* __restrict__ Sh, float* __restrict__ ent_acc){
    __shared__ float sA[16*68], sB[16*68];
    __shared__ float red[256];
    int tid = threadIdx.x;
    int m0 = blockIdx.x*64;
    int tx = tid & 15, ty = tid >> 4;
    int lr = tid >> 2, lk = (tid & 3)*4;
    int wk = tid >> 4, wn = (tid & 15)*4;
    float acc[4][4] = {};
    for (int k0 = 0; k0 < 64; k0 += 16){
        float4 a = *(const float4*)&agg2[(size_t)(m0+lr)*64 + k0 + lk];
        float4 r = *(const float4*)&r2[(size_t)(m0+lr)*64 + k0 + lk];
        sA[(lk+0)*68+lr] = lky(a.x + r.x + b2l[k0+lk+0]);
        sA[(lk+1)*68+lr] = lky(a.y + r.y + b2l[k0+lk+1]);
        sA[(lk+2)*68+lr] = lky(a.z + r.z + b2l[k0+lk+2]);
        sA[(lk+3)*68+lr] = lky(a.w + r.w + b2l[k0+lk+3]);
        *(float4*)&sB[wk*68+wn] = *(const float4*)&Wm[(size_t)(k0+wk)*64 + wn];
        __syncthreads();
        #pragma unroll
        for (int kk = 0; kk < 16; kk++){
            float4 av = *(const float4*)&sA[kk*68 + ty*4];
            float4 bv = *(const float4*)&sB[kk*68 + tx*4];
            float a4[4] = {av.x, av.y, av.z, av.w};
            float b4[4] = {bv.x, bv.y, bv.z, bv.w};
            #pragma unroll
            for (int i = 0; i < 4; i++)
                #pragma unroll
                for (int j = 0; j < 4; j++) acc[i][j] += a4[i]*b4[j];
        }
        __syncthreads();
    }
    float bb[4];
    #pragma unroll
    for (int j = 0; j < 4; j++) bb[j] = bm[tx*4 + j];
    float ent_local = 0.f;
    #pragma unroll
    for (int i = 0; i < 4; i++){
        float v[4];
        #pragma unroll
        for (int j = 0; j < 4; j++) v[j] = acc[i][j] + bb[j];
        // row max across the 16-lane tx group (lanes of same ty are contiguous)
        float m = fmaxf(fmaxf(v[0], v[1]), fmaxf(v[2], v[3]));
        for (int o = 1; o < 16; o <<= 1) m = fmaxf(m, __shfl_xor(m, o));
        float e[4];
        float sm = 0.f;
        #pragma unroll
        for (int j = 0; j < 4; j++){ e[j] = __expf(v[j] - m); sm += e[j]; }
        for (int o = 1; o < 16; o <<= 1) sm += __shfl_xor(sm, o);
        float inv = 1.f/sm;
        float p[4];
        float w = 0.f;
        #pragma unroll
        for (int j = 0; j < 4; j++){
            p[j] = e[j]*inv;
            w += -p[j]*__logf(p[j] + 1e-15f);
        }
        for (int o = 1; o < 16; o <<= 1) w += __shfl_xor(w, o);
        if (tx == 0) ent_local += w;
        size_t idx = (size_t)(m0 + ty*4 + i)*64 + tx*4;
        float4 of = { p[0], p[1], p[2], p[3] };
        *(float4*)&S[idx] = of;
        ushort4 oh = { f2bf(p[0]), f2bf(p[1]), f2bf(p[2]), f2bf(p[3]) };
        *(ushort4*)&Sh[idx] = oh;
    }
    red[tid] = ent_local; __syncthreads();
    for (int o = 128; o; o >>= 1){ if (tid < o) red[tid] += red[tid+o]; __syncthreads(); }
    if (tid == 0) atomicAdd(ent_acc, red[0]);
}

// ---------------- pooled[b] = s[b]^T z[b], 4-way n-split ----------------
__global__ void k_pooled(const float* __restrict__ S, const float* __restrict__ Z,
                         float* __restrict__ P){
    __shared__ float sS[8*64], sZ[8*128];
    int b = blockIdx.x >> 2, part = blockIdx.x & 3;
    int tid = threadIdx.x;
    int kk = (tid & 31)*2, fg = tid >> 5;
    float acc[2][16] = {};
    int nbase = b*NPG + part*256;
    for (int n0 = 0; n0 < 256; n0 += 8){
        for (int i = tid; i < 512; i += 256){ int r = i >> 6, c = i & 63; sS[i] = S[(size_t)(nbase+n0+r)*64 + c]; }
        for (int i = tid; i < 1024; i += 256){ int r = i >> 7, c = i & 127; sZ[i] = Z[(size_t)(nbase+n0+r)*128 + c]; }
        __syncthreads();
        for (int nn = 0; nn < 8; nn++){
            float a0 = sS[nn*64+kk], a1 = sS[nn*64+kk+1];
            #pragma unroll
            for (int j = 0; j < 16; j++){
                float zz = sZ[nn*128 + fg*16 + j];
                acc[0][j] += a0*zz; acc[1][j] += a1*zz;
            }
        }
        __syncthreads();
    }
    for (int c = 0; c < 2; c++)
        for (int j = 0; j < 16; j++)
            atomicAdd(&P[((size_t)b*64 + kk + c)*128 + fg*16 + j], acc[c][j]);
}

// ---------------- AP[b] += s^T t AND GR[b] += s^T s in one pass ----------------
__global__ void k_adjp2(const float* __restrict__ S, const float* __restrict__ T,
                        float* __restrict__ AP, float* __restrict__ GR){
    __shared__ float sS[8*64], sT[8*64];
    int b = blockIdx.x >> 2, part = blockIdx.x & 3;
    int tid = threadIdx.x;
    int kk = (tid & 31)*2, lg = tid >> 5;
    float acc[2][8] = {};
    float acg[2][8] = {};
    int nbase = b*NPG + part*256;
    for (int n0 = 0; n0 < 256; n0 += 8){
        for (int i = tid; i < 512; i += 256){
            int r = i >> 6, c = i & 63;
            sS[i] = S[(size_t)(nbase+n0+r)*64 + c];
            sT[i] = T[(size_t)(nbase+n0+r)*64 + c];
        }
        __syncthreads();
        for (int nn = 0; nn < 8; nn++){
            float a0 = sS[nn*64+kk], a1 = sS[nn*64+kk+1];
            #pragma unroll
            for (int j = 0; j < 8; j++){
                float tt = sT[nn*64 + lg*8 + j];
                float ss = sS[nn*64 + lg*8 + j];
                acc[0][j] += a0*tt; acc[1][j] += a1*tt;
                acg[0][j] += a0*ss; acg[1][j] += a1*ss;
            }
        }
        __syncthreads();
    }
    for (int c = 0; c < 2; c++)
        for (int j = 0; j < 8; j++){
            atomicAdd(&AP[((size_t)b*64 + kk + c)*64 + lg*8 + j], acc[c][j]);
            atomicAdd(&GR[((size_t)b*64 + kk + c)*64 + lg*8 + j], acg[c][j]);
        }
}

// ---------------- sum of squares of gram ----------------
__global__ void k_gramsq(const float* __restrict__ gram, float* __restrict__ acc_out){
    int i = blockIdx.x*256 + threadIdx.x;
    float v = gram[i];
    float s = v*v;
    for (int o = 32; o; o >>= 1) s += __shfl_xor(s, o);
    __shared__ float red[4];
    if ((threadIdx.x & 63) == 0) red[threadIdx.x >> 6] = s;
    __syncthreads();
    if (threadIdx.x == 0) atomicAdd(acc_out, red[0]+red[1]+red[2]+red[3]);
}

// ---------------- cross = sum_b trace(adjp[b]) ----------------
__global__ void k_trace(const float* __restrict__ AP, float* __restrict__ acc_out){
    int i = blockIdx.x*256 + threadIdx.x;      // 4096 diag entries
    float s = AP[(size_t)(i >> 6)*4096 + (i & 63)*65];
    for (int o = 32; o; o >>= 1) s += __shfl_xor(s, o);
    __shared__ float red[4];
    if ((threadIdx.x & 63) == 0) red[threadIdx.x >> 6] = s;
    __syncthreads();
    if (threadIdx.x == 0) atomicAdd(acc_out, red[0]+red[1]+red[2]+red[3]);
}

// ---------------- head stage A: aggout[b] = (adjp[b] @ pooled[b]) / rowsum ----------------
__global__ void __launch_bounds__(256) k_heada(
        const float* __restrict__ AP, const float* __restrict__ P,
        float* __restrict__ aggout){
    __shared__ float sapT[64*65];   // transposed adjp, padded
    __shared__ float sp[64*33];     // pooled column chunk
    __shared__ float srs[64];
    int b = blockIdx.x, c0 = blockIdx.y*32;
    int tid = threadIdx.x;
    for (int i = tid; i < 4096; i += 256){
        int k = i >> 6, l = i & 63;
        sapT[l*65 + k] = AP[(size_t)b*4096 + i];
    }
    for (int i = tid; i < 2048; i += 256){
        int l = i >> 5, j = i & 31;
        sp[l*33 + j] = P[(size_t)b*8192 + l*128 + c0 + j];
    }
    __syncthreads();
    if (tid < 64){
        float s = 0.f;
        for (int l = 0; l < 64; l++) s += sapT[l*65 + tid];
        srs[tid] = fmaxf(s, 1.f);
    }
    __syncthreads();
    int k = tid & 63, jg = (tid >> 6)*8;
    float acc[8] = {};
    for (int l = 0; l < 64; l++){
        float a = sapT[l*65 + k];
        #pragma unroll
        for (int j = 0; j < 8; j++) acc[j] += a*sp[l*33 + jg + j];
    }
    float inv = 1.f/srs[k];
    #pragma unroll
    for (int j = 0; j < 8; j++)
        aggout[(size_t)b*8192 + k*128 + c0 + jg + j] = acc[j]*inv;
}

// ---------------- head stage C: hcacc[b,:] += h[b, chunk] @ Wc1[chunk, :] ----------------
__global__ void __launch_bounds__(256) k_head2(
        const float* __restrict__ hbuf, const float* __restrict__ Wc1,
        float* __restrict__ hcacc){
    __shared__ float sh[512];
    __shared__ float sred[256];
    int b = blockIdx.x >> 4, ch = blockIdx.x & 15;
    int tid = threadIdx.x;
    for (int i = tid; i < 512; i += 256) sh[i] = hbuf[(size_t)b*8192 + ch*512 + i];
    __syncthreads();
    int j = tid & 127, half = tid >> 7;
    float acc = 0.f;
    const float* W = Wc1 + (size_t)(ch*512 + half*256)*128;
    const float* hh = sh + half*256;
    for (int r = 0; r < 256; r++) acc += hh[r]*W[(size_t)r*128 + j];
    sred[tid] = acc; __syncthreads();
    if (tid < 128) atomicAdd(&hcacc[(size_t)b*128 + tid], sred[tid] + sred[tid+128]);
}

// ---------------- head stage D: logits ----------------
__global__ void k_head3(const float* __restrict__ hcacc, const float* __restrict__ bc1,
                        const float* __restrict__ Wc2, const float* __restrict__ bc2,
                        float* __restrict__ out){
    int b = blockIdx.x, t = threadIdx.x;   // 128 threads
    float hc = lky(hcacc[(size_t)b*128 + t] + bc1[t]);
    float p = hc*Wc2[t];
    for (int o = 32; o; o >>= 1) p += __shfl_xor(p, o);
    __shared__ float r2[2];
    if ((t & 63) == 0) r2[t >> 6] = p;
    __syncthreads();
    if (t == 0) out[b] = r2[0] + r2[1] + bc2[0];
}

__global__ void k_finalize(const unsigned int* __restrict__ a2,
                           const float* __restrict__ cross,
                           const float* __restrict__ normg,
                           const float* __restrict__ ent,
                           float* __restrict__ out){
    float ss = (float)(*a2) - 2.f*(*cross) + (*normg);
    if (ss < 0.f) ss = 0.f;
    float link = sqrtf(ss) / 67108864.f;     // a.size
    out[64] = link + (*ent)/(float)NT;
}

extern "C" void kernel_launch(void* const* d_in, const int* in_sizes, int n_in,
                              void* d_out, int out_size, void* d_ws, size_t ws_size,
                              hipStream_t stream){
    const float* x    = (const float*)d_in[0];
    const int*   ei   = (const int*)d_in[1];
    const int*   src  = ei;
    const int*   dst  = ei + ETOT;
    const float* W1l  = (const float*)d_in[5];
    const float* b1l  = (const float*)d_in[6];
    const float* W1r  = (const float*)d_in[7];
    const float* W2l  = (const float*)d_in[8];
    const float* b2l  = (const float*)d_in[9];
    const float* W2r  = (const float*)d_in[10];
    const float* Wm   = (const float*)d_in[11];
    const float* bm   = (const float*)d_in[12];
    const float* Wrel = (const float*)d_in[13];
    const float* Wroot= (const float*)d_in[14];
    const float* broot= (const float*)d_in[15];
    const float* Wc1  = (const float*)d_in[16];
    const float* bc1  = (const float*)d_in[17];
    const float* Wc2  = (const float*)d_in[18];
    const float* bc2  = (const float*)d_in[19];
    float* out = (float*)d_out;

    char* w = (char*)d_ws;
    size_t off = 0;
    auto take = [&](size_t bytes)->void*{
        void* p = w + off; off = (off + bytes + 255) & ~(size_t)255; return p;
    };
    // --- small zeroed zone ---
    int*   cnt_d  = (int*)take((size_t)NT*4);
    int*   cnt_s  = (int*)take((size_t)NT*4);
    int*   cur_d  = (int*)take((size_t)NT*4);
    int*   cur_s  = (int*)take((size_t)NT*4);
    float* pooled = (float*)take((size_t)BATCH*64*128*4);
    float* adjp   = (float*)take((size_t)BATCH*64*64*4);
    float* gram   = (float*)take((size_t)BATCH*64*64*4);
    float* hcacc  = (float*)take((size_t)BATCH*128*4);
    int*   tots   = (int*)take(2*64*4);
    float* accb   = (float*)take(64);
    size_t zero_small = off;
    // --- non-zeroed ---
    int*   ipd   = (int*)take((size_t)(NT+1)*4);
    int*   ips   = (int*)take((size_t)(NT+1)*4);
    int*   lst_d = (int*)take((size_t)ETOT*4);
    int*   lst_s = (int*)take((size_t)ETOT*4);
    // 16 MB region: xh -> r2/spre -> tbuf
    char*  reg16 = (char*)take((size_t)16*1024*1024);
    // 64 MB region: hist -> [aggbuf 32MB | zbuf 32MB]; then agg2 (0..16M), s2 (16..32M)
    char*  reg64 = (char*)take((size_t)64*1024*1024);
    // 8 MB region: y2h -> s2h
    char*  reg8  = (char*)take((size_t)8*1024*1024);
    float* hbuf  = (float*)take((size_t)BATCH*8192*4);
    float* aggo  = (float*)take((size_t)BATCH*8192*4);

    unsigned short* xh   = (unsigned short*)reg16;
    float*          r2   = (float*)reg16;
    float*          tbuf = (float*)reg16;
    unsigned*       hist = (unsigned*)reg64;
    float*          aggbuf = (float*)reg64;                          // NT*128 f32
    float*          zbuf   = (float*)(reg64 + (size_t)32*1024*1024); // NT*128 f32
    float*          agg2   = (float*)reg64;                          // NT*64 (first 16MB)
    float*          s2     = (float*)(reg64 + (size_t)16*1024*1024); // NT*64 (16..32MB)
    unsigned short* y2h  = (unsigned short*)reg8;
    unsigned short* s2h  = (unsigned short*)reg8;

    float* crossp = accb + 0;
    float* normgp = accb + 1;
    float* entp   = accb + 2;
    unsigned int* a2p = (unsigned int*)(accb + 3);

    hipMemsetAsync(d_ws, 0, zero_small, stream);
    hipMemsetAsync(hist, 0, (size_t)64*1024*1024, stream);

    // hist (sum a^2) + CSR degree counts in one edge pass; reg64 frees after sumsq
    k_hist<<<ETOT/256, 256, 0, stream>>>(src, dst, hist, cnt_d, cnt_s);
    k_sumsq<<<2048, 256, 0, stream>>>((const uint4*)hist, a2p);

    // x -> bf16
    k_castx<<<NT*128/4/256, 256, 0, stream>>>(x, xh, NT*128/4);

    // CSR build
    k_scan_local<<<dim3(64,2), 1024, 0, stream>>>(cnt_d, cnt_s, ipd, ips, tots);
    k_scan_add<<<dim3(64,2), 1024, 0, stream>>>(tots, ipd, ips);
    k_fill<<<ETOT/256, 256, 0, stream>>>(src, dst, ipd, ips, cur_d, cur_s, lst_d, lst_s);

    // SAGE layer 1: z = leaky(mean_agg(x)@W1l + b1l + x@W1r)
    k_aggh<64><<<NT/4, 256, 0, stream>>>(xh, ipd, lst_d, aggbuf, 1);
    k_gemm<<<dim3(NT/64, 2), 256, 0, stream>>>(aggbuf, x, W1l, W1r, b1l, zbuf, NT, 128, 128, 1, 1, 0);

    // SAGE layer 2 (GEMM-before-gather, dual-B single pass): y2h = z@W2l (bf16), r2 = z@W2r (f32)
    k_gemm2b<<<NT/64, 256, 0, stream>>>(zbuf, W2l, W2r, y2h, r2, 128);
    k_aggh<32><<<NT/8, 256, 0, stream>>>(y2h, ipd, lst_d, agg2, 1);
    // fused: spre = lky(agg2+r2+b2l); s2 = softmax(spre@Wm+bm); ent; s2h bf16
    k_gemm_wm<<<NT/64, 256, 0, stream>>>(agg2, r2, b2l, Wm, bm, s2, s2h, entp);

    // t = A @ s
    k_aggh<32><<<NT/8, 256, 0, stream>>>(s2h, ips, lst_s, tbuf, 0);

    // pooled, adj_p + gram (fused), normg, cross = trace(adjp)
    k_pooled<<<BATCH*4, 256, 0, stream>>>(s2, zbuf, pooled);
    k_adjp2<<<BATCH*4, 256, 0, stream>>>(s2, tbuf, adjp, gram);
    k_gramsq<<<BATCH*4096/256, 256, 0, stream>>>(gram, normgp);
    k_trace<<<16, 256, 0, stream>>>(adjp, crossp);

    // head: A (agg), B (dual GEMM), C (split-K), D (logits)
    k_heada<<<dim3(BATCH, 4), 256, 0, stream>>>(adjp, pooled, aggo);
    k_gemm<<<dim3(BATCH*64/64, 2), 256, 0, stream>>>(aggo, pooled, Wrel, Wroot, broot, hbuf, BATCH*64, 128, 128, 1, 1, 0);
    k_head2<<<BATCH*16, 256, 0, stream>>>(hbuf, Wc1, hcacc);
    k_head3<<<BATCH, 128, 0, stream>>>(hcacc, bc1, Wc2, bc2, out);
    k_finalize<<<1, 1, 0, stream>>>(a2p, crossp, normgp, entp, out);
}

// Round 6
// 973.885 us; speedup vs baseline: 3.5447x; 1.1717x over previous
//
#include <hip/hip_runtime.h>
#include <math.h>

#define BATCH 64
#define NPG 1024
#define NT (BATCH*NPG)        // 65536 nodes
#define EPER 32768
#define ETOT (BATCH*EPER)     // 2097152 edges

typedef __attribute__((ext_vector_type(4))) float f32x4;
typedef __attribute__((ext_vector_type(8))) short s16x8;

__device__ __forceinline__ float lky(float x){ return x > 0.f ? x : 0.01f*x; }
__device__ __forceinline__ unsigned short f2bf(float f){
    unsigned u = __float_as_uint(f);
    u = u + 0x7FFFu + ((u >> 16) & 1u);      // RNE
    return (unsigned short)(u >> 16);
}
__device__ __forceinline__ float bf2f_lo(unsigned v){ return __uint_as_float(v << 16); }
__device__ __forceinline__ float bf2f_hi(unsigned v){ return __uint_as_float(v & 0xFFFF0000u); }

// ---------------- sum(a^2) via per-graph LDS nibble histogram (+ degree counts on pass 0) ----------------
__global__ void __launch_bounds__(1024) k_a2lds(const int* __restrict__ src, const int* __restrict__ dst,
                                                unsigned* __restrict__ acc_out, int* cnt_d, int* cnt_s){
    __shared__ unsigned nib[32768];   // 128 KB = 262144 nibble counters
    __shared__ unsigned red[16];
    int b = blockIdx.x, pass = blockIdx.y, tid = threadIdx.x;
    for (int i = tid; i < 32768; i += 1024) nib[i] = 0;
    __syncthreads();
    int base = b*EPER;
    for (int i = tid; i < EPER; i += 1024){
        int sv = src[base+i], dv = dst[base+i];
        if (pass == 0){ atomicAdd(&cnt_d[dv], 1); atomicAdd(&cnt_s[sv], 1); }
        unsigned key = (((unsigned)sv & 1023u) << 10) | ((unsigned)dv & 1023u);
        if ((int)(key >> 18) == pass)
            atomicAdd(&nib[(key & 0x3FFFFu) >> 3], 1u << ((key & 7u)*4u));
    }
    __syncthreads();
    unsigned local = 0;
    for (int i = tid; i < 32768; i += 1024){
        unsigned w = nib[i];
        if (w){
            #pragma unroll
            for (int q = 0; q < 8; q++){ unsigned c = (w >> (4*q)) & 15u; local += c*c; }
        }
    }
    for (int o = 32; o; o >>= 1) local += __shfl_xor(local, o);
    if ((tid & 63) == 0) red[tid >> 6] = local;
    __syncthreads();
    if (tid == 0){
        unsigned s = 0;
        for (int q = 0; q < 16; q++) s += red[q];
        atomicAdd(acc_out, s);
    }
}

// ---------------- CSR scans + fill ----------------
__global__ void k_scan_local(const int* __restrict__ cnt_d, const int* __restrict__ cnt_s,
                             int* __restrict__ ipd, int* __restrict__ ips, int* __restrict__ tots){
    __shared__ int buf[1024];
    int which = blockIdx.y;
    const int* cnt = which ? cnt_s : cnt_d;
    int* ip = which ? ips : ipd;
    int base = blockIdx.x*1024;
    int tid = threadIdx.x;
    int v = cnt[base + tid];
    int x = v;
    buf[tid] = x; __syncthreads();
    for (int off = 1; off < 1024; off <<= 1){
        int t = (tid >= off) ? buf[tid - off] : 0;
        __syncthreads();
        x += t; buf[tid] = x; __syncthreads();
    }
    ip[base + tid] = x - v;
    if (tid == 1023) tots[which*64 + blockIdx.x] = x;
}

__global__ void k_scan_add(const int* __restrict__ tots, int* __restrict__ ipd, int* __restrict__ ips){
    int which = blockIdx.y;
    int* ip = which ? ips : ipd;
    const int* t = tots + which*64;
    __shared__ int soff;
    if (threadIdx.x == 0){
        int s = 0;
        for (int i = 0; i < (int)blockIdx.x; i++) s += t[i];
        soff = s;
    }
    __syncthreads();
    ip[blockIdx.x*1024 + threadIdx.x] += soff;
    if (blockIdx.x == 0 && threadIdx.x == 0) ip[NT] = ETOT;
}

__global__ void k_fill(const int* __restrict__ src, const int* __restrict__ dst,
                       const int* __restrict__ ipd, const int* __restrict__ ips,
                       int* cur_d, int* cur_s, int* lst_d, int* lst_s){
    int e = blockIdx.x*256 + threadIdx.x;
    if (e < ETOT){
        int s = src[e], d = dst[e];
        int p = atomicAdd(&cur_d[d], 1); lst_d[ipd[d] + p] = s;
        int q = atomicAdd(&cur_s[s], 1); lst_s[ips[s] + q] = d;
    }
}

// ---------------- bf16 segment gather (G threads per node, 2 feats/thread) ----------------
template<int G, int OBF>
__global__ void k_aggh(const unsigned short* __restrict__ X, const int* __restrict__ indptr,
                       const int* __restrict__ lst, void* __restrict__ out, int do_mean){
    int node = blockIdx.x*(256/G) + threadIdx.x/G;
    int g = threadIdx.x % G;
    int st = indptr[node], en = indptr[node+1];
    float a0 = 0.f, a1 = 0.f;
    for (int e = st; e < en; e++){
        int nb = lst[e];
        unsigned v = *(const unsigned*)&X[(size_t)nb*(2*G) + 2*g];
        a0 += bf2f_lo(v);
        a1 += bf2f_hi(v);
    }
    if (do_mean){
        int dg = en - st;
        float inv = 1.f/(float)(dg > 1 ? dg : 1);
        a0 *= inv; a1 *= inv;
    }
    if (OBF){
        unsigned pk = (unsigned)f2bf(a0) | ((unsigned)f2bf(a1) << 16);
        ((unsigned*)out)[(size_t)node*G + g] = pk;
    } else {
        ((float*)out)[(size_t)node*(2*G) + 2*g]     = a0;
        ((float*)out)[(size_t)node*(2*G) + 2*g + 1] = a1;
    }
}

// ---------------- MFMA dual-B GEMM: C1 = A@W1 (bf16), C2 = A@W2 (bf16 or f32); K=128 ----------------
// A: [M][128] bf16 (or f32 cast inline when AF32). Weights f32 [128][N] cast->bf16, staged in
// XOR-swizzled LDS as B^T [n][k]. Block 256 thr = 4 waves, 64 rows/block, full N per block.
template<int N, int AF32, int OBF2>
__global__ void __launch_bounds__(256) k_mfma2b(
        const void* __restrict__ Ain, const float* __restrict__ W1,
        const float* __restrict__ W2, unsigned short* __restrict__ C1,
        void* __restrict__ C2){
    __shared__ unsigned short ldsB[2*N*128];
    int tid = threadIdx.x;
    for (int i = tid; i < 128*N; i += 256){
        int k = i / N, n = i - k*N;
        int swz = (n*256 + 2*k) ^ ((n & 7) << 4);
        *(unsigned short*)((char*)ldsB + swz)          = f2bf(W1[i]);
        *(unsigned short*)((char*)ldsB + N*256 + swz)  = f2bf(W2[i]);
    }
    __syncthreads();
    int wave = tid >> 6, l = tid & 63;
    int lr = l & 15, lg = l >> 4;
    int arow = blockIdx.x*64 + wave*16 + lr;
    constexpr int NF = N/16;
    f32x4 acc1[NF], acc2[NF];
    f32x4 zv = {0.f, 0.f, 0.f, 0.f};
    #pragma unroll
    for (int nf = 0; nf < NF; nf++){ acc1[nf] = zv; acc2[nf] = zv; }
    const unsigned short* Ah = (const unsigned short*)Ain;
    const float* Af = (const float*)Ain;
    #pragma unroll
    for (int ks = 0; ks < 4; ks++){
        s16x8 af;
        if (AF32){
            const float* p = Af + (size_t)arow*128 + ks*32 + lg*8;
            float4 v0 = *(const float4*)p;
            float4 v1 = *(const float4*)(p + 4);
            af[0] = (short)f2bf(v0.x); af[1] = (short)f2bf(v0.y);
            af[2] = (short)f2bf(v0.z); af[3] = (short)f2bf(v0.w);
            af[4] = (short)f2bf(v1.x); af[5] = (short)f2bf(v1.y);
            af[6] = (short)f2bf(v1.z); af[7] = (short)f2bf(v1.w);
        } else {
            af = *(const s16x8*)(Ah + (size_t)arow*128 + ks*32 + lg*8);
        }
        #pragma unroll
        for (int nf = 0; nf < NF; nf++){
            int n = nf*16 + lr;
            int swz = (n*256 + ks*64 + lg*16) ^ ((n & 7) << 4);
            s16x8 b1 = *(const s16x8*)((const char*)ldsB + swz);
            s16x8 b2 = *(const s16x8*)((const char*)ldsB + N*256 + swz);
            acc1[nf] = __builtin_amdgcn_mfma_f32_16x16x32_bf16(af, b1, acc1[nf], 0, 0, 0);
            acc2[nf] = __builtin_amdgcn_mfma_f32_16x16x32_bf16(af, b2, acc2[nf], 0, 0, 0);
        }
    }
    int orow = blockIdx.x*64 + wave*16 + lg*4;   // C/D: col=lane&15, row=(lane>>4)*4+reg
    #pragma unroll
    for (int nf = 0; nf < NF; nf++){
        int c = nf*16 + lr;
        #pragma unroll
        for (int j = 0; j < 4; j++){
            size_t idx = (size_t)(orow + j)*N + c;
            C1[idx] = f2bf(acc1[nf][j]);
            if (OBF2) ((unsigned short*)C2)[idx] = f2bf(acc2[nf][j]);
            else      ((float*)C2)[idx] = acc2[nf][j];
        }
    }
}

// ---------------- z = lky(agg1h + r1h + b1l) -> zh bf16 (8 elems/thread) ----------------
__global__ void k_fin1(const uint4* __restrict__ agg1h, const uint4* __restrict__ r1h,
                       const float* __restrict__ b1l, uint4* __restrict__ zh){
    size_t i = (size_t)blockIdx.x*256 + threadIdx.x;   // NT*128/8 items
    uint4 a = agg1h[i], r = r1h[i];
    int c0 = ((int)(i & 15))*8;
    unsigned av[4] = {a.x, a.y, a.z, a.w};
    unsigned rv[4] = {r.x, r.y, r.z, r.w};
    unsigned ov[4];
    #pragma unroll
    for (int q = 0; q < 4; q++){
        float z0 = lky(bf2f_lo(av[q]) + bf2f_lo(rv[q]) + b1l[c0 + 2*q]);
        float z1 = lky(bf2f_hi(av[q]) + bf2f_hi(rv[q]) + b1l[c0 + 2*q + 1]);
        ov[q] = (unsigned)f2bf(z0) | ((unsigned)f2bf(z1) << 16);
    }
    uint4 o = {ov[0], ov[1], ov[2], ov[3]};
    zh[i] = o;
}

// ---------------- fp32 dual GEMM (head only): C = act(A1@W1 [+ A2@W2] + bias) ----------------
__global__ void __launch_bounds__(256) k_gemm(
        const float* __restrict__ A1, const float* __restrict__ A2,
        const float* __restrict__ W1, const float* __restrict__ W2,
        const float* __restrict__ bias, void* __restrict__ C,
        int M, int Nn, int Kd, int dual, int act, int obf){
    __shared__ float sA1[16*68], sB1[16*68], sA2[16*68], sB2[16*68];
    int tid = threadIdx.x;
    int m0 = blockIdx.x*64, n0 = blockIdx.y*64;
    int tx = tid & 15, ty = tid >> 4;
    int lr = tid >> 2, lk = (tid & 3)*4;
    int wk = tid >> 4, wn = (tid & 15)*4;
    float acc[4][4] = {};
    for (int k0 = 0; k0 < Kd; k0 += 16){
        float4 a1 = *(const float4*)&A1[(size_t)(m0+lr)*Kd + k0 + lk];
        float4 w1 = *(const float4*)&W1[(size_t)(k0+wk)*Nn + n0 + wn];
        sA1[(lk+0)*68+lr] = a1.x; sA1[(lk+1)*68+lr] = a1.y;
        sA1[(lk+2)*68+lr] = a1.z; sA1[(lk+3)*68+lr] = a1.w;
        *(float4*)&sB1[wk*68+wn] = w1;
        if (dual){
            float4 a2 = *(const float4*)&A2[(size_t)(m0+lr)*Kd + k0 + lk];
            float4 w2 = *(const float4*)&W2[(size_t)(k0+wk)*Nn + n0 + wn];
            sA2[(lk+0)*68+lr] = a2.x; sA2[(lk+1)*68+lr] = a2.y;
            sA2[(lk+2)*68+lr] = a2.z; sA2[(lk+3)*68+lr] = a2.w;
            *(float4*)&sB2[wk*68+wn] = w2;
        }
        __syncthreads();
        #pragma unroll
        for (int kk = 0; kk < 16; kk++){
            float4 av = *(const float4*)&sA1[kk*68 + ty*4];
            float4 bv = *(const float4*)&sB1[kk*68 + tx*4];
            float a[4] = {av.x, av.y, av.z, av.w};
            float b[4] = {bv.x, bv.y, bv.z, bv.w};
            #pragma unroll
            for (int i = 0; i < 4; i++)
                #pragma unroll
                for (int j = 0; j < 4; j++) acc[i][j] += a[i]*b[j];
            if (dual){
                float4 av2 = *(const float4*)&sA2[kk*68 + ty*4];
                float4 bv2 = *(const float4*)&sB2[kk*68 + tx*4];
                float a2[4] = {av2.x, av2.y, av2.z, av2.w};
                float b2[4] = {bv2.x, bv2.y, bv2.z, bv2.w};
                #pragma unroll
                for (int i = 0; i < 4; i++)
                    #pragma unroll
                    for (int j = 0; j < 4; j++) acc[i][j] += a2[i]*b2[j];
            }
        }
        __syncthreads();
    }
    float bb[4] = {0.f, 0.f, 0.f, 0.f};
    if (bias){
        #pragma unroll
        for (int j = 0; j < 4; j++) bb[j] = bias[n0 + tx*4 + j];
    }
    #pragma unroll
    for (int i = 0; i < 4; i++){
        float v0 = acc[i][0]+bb[0], v1 = acc[i][1]+bb[1], v2 = acc[i][2]+bb[2], v3 = acc[i][3]+bb[3];
        if (act){ v0 = lky(v0); v1 = lky(v1); v2 = lky(v2); v3 = lky(v3); }
        size_t idx = (size_t)(m0 + ty*4 + i)*Nn + n0 + tx*4;
        if (obf){
            ushort4 o = { f2bf(v0), f2bf(v1), f2bf(v2), f2bf(v3) };
            *(ushort4*)&((unsigned short*)C)[idx] = o;
        } else {
            float4 o = { v0, v1, v2, v3 };
            *(float4*)&((float*)C)[idx] = o;
        }
    }
}

// ---------------- fused: spre = lky(agg2 + r2 + b2l); s = softmax(spre@Wm + bm); ent ----------------
__global__ void __launch_bounds__(256) k_gemm_wm(
        const float* __restrict__ agg2, const float* __restrict__ r2,
        const float* __restrict__ b2l, const float* __restrict__ Wm,
        const float* __restrict__ bm, float* __restrict__ S,
        unsigned short* __restrict__ Sh, float* __restrict__ ent_acc){
    __shared__ float sA[16*68], sB[16*68];
    __shared__ float red[256];
    int tid = threadIdx.x;
    int m0 = blockIdx.x*64;
    int tx = tid & 15, ty = tid >> 4;
    int lr = tid >> 2, lk = (tid & 3)*4;
    int wk = tid >> 4, wn = (tid & 15)*4;
    float acc[4][4] = {};
    for (int k0 = 0; k0 < 64; k0 += 16){
        float4 a = *(const float4*)&agg2[(size_t)(m0+lr)*64 + k0 + lk];
        float4 r = *(const float4*)&r2[(size_t)(m0+lr)*64 + k0 + lk];
        sA[(lk+0)*68+lr] = lky(a.x + r.x + b2l[k0+lk+0]);
        sA[(lk+1)*68+lr] = lky(a.y + r.y + b2l[k0+lk+1]);
        sA[(lk+2)*68+lr] = lky(a.z + r.z + b2l[k0+lk+2]);
        sA[(lk+3)*68+lr] = lky(a.w + r.w + b2l[k0+lk+3]);
        *(float4*)&sB[wk*68+wn] = *(const float4*)&Wm[(size_t)(k0+wk)*64 + wn];
        __syncthreads();
        #pragma unroll
        for (int kk = 0; kk < 16; kk++){
            float4 av = *(const float4*)&sA[kk*68 + ty*4];
            float4 bv = *(const float4*)&sB[kk*68 + tx*4];
            float a4[4] = {av.x, av.y, av.z, av.w};
            float b4[4] = {bv.x, bv.y, bv.z, bv.w};
            #pragma unroll
            for (int i = 0; i < 4; i++)
                #pragma unroll
                for (int j = 0; j < 4; j++) acc[i][j] += a4[i]*b4[j];
        }
        __syncthreads();
    }
    float bb[4];
    #pragma unroll
    for (int j = 0; j < 4; j++) bb[j] = bm[tx*4 + j];
    float ent_local = 0.f;
    #pragma unroll
    for (int i = 0; i < 4; i++){
        float v[4];
        #pragma unroll
        for (int j = 0; j < 4; j++) v[j] = acc[i][j] + bb[j];
        float m = fmaxf(fmaxf(v[0], v[1]), fmaxf(v[2], v[3]));
        for (int o = 1; o < 16; o <<= 1) m = fmaxf(m, __shfl_xor(m, o));
        float e[4];
        float sm = 0.f;
        #pragma unroll
        for (int j = 0; j < 4; j++){ e[j] = __expf(v[j] - m); sm += e[j]; }
        for (int o = 1; o < 16; o <<= 1) sm += __shfl_xor(sm, o);
        float inv = 1.f/sm;
        float p[4];
        float w = 0.f;
        #pragma unroll
        for (int j = 0; j < 4; j++){
            p[j] = e[j]*inv;
            w += -p[j]*__logf(p[j] + 1e-15f);
        }
        for (int o = 1; o < 16; o <<= 1) w += __shfl_xor(w, o);
        if (tx == 0) ent_local += w;
        size_t idx = (size_t)(m0 + ty*4 + i)*64 + tx*4;
        float4 of = { p[0], p[1], p[2], p[3] };
        *(float4*)&S[idx] = of;
        ushort4 oh = { f2bf(p[0]), f2bf(p[1]), f2bf(p[2]), f2bf(p[3]) };
        *(ushort4*)&Sh[idx] = oh;
    }
    red[tid] = ent_local; __syncthreads();
    for (int o = 128; o; o >>= 1){ if (tid < o) red[tid] += red[tid+o]; __syncthreads(); }
    if (tid == 0) atomicAdd(ent_acc, red[0]);
}

// ---------------- pooled[b] = s[b]^T z[b] (z in bf16), 4-way n-split ----------------
__global__ void k_pooled(const float* __restrict__ S, const unsigned short* __restrict__ Zh,
                         float* __restrict__ P){
    __shared__ float sS[8*64], sZ[8*128];
    int b = blockIdx.x >> 2, part = blockIdx.x & 3;
    int tid = threadIdx.x;
    int kk = (tid & 31)*2, fg = tid >> 5;
    float acc[2][16] = {};
    int nbase = b*NPG + part*256;
    for (int n0 = 0; n0 < 256; n0 += 8){
        for (int i = tid; i < 512; i += 256){ int r = i >> 6, c = i & 63; sS[i] = S[(size_t)(nbase+n0+r)*64 + c]; }
        for (int i = tid; i < 512; i += 256){
            int r = i >> 6, c2 = i & 63;
            unsigned v = *(const unsigned*)&Zh[(size_t)(nbase+n0+r)*128 + c2*2];
            sZ[r*128 + c2*2]     = bf2f_lo(v);
            sZ[r*128 + c2*2 + 1] = bf2f_hi(v);
        }
        __syncthreads();
        for (int nn = 0; nn < 8; nn++){
            float a0 = sS[nn*64+kk], a1 = sS[nn*64+kk+1];
            #pragma unroll
            for (int j = 0; j < 16; j++){
                float zz = sZ[nn*128 + fg*16 + j];
                acc[0][j] += a0*zz; acc[1][j] += a1*zz;
            }
        }
        __syncthreads();
    }
    for (int c = 0; c < 2; c++)
        for (int j = 0; j < 16; j++)
            atomicAdd(&P[((size_t)b*64 + kk + c)*128 + fg*16 + j], acc[c][j]);
}

// ---------------- AP[b] += s^T t AND GR[b] += s^T s in one pass ----------------
__global__ void k_adjp2(const float* __restrict__ S, const float* __restrict__ T,
                        float* __restrict__ AP, float* __restrict__ GR){
    __shared__ float sS[8*64], sT[8*64];
    int b = blockIdx.x >> 2, part = blockIdx.x & 3;
    int tid = threadIdx.x;
    int kk = (tid & 31)*2, lg = tid >> 5;
    float acc[2][8] = {};
    float acg[2][8] = {};
    int nbase = b*NPG + part*256;
    for (int n0 = 0; n0 < 256; n0 += 8){
        for (int i = tid; i < 512; i += 256){
            int r = i >> 6, c = i & 63;
            sS[i] = S[(size_t)(nbase+n0+r)*64 + c];
            sT[i] = T[(size_t)(nbase+n0+r)*64 + c];
        }
        __syncthreads();
        for (int nn = 0; nn < 8; nn++){
            float a0 = sS[nn*64+kk], a1 = sS[nn*64+kk+1];
            #pragma unroll
            for (int j = 0; j < 8; j++){
                float tt = sT[nn*64 + lg*8 + j];
                float ss = sS[nn*64 + lg*8 + j];
                acc[0][j] += a0*tt; acc[1][j] += a1*tt;
                acg[0][j] += a0*ss; acg[1][j] += a1*ss;
            }
        }
        __syncthreads();
    }
    for (int c = 0; c < 2; c++)
        for (int j = 0; j < 8; j++){
            atomicAdd(&AP[((size_t)b*64 + kk + c)*64 + lg*8 + j], acc[c][j]);
            atomicAdd(&GR[((size_t)b*64 + kk + c)*64 + lg*8 + j], acg[c][j]);
        }
}

// ---------------- sum of squares of gram ----------------
__global__ void k_gramsq(const float* __restrict__ gram, float* __restrict__ acc_out){
    int i = blockIdx.x*256 + threadIdx.x;
    float v = gram[i];
    float s = v*v;
    for (int o = 32; o; o >>= 1) s += __shfl_xor(s, o);
    __shared__ float red[4];
    if ((threadIdx.x & 63) == 0) red[threadIdx.x >> 6] = s;
    __syncthreads();
    if (threadIdx.x == 0) atomicAdd(acc_out, red[0]+red[1]+red[2]+red[3]);
}

// ---------------- cross = sum_b trace(adjp[b]) ----------------
__global__ void k_trace(const float* __restrict__ AP, float* __restrict__ acc_out){
    int i = blockIdx.x*256 + threadIdx.x;      // 4096 diag entries
    float s = AP[(size_t)(i >> 6)*4096 + (i & 63)*65];
    for (int o = 32; o; o >>= 1) s += __shfl_xor(s, o);
    __shared__ float red[4];
    if ((threadIdx.x & 63) == 0) red[threadIdx.x >> 6] = s;
    __syncthreads();
    if (threadIdx.x == 0) atomicAdd(acc_out, red[0]+red[1]+red[2]+red[3]);
}

// ---------------- head stage A: aggout[b] = (adjp[b] @ pooled[b]) / rowsum ----------------
__global__ void __launch_bounds__(256) k_heada(
        const float* __restrict__ AP, const float* __restrict__ P,
        float* __restrict__ aggout){
    __shared__ float sapT[64*65];
    __shared__ float sp[64*33];
    __shared__ float srs[64];
    int b = blockIdx.x, c0 = blockIdx.y*32;
    int tid = threadIdx.x;
    for (int i = tid; i < 4096; i += 256){
        int k = i >> 6, l = i & 63;
        sapT[l*65 + k] = AP[(size_t)b*4096 + i];
    }
    for (int i = tid; i < 2048; i += 256){
        int l = i >> 5, j = i & 31;
        sp[l*33 + j] = P[(size_t)b*8192 + l*128 + c0 + j];
    }
    __syncthreads();
    if (tid < 64){
        float s = 0.f;
        for (int l = 0; l < 64; l++) s += sapT[l*65 + tid];
        srs[tid] = fmaxf(s, 1.f);
    }
    __syncthreads();
    int k = tid & 63, jg = (tid >> 6)*8;
    float acc[8] = {};
    for (int l = 0; l < 64; l++){
        float a = sapT[l*65 + k];
        #pragma unroll
        for (int j = 0; j < 8; j++) acc[j] += a*sp[l*33 + jg + j];
    }
    float inv = 1.f/srs[k];
    #pragma unroll
    for (int j = 0; j < 8; j++)
        aggout[(size_t)b*8192 + k*128 + c0 + jg + j] = acc[j]*inv;
}

// ---------------- head stage C: hcacc[b,:] += h[b, chunk] @ Wc1[chunk, :] ----------------
__global__ void __launch_bounds__(256) k_head2(
        const float* __restrict__ hbuf, const float* __restrict__ Wc1,
        float* __restrict__ hcacc){
    __shared__ float sh[512];
    __shared__ float sred[256];
    int b = blockIdx.x >> 4, ch = blockIdx.x & 15;
    int tid = threadIdx.x;
    for (int i = tid; i < 512; i += 256) sh[i] = hbuf[(size_t)b*8192 + ch*512 + i];
    __syncthreads();
    int j = tid & 127, half = tid >> 7;
    float acc = 0.f;
    const float* W = Wc1 + (size_t)(ch*512 + half*256)*128;
    const float* hh = sh + half*256;
    for (int r = 0; r < 256; r++) acc += hh[r]*W[(size_t)r*128 + j];
    sred[tid] = acc; __syncthreads();
    if (tid < 128) atomicAdd(&hcacc[(size_t)b*128 + tid], sred[tid] + sred[tid+128]);
}

// ---------------- head stage D: logits ----------------
__global__ void k_head3(const float* __restrict__ hcacc, const float* __restrict__ bc1,
                        const float* __restrict__ Wc2, const float* __restrict__ bc2,
                        float* __restrict__ out){
    int b = blockIdx.x, t = threadIdx.x;   // 128 threads
    float hc = lky(hcacc[(size_t)b*128 + t] + bc1[t]);
    float p = hc*Wc2[t];
    for (int o = 32; o; o >>= 1) p += __shfl_xor(p, o);
    __shared__ float r2[2];
    if ((t & 63) == 0) r2[t >> 6] = p;
    __syncthreads();
    if (t == 0) out[b] = r2[0] + r2[1] + bc2[0];
}

__global__ void k_finalize(const unsigned int* __restrict__ a2,
                           const float* __restrict__ cross,
                           const float* __restrict__ normg,
                           const float* __restrict__ ent,
                           float* __restrict__ out){
    float ss = (float)(*a2) - 2.f*(*cross) + (*normg);
    if (ss < 0.f) ss = 0.f;
    float link = sqrtf(ss) / 67108864.f;     // a.size
    out[64] = link + (*ent)/(float)NT;
}

extern "C" void kernel_launch(void* const* d_in, const int* in_sizes, int n_in,
                              void* d_out, int out_size, void* d_ws, size_t ws_size,
                              hipStream_t stream){
    const float* x    = (const float*)d_in[0];
    const int*   ei   = (const int*)d_in[1];
    const int*   src  = ei;
    const int*   dst  = ei + ETOT;
    const float* W1l  = (const float*)d_in[5];
    const float* b1l  = (const float*)d_in[6];
    const float* W1r  = (const float*)d_in[7];
    const float* W2l  = (const float*)d_in[8];
    const float* b2l  = (const float*)d_in[9];
    const float* W2r  = (const float*)d_in[10];
    const float* Wm   = (const float*)d_in[11];
    const float* bm   = (const float*)d_in[12];
    const float* Wrel = (const float*)d_in[13];
    const float* Wroot= (const float*)d_in[14];
    const float* broot= (const float*)d_in[15];
    const float* Wc1  = (const float*)d_in[16];
    const float* bc1  = (const float*)d_in[17];
    const float* Wc2  = (const float*)d_in[18];
    const float* bc2  = (const float*)d_in[19];
    float* out = (float*)d_out;

    char* w = (char*)d_ws;
    size_t off = 0;
    auto take = [&](size_t bytes)->void*{
        void* p = w + off; off = (off + bytes + 255) & ~(size_t)255; return p;
    };
    const size_t MB = 1024*1024;
    // --- small zeroed zone ---
    int*   cnt_d  = (int*)take((size_t)NT*4);
    int*   cnt_s  = (int*)take((size_t)NT*4);
    int*   cur_d  = (int*)take((size_t)NT*4);
    int*   cur_s  = (int*)take((size_t)NT*4);
    float* pooled = (float*)take((size_t)BATCH*64*128*4);
    float* adjp   = (float*)take((size_t)BATCH*64*64*4);
    float* gram   = (float*)take((size_t)BATCH*64*64*4);
    float* hcacc  = (float*)take((size_t)BATCH*128*4);
    int*   tots   = (int*)take(2*64*4);
    float* accb   = (float*)take(64);
    size_t zero_small = off;
    // --- non-zeroed ---
    int*   ipd   = (int*)take((size_t)(NT+1)*4);
    int*   ips   = (int*)take((size_t)(NT+1)*4);
    int*   lst_d = (int*)take((size_t)ETOT*4);
    int*   lst_s = (int*)take((size_t)ETOT*4);
    char*  regA  = (char*)take(16*MB);   // agg2 (f32)
    char*  regB  = (char*)take(16*MB);   // y1h -> r2 -> tbuf
    char*  regC  = (char*)take(16*MB);   // r1h -> [y2h | s2h]
    char*  regD  = (char*)take(16*MB);   // agg1h -> s2
    char*  regE  = (char*)take(16*MB);   // zh
    float* hbuf  = (float*)take((size_t)BATCH*8192*4);
    float* aggo  = (float*)take((size_t)BATCH*8192*4);

    unsigned short* y1h   = (unsigned short*)regB;
    float*          r2    = (float*)regB;
    float*          tbuf  = (float*)regB;
    unsigned short* r1h   = (unsigned short*)regC;
    unsigned short* y2h   = (unsigned short*)regC;
    unsigned short* s2h   = (unsigned short*)(regC + 8*MB);
    unsigned short* agg1h = (unsigned short*)regD;
    float*          s2    = (float*)regD;
    unsigned short* zh    = (unsigned short*)regE;
    float*          agg2  = (float*)regA;

    float* crossp = accb + 0;
    float* normgp = accb + 1;
    float* entp   = accb + 2;
    unsigned int* a2p = (unsigned int*)(accb + 3);

    hipMemsetAsync(d_ws, 0, zero_small, stream);

    // sum(a^2) via LDS nibble hist; pass 0 also produces CSR degree counts
    k_a2lds<<<dim3(BATCH, 4), 1024, 0, stream>>>(src, dst, a2p, cnt_d, cnt_s);

    // CSR build
    k_scan_local<<<dim3(64,2), 1024, 0, stream>>>(cnt_d, cnt_s, ipd, ips, tots);
    k_scan_add<<<dim3(64,2), 1024, 0, stream>>>(tots, ipd, ips);
    k_fill<<<ETOT/256, 256, 0, stream>>>(src, dst, ipd, ips, cur_d, cur_s, lst_d, lst_s);

    // SAGE layer 1 (GEMM-before-gather, MFMA): y1 = x@W1l (bf16), r1 = x@W1r (bf16)
    k_mfma2b<128,1,1><<<NT/64, 256, 0, stream>>>(x, W1l, W1r, y1h, r1h);
    k_aggh<64,1><<<NT/4, 256, 0, stream>>>(y1h, ipd, lst_d, agg1h, 1);
    k_fin1<<<NT*128/8/256, 256, 0, stream>>>((const uint4*)agg1h, (const uint4*)r1h, b1l, (uint4*)zh);

    // SAGE layer 2 (MFMA): y2 = z@W2l (bf16), r2 = z@W2r (f32)
    k_mfma2b<64,0,0><<<NT/64, 256, 0, stream>>>(zh, W2l, W2r, y2h, r2);
    k_aggh<32,0><<<NT/8, 256, 0, stream>>>(y2h, ipd, lst_d, agg2, 1);
    // fused: spre = lky(agg2+r2+b2l); s2 = softmax(spre@Wm+bm); ent; s2h bf16
    k_gemm_wm<<<NT/64, 256, 0, stream>>>(agg2, r2, b2l, Wm, bm, s2, s2h, entp);

    // t = A @ s
    k_aggh<32,0><<<NT/8, 256, 0, stream>>>(s2h, ips, lst_s, tbuf, 0);

    // pooled, adj_p + gram (fused), normg, cross = trace(adjp)
    k_pooled<<<BATCH*4, 256, 0, stream>>>(s2, zh, pooled);
    k_adjp2<<<BATCH*4, 256, 0, stream>>>(s2, tbuf, adjp, gram);
    k_gramsq<<<BATCH*4096/256, 256, 0, stream>>>(gram, normgp);
    k_trace<<<16, 256, 0, stream>>>(adjp, crossp);

    // head: A (agg), B (dual GEMM fp32), C (split-K), D (logits)
    k_heada<<<dim3(BATCH, 4), 256, 0, stream>>>(adjp, pooled, aggo);
    k_gemm<<<dim3(BATCH*64/64, 2), 256, 0, stream>>>(aggo, pooled, Wrel, Wroot, broot, hbuf, BATCH*64, 128, 128, 1, 1, 0);
    k_head2<<<BATCH*16, 256, 0, stream>>>(hbuf, Wc1, hcacc);
    k_head3<<<BATCH, 128, 0, stream>>>(hcacc, bc1, Wc2, bc2, out);
    k_finalize<<<1, 1, 0, stream>>>(a2p, crossp, normgp, entp, out);
}

// Round 7
// 751.979 us; speedup vs baseline: 4.5907x; 1.2951x over previous
//
#include <hip/hip_runtime.h>
#include <math.h>

#define BATCH 64
#define NPG 1024
#define NT (BATCH*NPG)        // 65536 nodes
#define EPER 32768
#define ETOT (BATCH*EPER)     // 2097152 edges

typedef __attribute__((ext_vector_type(4))) float f32x4;
typedef __attribute__((ext_vector_type(8))) short s16x8;

__device__ __forceinline__ float lky(float x){ return x > 0.f ? x : 0.01f*x; }
__device__ __forceinline__ unsigned short f2bf(float f){
    unsigned u = __float_as_uint(f);
    u = u + 0x7FFFu + ((u >> 16) & 1u);      // RNE
    return (unsigned short)(u >> 16);
}
__device__ __forceinline__ float bf2f_lo(unsigned v){ return __uint_as_float(v << 16); }
__device__ __forceinline__ float bf2f_hi(unsigned v){ return __uint_as_float(v & 0xFFFF0000u); }

// ---------------- sum(a^2) via per-graph LDS nibble histogram (+ degree counts on pass 0) ----------------
__global__ void __launch_bounds__(1024) k_a2lds(const int* __restrict__ src, const int* __restrict__ dst,
                                                unsigned* __restrict__ acc_out, int* cnt_d, int* cnt_s){
    __shared__ unsigned nib[32768];   // 128 KB = 262144 nibble counters
    __shared__ unsigned red[16];
    int b = blockIdx.x, pass = blockIdx.y, tid = threadIdx.x;
    for (int i = tid; i < 32768; i += 1024) nib[i] = 0;
    __syncthreads();
    int base = b*EPER;
    for (int i = tid; i < EPER; i += 1024){
        int sv = src[base+i], dv = dst[base+i];
        if (pass == 0){ atomicAdd(&cnt_d[dv], 1); atomicAdd(&cnt_s[sv], 1); }
        unsigned key = (((unsigned)sv & 1023u) << 10) | ((unsigned)dv & 1023u);
        if ((int)(key >> 18) == pass)
            atomicAdd(&nib[(key & 0x3FFFFu) >> 3], 1u << ((key & 7u)*4u));
    }
    __syncthreads();
    unsigned local = 0;
    for (int i = tid; i < 32768; i += 1024){
        unsigned w = nib[i];
        if (w){
            #pragma unroll
            for (int q = 0; q < 8; q++){ unsigned c = (w >> (4*q)) & 15u; local += c*c; }
        }
    }
    for (int o = 32; o; o >>= 1) local += __shfl_xor(local, o);
    if ((tid & 63) == 0) red[tid >> 6] = local;
    __syncthreads();
    if (tid == 0){
        unsigned s = 0;
        for (int q = 0; q < 16; q++) s += red[q];
        atomicAdd(acc_out, s);
    }
}

// ---------------- CSR scans + fill ----------------
__global__ void k_scan_local(const int* __restrict__ cnt_d, const int* __restrict__ cnt_s,
                             int* __restrict__ ipd, int* __restrict__ ips, int* __restrict__ tots){
    __shared__ int buf[1024];
    int which = blockIdx.y;
    const int* cnt = which ? cnt_s : cnt_d;
    int* ip = which ? ips : ipd;
    int base = blockIdx.x*1024;
    int tid = threadIdx.x;
    int v = cnt[base + tid];
    int x = v;
    buf[tid] = x; __syncthreads();
    for (int off = 1; off < 1024; off <<= 1){
        int t = (tid >= off) ? buf[tid - off] : 0;
        __syncthreads();
        x += t; buf[tid] = x; __syncthreads();
    }
    ip[base + tid] = x - v;
    if (tid == 1023) tots[which*64 + blockIdx.x] = x;
}

__global__ void k_scan_add(const int* __restrict__ tots, int* __restrict__ ipd, int* __restrict__ ips){
    int which = blockIdx.y;
    int* ip = which ? ips : ipd;
    const int* t = tots + which*64;
    __shared__ int soff;
    if (threadIdx.x == 0){
        int s = 0;
        for (int i = 0; i < (int)blockIdx.x; i++) s += t[i];
        soff = s;
    }
    __syncthreads();
    ip[blockIdx.x*1024 + threadIdx.x] += soff;
    if (blockIdx.x == 0 && threadIdx.x == 0) ip[NT] = ETOT;
}

__global__ void k_fill(const int* __restrict__ src, const int* __restrict__ dst,
                       const int* __restrict__ ipd, const int* __restrict__ ips,
                       int* cur_d, int* cur_s, int* lst_d, int* lst_s){
    int e = blockIdx.x*256 + threadIdx.x;
    if (e < ETOT){
        int s = src[e], d = dst[e];
        int p = atomicAdd(&cur_d[d], 1); lst_d[ipd[d] + p] = s;
        int q = atomicAdd(&cur_s[s], 1); lst_s[ips[s] + q] = d;
    }
}

// ---------------- bf16 segment gather (G threads per node, 2 feats/thread) ----------------
template<int G, int OBF>
__global__ void k_aggh(const unsigned short* __restrict__ X, const int* __restrict__ indptr,
                       const int* __restrict__ lst, void* __restrict__ out, int do_mean){
    int node = blockIdx.x*(256/G) + threadIdx.x/G;
    int g = threadIdx.x % G;
    int st = indptr[node], en = indptr[node+1];
    float a0 = 0.f, a1 = 0.f;
    for (int e = st; e < en; e++){
        int nb = lst[e];
        unsigned v = *(const unsigned*)&X[(size_t)nb*(2*G) + 2*g];
        a0 += bf2f_lo(v);
        a1 += bf2f_hi(v);
    }
    if (do_mean){
        int dg = en - st;
        float inv = 1.f/(float)(dg > 1 ? dg : 1);
        a0 *= inv; a1 *= inv;
    }
    if (OBF){
        unsigned pk = (unsigned)f2bf(a0) | ((unsigned)f2bf(a1) << 16);
        ((unsigned*)out)[(size_t)node*G + g] = pk;
    } else {
        ((float*)out)[(size_t)node*(2*G) + 2*g]     = a0;
        ((float*)out)[(size_t)node*(2*G) + 2*g + 1] = a1;
    }
}

// ---------------- MFMA dual-B GEMM: C1 = A@W1 (bf16), C2 = A@W2 (bf16 or f32); K=128 ----------------
template<int N, int AF32, int OBF2>
__global__ void __launch_bounds__(256) k_mfma2b(
        const void* __restrict__ Ain, const float* __restrict__ W1,
        const float* __restrict__ W2, unsigned short* __restrict__ C1,
        void* __restrict__ C2){
    __shared__ unsigned short ldsB[2*N*128];
    int tid = threadIdx.x;
    for (int i = tid; i < 128*N; i += 256){
        int k = i / N, n = i - k*N;
        int swz = (n*256 + 2*k) ^ ((n & 7) << 4);
        *(unsigned short*)((char*)ldsB + swz)          = f2bf(W1[i]);
        *(unsigned short*)((char*)ldsB + N*256 + swz)  = f2bf(W2[i]);
    }
    __syncthreads();
    int wave = tid >> 6, l = tid & 63;
    int lr = l & 15, lg = l >> 4;
    int arow = blockIdx.x*64 + wave*16 + lr;
    constexpr int NF = N/16;
    f32x4 acc1[NF], acc2[NF];
    f32x4 zv = {0.f, 0.f, 0.f, 0.f};
    #pragma unroll
    for (int nf = 0; nf < NF; nf++){ acc1[nf] = zv; acc2[nf] = zv; }
    const unsigned short* Ah = (const unsigned short*)Ain;
    const float* Af = (const float*)Ain;
    #pragma unroll
    for (int ks = 0; ks < 4; ks++){
        s16x8 af;
        if (AF32){
            const float* p = Af + (size_t)arow*128 + ks*32 + lg*8;
            float4 v0 = *(const float4*)p;
            float4 v1 = *(const float4*)(p + 4);
            af[0] = (short)f2bf(v0.x); af[1] = (short)f2bf(v0.y);
            af[2] = (short)f2bf(v0.z); af[3] = (short)f2bf(v0.w);
            af[4] = (short)f2bf(v1.x); af[5] = (short)f2bf(v1.y);
            af[6] = (short)f2bf(v1.z); af[7] = (short)f2bf(v1.w);
        } else {
            af = *(const s16x8*)(Ah + (size_t)arow*128 + ks*32 + lg*8);
        }
        #pragma unroll
        for (int nf = 0; nf < NF; nf++){
            int n = nf*16 + lr;
            int swz = (n*256 + ks*64 + lg*16) ^ ((n & 7) << 4);
            s16x8 b1 = *(const s16x8*)((const char*)ldsB + swz);
            s16x8 b2 = *(const s16x8*)((const char*)ldsB + N*256 + swz);
            acc1[nf] = __builtin_amdgcn_mfma_f32_16x16x32_bf16(af, b1, acc1[nf], 0, 0, 0);
            acc2[nf] = __builtin_amdgcn_mfma_f32_16x16x32_bf16(af, b2, acc2[nf], 0, 0, 0);
        }
    }
    int orow = blockIdx.x*64 + wave*16 + lg*4;
    #pragma unroll
    for (int nf = 0; nf < NF; nf++){
        int c = nf*16 + lr;
        #pragma unroll
        for (int j = 0; j < 4; j++){
            size_t idx = (size_t)(orow + j)*N + c;
            C1[idx] = f2bf(acc1[nf][j]);
            if (OBF2) ((unsigned short*)C2)[idx] = f2bf(acc2[nf][j]);
            else      ((float*)C2)[idx] = acc2[nf][j];
        }
    }
}

// ---------------- z = lky(agg1h + r1h + b1l) -> zh bf16 (8 elems/thread) ----------------
__global__ void k_fin1(const uint4* __restrict__ agg1h, const uint4* __restrict__ r1h,
                       const float* __restrict__ b1l, uint4* __restrict__ zh){
    size_t i = (size_t)blockIdx.x*256 + threadIdx.x;   // NT*128/8 items
    uint4 a = agg1h[i], r = r1h[i];
    int c0 = ((int)(i & 15))*8;
    unsigned av[4] = {a.x, a.y, a.z, a.w};
    unsigned rv[4] = {r.x, r.y, r.z, r.w};
    unsigned ov[4];
    #pragma unroll
    for (int q = 0; q < 4; q++){
        float z0 = lky(bf2f_lo(av[q]) + bf2f_lo(rv[q]) + b1l[c0 + 2*q]);
        float z1 = lky(bf2f_hi(av[q]) + bf2f_hi(rv[q]) + b1l[c0 + 2*q + 1]);
        ov[q] = (unsigned)f2bf(z0) | ((unsigned)f2bf(z1) << 16);
    }
    uint4 o = {ov[0], ov[1], ov[2], ov[3]};
    zh[i] = o;
}

// ---------------- fp32 dual GEMM (head only): C = act(A1@W1 [+ A2@W2] + bias) ----------------
__global__ void __launch_bounds__(256) k_gemm(
        const float* __restrict__ A1, const float* __restrict__ A2,
        const float* __restrict__ W1, const float* __restrict__ W2,
        const float* __restrict__ bias, void* __restrict__ C,
        int M, int Nn, int Kd, int dual, int act, int obf){
    __shared__ float sA1[16*68], sB1[16*68], sA2[16*68], sB2[16*68];
    int tid = threadIdx.x;
    int m0 = blockIdx.x*64, n0 = blockIdx.y*64;
    int tx = tid & 15, ty = tid >> 4;
    int lr = tid >> 2, lk = (tid & 3)*4;
    int wk = tid >> 4, wn = (tid & 15)*4;
    float acc[4][4] = {};
    for (int k0 = 0; k0 < Kd; k0 += 16){
        float4 a1 = *(const float4*)&A1[(size_t)(m0+lr)*Kd + k0 + lk];
        float4 w1 = *(const float4*)&W1[(size_t)(k0+wk)*Nn + n0 + wn];
        sA1[(lk+0)*68+lr] = a1.x; sA1[(lk+1)*68+lr] = a1.y;
        sA1[(lk+2)*68+lr] = a1.z; sA1[(lk+3)*68+lr] = a1.w;
        *(float4*)&sB1[wk*68+wn] = w1;
        if (dual){
            float4 a2 = *(const float4*)&A2[(size_t)(m0+lr)*Kd + k0 + lk];
            float4 w2 = *(const float4*)&W2[(size_t)(k0+wk)*Nn + n0 + wn];
            sA2[(lk+0)*68+lr] = a2.x; sA2[(lk+1)*68+lr] = a2.y;
            sA2[(lk+2)*68+lr] = a2.z; sA2[(lk+3)*68+lr] = a2.w;
            *(float4*)&sB2[wk*68+wn] = w2;
        }
        __syncthreads();
        #pragma unroll
        for (int kk = 0; kk < 16; kk++){
            float4 av = *(const float4*)&sA1[kk*68 + ty*4];
            float4 bv = *(const float4*)&sB1[kk*68 + tx*4];
            float a[4] = {av.x, av.y, av.z, av.w};
            float b[4] = {bv.x, bv.y, bv.z, bv.w};
            #pragma unroll
            for (int i = 0; i < 4; i++)
                #pragma unroll
                for (int j = 0; j < 4; j++) acc[i][j] += a[i]*b[j];
            if (dual){
                float4 av2 = *(const float4*)&sA2[kk*68 + ty*4];
                float4 bv2 = *(const float4*)&sB2[kk*68 + tx*4];
                float a2[4] = {av2.x, av2.y, av2.z, av2.w};
                float b2[4] = {bv2.x, bv2.y, bv2.z, bv2.w};
                #pragma unroll
                for (int i = 0; i < 4; i++)
                    #pragma unroll
                    for (int j = 0; j < 4; j++) acc[i][j] += a2[i]*b2[j];
            }
        }
        __syncthreads();
    }
    float bb[4] = {0.f, 0.f, 0.f, 0.f};
    if (bias){
        #pragma unroll
        for (int j = 0; j < 4; j++) bb[j] = bias[n0 + tx*4 + j];
    }
    #pragma unroll
    for (int i = 0; i < 4; i++){
        float v0 = acc[i][0]+bb[0], v1 = acc[i][1]+bb[1], v2 = acc[i][2]+bb[2], v3 = acc[i][3]+bb[3];
        if (act){ v0 = lky(v0); v1 = lky(v1); v2 = lky(v2); v3 = lky(v3); }
        size_t idx = (size_t)(m0 + ty*4 + i)*Nn + n0 + tx*4;
        if (obf){
            ushort4 o = { f2bf(v0), f2bf(v1), f2bf(v2), f2bf(v3) };
            *(ushort4*)&((unsigned short*)C)[idx] = o;
        } else {
            float4 o = { v0, v1, v2, v3 };
            *(float4*)&((float*)C)[idx] = o;
        }
    }
}

// ---------------- fused: spre = lky(agg2 + r2 + b2l); s = softmax(spre@Wm + bm); ent; bf16 out ----------------
__global__ void __launch_bounds__(256) k_gemm_wm(
        const float* __restrict__ agg2, const float* __restrict__ r2,
        const float* __restrict__ b2l, const float* __restrict__ Wm,
        const float* __restrict__ bm,
        unsigned short* __restrict__ Sh, float* __restrict__ ent_acc){
    __shared__ float sA[16*68], sB[16*68];
    __shared__ float red[256];
    int tid = threadIdx.x;
    int m0 = blockIdx.x*64;
    int tx = tid & 15, ty = tid >> 4;
    int lr = tid >> 2, lk = (tid & 3)*4;
    int wk = tid >> 4, wn = (tid & 15)*4;
    float acc[4][4] = {};
    for (int k0 = 0; k0 < 64; k0 += 16){
        float4 a = *(const float4*)&agg2[(size_t)(m0+lr)*64 + k0 + lk];
        float4 r = *(const float4*)&r2[(size_t)(m0+lr)*64 + k0 + lk];
        sA[(lk+0)*68+lr] = lky(a.x + r.x + b2l[k0+lk+0]);
        sA[(lk+1)*68+lr] = lky(a.y + r.y + b2l[k0+lk+1]);
        sA[(lk+2)*68+lr] = lky(a.z + r.z + b2l[k0+lk+2]);
        sA[(lk+3)*68+lr] = lky(a.w + r.w + b2l[k0+lk+3]);
        *(float4*)&sB[wk*68+wn] = *(const float4*)&Wm[(size_t)(k0+wk)*64 + wn];
        __syncthreads();
        #pragma unroll
        for (int kk = 0; kk < 16; kk++){
            float4 av = *(const float4*)&sA[kk*68 + ty*4];
            float4 bv = *(const float4*)&sB[kk*68 + tx*4];
            float a4[4] = {av.x, av.y, av.z, av.w};
            float b4[4] = {bv.x, bv.y, bv.z, bv.w};
            #pragma unroll
            for (int i = 0; i < 4; i++)
                #pragma unroll
                for (int j = 0; j < 4; j++) acc[i][j] += a4[i]*b4[j];
        }
        __syncthreads();
    }
    float bb[4];
    #pragma unroll
    for (int j = 0; j < 4; j++) bb[j] = bm[tx*4 + j];
    float ent_local = 0.f;
    #pragma unroll
    for (int i = 0; i < 4; i++){
        float v[4];
        #pragma unroll
        for (int j = 0; j < 4; j++) v[j] = acc[i][j] + bb[j];
        float m = fmaxf(fmaxf(v[0], v[1]), fmaxf(v[2], v[3]));
        for (int o = 1; o < 16; o <<= 1) m = fmaxf(m, __shfl_xor(m, o));
        float e[4];
        float sm = 0.f;
        #pragma unroll
        for (int j = 0; j < 4; j++){ e[j] = __expf(v[j] - m); sm += e[j]; }
        for (int o = 1; o < 16; o <<= 1) sm += __shfl_xor(sm, o);
        float inv = 1.f/sm;
        float p[4];
        float w = 0.f;
        #pragma unroll
        for (int j = 0; j < 4; j++){
            p[j] = e[j]*inv;
            w += -p[j]*__logf(p[j] + 1e-15f);
        }
        for (int o = 1; o < 16; o <<= 1) w += __shfl_xor(w, o);
        if (tx == 0) ent_local += w;
        size_t idx = (size_t)(m0 + ty*4 + i)*64 + tx*4;
        ushort4 oh = { f2bf(p[0]), f2bf(p[1]), f2bf(p[2]), f2bf(p[3]) };
        *(ushort4*)&Sh[idx] = oh;
    }
    red[tid] = ent_local; __syncthreads();
    for (int o = 128; o; o >>= 1){ if (tid < o) red[tid] += red[tid+o]; __syncthreads(); }
    if (tid == 0) atomicAdd(ent_acc, red[0]);
}

// ---------------- fused MFMA: [pooled | adjp | gram] = s^T @ [z | t | s] per graph ----------------
// grid 64 blocks x 1024 thr (16 waves). M=64, N=256, K=1024 per graph.
// LDS transposed, stride-72-padded (2-lane/bank). Epilogue fuses trace(adjp)->cross and ||gram||^2->normg.
__global__ void __launch_bounds__(1024) k_spmm(
        const unsigned short* __restrict__ Sh, const unsigned short* __restrict__ Zh,
        const unsigned short* __restrict__ Th,
        float* __restrict__ P, float* __restrict__ AP, float* __restrict__ GR,
        float* __restrict__ crossp, float* __restrict__ normgp){
    __shared__ unsigned short At[64*72];    // A^T: [m up to 64][k 64]
    __shared__ unsigned short Bt[256*72];   // B^T: [col 256][k 64]
    __shared__ float rtr[16], rsq[16];
    int b = blockIdx.x, tid = threadIdx.x;
    int w = tid >> 6, l = tid & 63;
    int lr = l & 15, lg = l >> 4;
    int mt = w & 3, ng = w >> 2;
    f32x4 acc[4];
    f32x4 zv = {0.f, 0.f, 0.f, 0.f};
    #pragma unroll
    for (int q = 0; q < 4; q++) acc[q] = zv;
    int gb = b*NPG;
    int sa_n = tid & 63, sa_c = (tid >> 6)*4;      // At stage: 64 rows x 16 col-groups
    int sb_k = tid & 63, sb_g = tid >> 6;          // Bt stage: 64 k x 16 col-groups of 16
    for (int n0 = 0; n0 < NPG; n0 += 64){
        ushort4 sv = *(const ushort4*)&Sh[(size_t)(gb+n0+sa_n)*64 + sa_c];
        At[(sa_c+0)*72 + sa_n] = sv.x;
        At[(sa_c+1)*72 + sa_n] = sv.y;
        At[(sa_c+2)*72 + sa_n] = sv.z;
        At[(sa_c+3)*72 + sa_n] = sv.w;
        {
            int R = gb + n0 + sb_k;
            const unsigned short* srcp;
            if (sb_g < 8)       srcp = &Zh[(size_t)R*128 + sb_g*16];
            else if (sb_g < 12) srcp = &Th[(size_t)R*64 + (sb_g-8)*16];
            else                srcp = &Sh[(size_t)R*64 + (sb_g-12)*16];
            ushort4 a0 = *(const ushort4*)(srcp);
            ushort4 a1 = *(const ushort4*)(srcp+4);
            ushort4 a2 = *(const ushort4*)(srcp+8);
            ushort4 a3 = *(const ushort4*)(srcp+12);
            int cb = sb_g*16;
            Bt[(cb+ 0)*72+sb_k]=a0.x; Bt[(cb+ 1)*72+sb_k]=a0.y; Bt[(cb+ 2)*72+sb_k]=a0.z; Bt[(cb+ 3)*72+sb_k]=a0.w;
            Bt[(cb+ 4)*72+sb_k]=a1.x; Bt[(cb+ 5)*72+sb_k]=a1.y; Bt[(cb+ 6)*72+sb_k]=a1.z; Bt[(cb+ 7)*72+sb_k]=a1.w;
            Bt[(cb+ 8)*72+sb_k]=a2.x; Bt[(cb+ 9)*72+sb_k]=a2.y; Bt[(cb+10)*72+sb_k]=a2.z; Bt[(cb+11)*72+sb_k]=a2.w;
            Bt[(cb+12)*72+sb_k]=a3.x; Bt[(cb+13)*72+sb_k]=a3.y; Bt[(cb+14)*72+sb_k]=a3.z; Bt[(cb+15)*72+sb_k]=a3.w;
        }
        __syncthreads();
        #pragma unroll
        for (int ks = 0; ks < 2; ks++){
            s16x8 af = *(const s16x8*)&At[(mt*16+lr)*72 + ks*32 + lg*8];
            #pragma unroll
            for (int q = 0; q < 4; q++){
                s16x8 bf = *(const s16x8*)&Bt[((ng*4+q)*16+lr)*72 + ks*32 + lg*8];
                acc[q] = __builtin_amdgcn_mfma_f32_16x16x32_bf16(af, bf, acc[q], 0, 0, 0);
            }
        }
        __syncthreads();
    }
    float tr = 0.f, sq = 0.f;
    #pragma unroll
    for (int q = 0; q < 4; q++){
        int col = (ng*4+q)*16 + lr;
        #pragma unroll
        for (int j = 0; j < 4; j++){
            int m = mt*16 + lg*4 + j;
            float v = acc[q][j];
            if (col < 128){
                P[((size_t)b*64+m)*128 + col] = v;
            } else if (col < 192){
                AP[((size_t)b*64+m)*64 + (col-128)] = v;
                if (col-128 == m) tr += v;
            } else {
                GR[((size_t)b*64+m)*64 + (col-192)] = v;
                sq += v*v;
            }
        }
    }
    for (int o = 32; o; o >>= 1){ tr += __shfl_xor(tr, o); sq += __shfl_xor(sq, o); }
    if (l == 0){ rtr[w] = tr; rsq[w] = sq; }
    __syncthreads();
    if (tid == 0){
        float str = 0.f, ssq = 0.f;
        for (int i = 0; i < 16; i++){ str += rtr[i]; ssq += rsq[i]; }
        atomicAdd(crossp, str);
        atomicAdd(normgp, ssq);
    }
}

// ---------------- head stage A: aggout[b] = (adjp[b] @ pooled[b]) / rowsum ----------------
__global__ void __launch_bounds__(256) k_heada(
        const float* __restrict__ AP, const float* __restrict__ P,
        float* __restrict__ aggout){
    __shared__ float sapT[64*65];
    __shared__ float sp[64*33];
    __shared__ float srs[64];
    int b = blockIdx.x, c0 = blockIdx.y*32;
    int tid = threadIdx.x;
    for (int i = tid; i < 4096; i += 256){
        int k = i >> 6, l = i & 63;
        sapT[l*65 + k] = AP[(size_t)b*4096 + i];
    }
    for (int i = tid; i < 2048; i += 256){
        int l = i >> 5, j = i & 31;
        sp[l*33 + j] = P[(size_t)b*8192 + l*128 + c0 + j];
    }
    __syncthreads();
    if (tid < 64){
        float s = 0.f;
        for (int l = 0; l < 64; l++) s += sapT[l*65 + tid];
        srs[tid] = fmaxf(s, 1.f);
    }
    __syncthreads();
    int k = tid & 63, jg = (tid >> 6)*8;
    float acc[8] = {};
    for (int l = 0; l < 64; l++){
        float a = sapT[l*65 + k];
        #pragma unroll
        for (int j = 0; j < 8; j++) acc[j] += a*sp[l*33 + jg + j];
    }
    float inv = 1.f/srs[k];
    #pragma unroll
    for (int j = 0; j < 8; j++)
        aggout[(size_t)b*8192 + k*128 + c0 + jg + j] = acc[j]*inv;
}

// ---------------- head stage C: hcacc[b,:] += h[b, chunk] @ Wc1[chunk, :] ----------------
__global__ void __launch_bounds__(256) k_head2(
        const float* __restrict__ hbuf, const float* __restrict__ Wc1,
        float* __restrict__ hcacc){
    __shared__ float sh[512];
    __shared__ float sred[256];
    int b = blockIdx.x >> 4, ch = blockIdx.x & 15;
    int tid = threadIdx.x;
    for (int i = tid; i < 512; i += 256) sh[i] = hbuf[(size_t)b*8192 + ch*512 + i];
    __syncthreads();
    int j = tid & 127, half = tid >> 7;
    float acc = 0.f;
    const float* W = Wc1 + (size_t)(ch*512 + half*256)*128;
    const float* hh = sh + half*256;
    for (int r = 0; r < 256; r++) acc += hh[r]*W[(size_t)r*128 + j];
    sred[tid] = acc; __syncthreads();
    if (tid < 128) atomicAdd(&hcacc[(size_t)b*128 + tid], sred[tid] + sred[tid+128]);
}

// ---------------- head stage D: logits ----------------
__global__ void k_head3(const float* __restrict__ hcacc, const float* __restrict__ bc1,
                        const float* __restrict__ Wc2, const float* __restrict__ bc2,
                        float* __restrict__ out){
    int b = blockIdx.x, t = threadIdx.x;   // 128 threads
    float hc = lky(hcacc[(size_t)b*128 + t] + bc1[t]);
    float p = hc*Wc2[t];
    for (int o = 32; o; o >>= 1) p += __shfl_xor(p, o);
    __shared__ float r2[2];
    if ((t & 63) == 0) r2[t >> 6] = p;
    __syncthreads();
    if (t == 0) out[b] = r2[0] + r2[1] + bc2[0];
}

__global__ void k_finalize(const unsigned int* __restrict__ a2,
                           const float* __restrict__ cross,
                           const float* __restrict__ normg,
                           const float* __restrict__ ent,
                           float* __restrict__ out){
    float ss = (float)(*a2) - 2.f*(*cross) + (*normg);
    if (ss < 0.f) ss = 0.f;
    float link = sqrtf(ss) / 67108864.f;     // a.size
    out[64] = link + (*ent)/(float)NT;
}

extern "C" void kernel_launch(void* const* d_in, const int* in_sizes, int n_in,
                              void* d_out, int out_size, void* d_ws, size_t ws_size,
                              hipStream_t stream){
    const float* x    = (const float*)d_in[0];
    const int*   ei   = (const int*)d_in[1];
    const int*   src  = ei;
    const int*   dst  = ei + ETOT;
    const float* W1l  = (const float*)d_in[5];
    const float* b1l  = (const float*)d_in[6];
    const float* W1r  = (const float*)d_in[7];
    const float* W2l  = (const float*)d_in[8];
    const float* b2l  = (const float*)d_in[9];
    const float* W2r  = (const float*)d_in[10];
    const float* Wm   = (const float*)d_in[11];
    const float* bm   = (const float*)d_in[12];
    const float* Wrel = (const float*)d_in[13];
    const float* Wroot= (const float*)d_in[14];
    const float* broot= (const float*)d_in[15];
    const float* Wc1  = (const float*)d_in[16];
    const float* bc1  = (const float*)d_in[17];
    const float* Wc2  = (const float*)d_in[18];
    const float* bc2  = (const float*)d_in[19];
    float* out = (float*)d_out;

    char* w = (char*)d_ws;
    size_t off = 0;
    auto take = [&](size_t bytes)->void*{
        void* p = w + off; off = (off + bytes + 255) & ~(size_t)255; return p;
    };
    const size_t MB = 1024*1024;
    // --- small zeroed zone ---
    int*   cnt_d  = (int*)take((size_t)NT*4);
    int*   cnt_s  = (int*)take((size_t)NT*4);
    int*   cur_d  = (int*)take((size_t)NT*4);
    int*   cur_s  = (int*)take((size_t)NT*4);
    float* hcacc  = (float*)take((size_t)BATCH*128*4);
    int*   tots   = (int*)take(2*64*4);
    float* accb   = (float*)take(64);
    size_t zero_small = off;
    // --- non-zeroed ---
    float* pooled = (float*)take((size_t)BATCH*64*128*4);
    float* adjp   = (float*)take((size_t)BATCH*64*64*4);
    float* gram   = (float*)take((size_t)BATCH*64*64*4);
    int*   ipd   = (int*)take((size_t)(NT+1)*4);
    int*   ips   = (int*)take((size_t)(NT+1)*4);
    int*   lst_d = (int*)take((size_t)ETOT*4);
    int*   lst_s = (int*)take((size_t)ETOT*4);
    char*  regA  = (char*)take(16*MB);   // agg2 (f32)
    char*  regB  = (char*)take(16*MB);   // y1h -> r2 -> th
    char*  regC  = (char*)take(16*MB);   // r1h -> [y2h | s2h]
    char*  regD  = (char*)take(16*MB);   // agg1h
    char*  regE  = (char*)take(16*MB);   // zh
    float* hbuf  = (float*)take((size_t)BATCH*8192*4);
    float* aggo  = (float*)take((size_t)BATCH*8192*4);

    unsigned short* y1h   = (unsigned short*)regB;
    float*          r2    = (float*)regB;
    unsigned short* th    = (unsigned short*)regB;
    unsigned short* r1h   = (unsigned short*)regC;
    unsigned short* y2h   = (unsigned short*)regC;
    unsigned short* s2h   = (unsigned short*)(regC + 8*MB);
    unsigned short* agg1h = (unsigned short*)regD;
    unsigned short* zh    = (unsigned short*)regE;
    float*          agg2  = (float*)regA;

    float* crossp = accb + 0;
    float* normgp = accb + 1;
    float* entp   = accb + 2;
    unsigned int* a2p = (unsigned int*)(accb + 3);

    hipMemsetAsync(d_ws, 0, zero_small, stream);

    // sum(a^2) via LDS nibble hist; pass 0 also produces CSR degree counts
    k_a2lds<<<dim3(BATCH, 4), 1024, 0, stream>>>(src, dst, a2p, cnt_d, cnt_s);

    // CSR build
    k_scan_local<<<dim3(64,2), 1024, 0, stream>>>(cnt_d, cnt_s, ipd, ips, tots);
    k_scan_add<<<dim3(64,2), 1024, 0, stream>>>(tots, ipd, ips);
    k_fill<<<ETOT/256, 256, 0, stream>>>(src, dst, ipd, ips, cur_d, cur_s, lst_d, lst_s);

    // SAGE layer 1 (GEMM-before-gather, MFMA): y1 = x@W1l (bf16), r1 = x@W1r (bf16)
    k_mfma2b<128,1,1><<<NT/64, 256, 0, stream>>>(x, W1l, W1r, y1h, r1h);
    k_aggh<64,1><<<NT/4, 256, 0, stream>>>(y1h, ipd, lst_d, agg1h, 1);
    k_fin1<<<NT*128/8/256, 256, 0, stream>>>((const uint4*)agg1h, (const uint4*)r1h, b1l, (uint4*)zh);

    // SAGE layer 2 (MFMA): y2 = z@W2l (bf16), r2 = z@W2r (f32)
    k_mfma2b<64,0,0><<<NT/64, 256, 0, stream>>>(zh, W2l, W2r, y2h, r2);
    k_aggh<32,0><<<NT/8, 256, 0, stream>>>(y2h, ipd, lst_d, agg2, 1);
    // fused: spre = lky(agg2+r2+b2l); s = softmax(spre@Wm+bm) -> s2h bf16; ent
    k_gemm_wm<<<NT/64, 256, 0, stream>>>(agg2, r2, b2l, Wm, bm, s2h, entp);

    // t = A @ s (bf16 out; overwrites regB which is dead after gemm_wm)
    k_aggh<32,1><<<NT/8, 256, 0, stream>>>(s2h, ips, lst_s, th, 0);

    // fused MFMA: pooled/adjp/gram + trace(cross) + ||gram||^2(normg)
    k_spmm<<<BATCH, 1024, 0, stream>>>(s2h, zh, th, pooled, adjp, gram, crossp, normgp);

    // head: A (agg), B (dual GEMM fp32), C (split-K), D (logits)
    k_heada<<<dim3(BATCH, 4), 256, 0, stream>>>(adjp, pooled, aggo);
    k_gemm<<<dim3(BATCH*64/64, 2), 256, 0, stream>>>(aggo, pooled, Wrel, Wroot, broot, hbuf, BATCH*64, 128, 128, 1, 1, 0);
    k_head2<<<BATCH*16, 256, 0, stream>>>(hbuf, Wc1, hcacc);
    k_head3<<<BATCH, 128, 0, stream>>>(hcacc, bc1, Wc2, bc2, out);
    k_finalize<<<1, 1, 0, stream>>>(a2p, crossp, normgp, entp, out);
}

// Round 8
// 577.152 us; speedup vs baseline: 5.9813x; 1.3029x over previous
//
#include <hip/hip_runtime.h>
#include <math.h>

#define BATCH 64
#define NPG 1024
#define NT (BATCH*NPG)        // 65536 nodes
#define EPER 32768
#define ETOT (BATCH*EPER)     // 2097152 edges

typedef __attribute__((ext_vector_type(4))) float f32x4;
typedef __attribute__((ext_vector_type(8))) short s16x8;

__device__ __forceinline__ float lky(float x){ return x > 0.f ? x : 0.01f*x; }
__device__ __forceinline__ unsigned short f2bf(float f){
    unsigned u = __float_as_uint(f);
    u = u + 0x7FFFu + ((u >> 16) & 1u);      // RNE
    return (unsigned short)(u >> 16);
}
__device__ __forceinline__ float bf2f_lo(unsigned v){ return __uint_as_float(v << 16); }
__device__ __forceinline__ float bf2f_hi(unsigned v){ return __uint_as_float(v & 0xFFFF0000u); }

// ---------------- sum(a^2) via per-graph LDS nibble histogram (+ degree counts on pass 0) ----------------
__global__ void __launch_bounds__(1024) k_a2lds(const int* __restrict__ src, const int* __restrict__ dst,
                                                unsigned* __restrict__ acc_out, int* cnt_d, int* cnt_s){
    __shared__ unsigned nib[32768];   // 128 KB = 262144 nibble counters
    __shared__ unsigned red[16];
    int b = blockIdx.x, pass = blockIdx.y, tid = threadIdx.x;
    for (int i = tid; i < 32768; i += 1024) nib[i] = 0;
    __syncthreads();
    int base = b*EPER;
    for (int i = tid; i < EPER; i += 1024){
        int sv = src[base+i], dv = dst[base+i];
        if (pass == 0){ atomicAdd(&cnt_d[dv], 1); atomicAdd(&cnt_s[sv], 1); }
        unsigned key = (((unsigned)sv & 1023u) << 10) | ((unsigned)dv & 1023u);
        if ((int)(key >> 18) == pass)
            atomicAdd(&nib[(key & 0x3FFFFu) >> 3], 1u << ((key & 7u)*4u));
    }
    __syncthreads();
    unsigned local = 0;
    for (int i = tid; i < 32768; i += 1024){
        unsigned w = nib[i];
        if (w){
            #pragma unroll
            for (int q = 0; q < 8; q++){ unsigned c = (w >> (4*q)) & 15u; local += c*c; }
        }
    }
    for (int o = 32; o; o >>= 1) local += __shfl_xor(local, o);
    if ((tid & 63) == 0) red[tid >> 6] = local;
    __syncthreads();
    if (tid == 0){
        unsigned s = 0;
        for (int q = 0; q < 16; q++) s += red[q];
        atomicAdd(acc_out, s);
    }
}

// ---------------- CSR scans + fill ----------------
__global__ void k_scan_local(const int* __restrict__ cnt_d, const int* __restrict__ cnt_s,
                             int* __restrict__ ipd, int* __restrict__ ips, int* __restrict__ tots){
    __shared__ int buf[1024];
    int which = blockIdx.y;
    const int* cnt = which ? cnt_s : cnt_d;
    int* ip = which ? ips : ipd;
    int base = blockIdx.x*1024;
    int tid = threadIdx.x;
    int v = cnt[base + tid];
    int x = v;
    buf[tid] = x; __syncthreads();
    for (int off = 1; off < 1024; off <<= 1){
        int t = (tid >= off) ? buf[tid - off] : 0;
        __syncthreads();
        x += t; buf[tid] = x; __syncthreads();
    }
    ip[base + tid] = x - v;
    if (tid == 1023) tots[which*64 + blockIdx.x] = x;
}

__global__ void k_scan_add(const int* __restrict__ tots, int* __restrict__ ipd, int* __restrict__ ips){
    int which = blockIdx.y;
    int* ip = which ? ips : ipd;
    const int* t = tots + which*64;
    __shared__ int soff;
    if (threadIdx.x == 0){
        int s = 0;
        for (int i = 0; i < (int)blockIdx.x; i++) s += t[i];
        soff = s;
    }
    __syncthreads();
    ip[blockIdx.x*1024 + threadIdx.x] += soff;
    if (blockIdx.x == 0 && threadIdx.x == 0) ip[NT] = ETOT;
}

// XCD-swizzled edge fill: blocks of one graph -> one XCD (128 blocks/graph)
__global__ void k_fill(const int* __restrict__ src, const int* __restrict__ dst,
                       const int* __restrict__ ipd, const int* __restrict__ ips,
                       int* cur_d, int* cur_s, int* lst_d, int* lst_s){
    int bid = blockIdx.x;                 // 8192 blocks
    int xcd = bid & 7, j = bid >> 3;
    int gi = j >> 7, chunk = j & 127;
    int graph = xcd + 8*gi;
    int e = graph*EPER + chunk*256 + threadIdx.x;
    int s = src[e], d = dst[e];
    int p = atomicAdd(&cur_d[d], 1); lst_d[ipd[d] + p] = s;
    int q = atomicAdd(&cur_s[s], 1); lst_s[ips[s] + q] = d;
}

// ---------------- bf16 segment gather, XCD-swizzled; G threads/node, 4 feats/thread ----------------
// feature dim D = 4*G. G=32 -> D=128, G=16 -> D=64.
template<int G, int OBF>
__global__ void k_aggh(const unsigned short* __restrict__ X, const int* __restrict__ indptr,
                       const int* __restrict__ lst, void* __restrict__ out, int do_mean){
    constexpr int NPB = 256/G;        // nodes per block
    constexpr int BPG = NPG/NPB;      // blocks per graph (pow2: 128 or 64)
    int bid = blockIdx.x;
    int xcd = bid & 7, j = bid >> 3;
    int gi = j/BPG, chunk = j - gi*BPG;
    int graph = xcd + 8*gi;
    int node = graph*NPG + chunk*NPB + threadIdx.x/G;
    int g = threadIdx.x % G;
    int st = indptr[node], en = indptr[node+1];
    float a0 = 0.f, a1 = 0.f, a2 = 0.f, a3 = 0.f;
    const unsigned short* Xg = X + 4*g;
    #pragma unroll 2
    for (int e = st; e < en; e++){
        int nb = lst[e];
        uint2 v = *(const uint2*)&Xg[(size_t)nb*(4*G)];
        a0 += bf2f_lo(v.x); a1 += bf2f_hi(v.x);
        a2 += bf2f_lo(v.y); a3 += bf2f_hi(v.y);
    }
    if (do_mean){
        int dg = en - st;
        float inv = 1.f/(float)(dg > 1 ? dg : 1);
        a0 *= inv; a1 *= inv; a2 *= inv; a3 *= inv;
    }
    if (OBF){
        uint2 pk;
        pk.x = (unsigned)f2bf(a0) | ((unsigned)f2bf(a1) << 16);
        pk.y = (unsigned)f2bf(a2) | ((unsigned)f2bf(a3) << 16);
        ((uint2*)out)[(size_t)node*G + g] = pk;
    } else {
        float4 o = { a0, a1, a2, a3 };
        ((float4*)out)[(size_t)node*G + g] = o;
    }
}

// ---------------- MFMA dual-B GEMM: C1 = A@W1 (bf16), C2 = A@W2 (bf16 or f32); K=128 ----------------
template<int N, int AF32, int OBF2>
__global__ void __launch_bounds__(256) k_mfma2b(
        const void* __restrict__ Ain, const float* __restrict__ W1,
        const float* __restrict__ W2, unsigned short* __restrict__ C1,
        void* __restrict__ C2){
    __shared__ unsigned short ldsB[2*N*128];
    int tid = threadIdx.x;
    for (int i = tid; i < 128*N; i += 256){
        int k = i / N, n = i - k*N;
        int swz = (n*256 + 2*k) ^ ((n & 7) << 4);
        *(unsigned short*)((char*)ldsB + swz)          = f2bf(W1[i]);
        *(unsigned short*)((char*)ldsB + N*256 + swz)  = f2bf(W2[i]);
    }
    __syncthreads();
    int wave = tid >> 6, l = tid & 63;
    int lr = l & 15, lg = l >> 4;
    int arow = blockIdx.x*64 + wave*16 + lr;
    constexpr int NF = N/16;
    f32x4 acc1[NF], acc2[NF];
    f32x4 zv = {0.f, 0.f, 0.f, 0.f};
    #pragma unroll
    for (int nf = 0; nf < NF; nf++){ acc1[nf] = zv; acc2[nf] = zv; }
    const unsigned short* Ah = (const unsigned short*)Ain;
    const float* Af = (const float*)Ain;
    #pragma unroll
    for (int ks = 0; ks < 4; ks++){
        s16x8 af;
        if (AF32){
            const float* p = Af + (size_t)arow*128 + ks*32 + lg*8;
            float4 v0 = *(const float4*)p;
            float4 v1 = *(const float4*)(p + 4);
            af[0] = (short)f2bf(v0.x); af[1] = (short)f2bf(v0.y);
            af[2] = (short)f2bf(v0.z); af[3] = (short)f2bf(v0.w);
            af[4] = (short)f2bf(v1.x); af[5] = (short)f2bf(v1.y);
            af[6] = (short)f2bf(v1.z); af[7] = (short)f2bf(v1.w);
        } else {
            af = *(const s16x8*)(Ah + (size_t)arow*128 + ks*32 + lg*8);
        }
        #pragma unroll
        for (int nf = 0; nf < NF; nf++){
            int n = nf*16 + lr;
            int swz = (n*256 + ks*64 + lg*16) ^ ((n & 7) << 4);
            s16x8 b1 = *(const s16x8*)((const char*)ldsB + swz);
            s16x8 b2 = *(const s16x8*)((const char*)ldsB + N*256 + swz);
            acc1[nf] = __builtin_amdgcn_mfma_f32_16x16x32_bf16(af, b1, acc1[nf], 0, 0, 0);
            acc2[nf] = __builtin_amdgcn_mfma_f32_16x16x32_bf16(af, b2, acc2[nf], 0, 0, 0);
        }
    }
    int orow = blockIdx.x*64 + wave*16 + lg*4;
    #pragma unroll
    for (int nf = 0; nf < NF; nf++){
        int c = nf*16 + lr;
        #pragma unroll
        for (int j = 0; j < 4; j++){
            size_t idx = (size_t)(orow + j)*N + c;
            C1[idx] = f2bf(acc1[nf][j]);
            if (OBF2) ((unsigned short*)C2)[idx] = f2bf(acc2[nf][j]);
            else      ((float*)C2)[idx] = acc2[nf][j];
        }
    }
}

// ---------------- z = lky(agg1h + r1h + b1l) -> zh bf16 (8 elems/thread) ----------------
__global__ void k_fin1(const uint4* __restrict__ agg1h, const uint4* __restrict__ r1h,
                       const float* __restrict__ b1l, uint4* __restrict__ zh){
    size_t i = (size_t)blockIdx.x*256 + threadIdx.x;   // NT*128/8 items
    uint4 a = agg1h[i], r = r1h[i];
    int c0 = ((int)(i & 15))*8;
    unsigned av[4] = {a.x, a.y, a.z, a.w};
    unsigned rv[4] = {r.x, r.y, r.z, r.w};
    unsigned ov[4];
    #pragma unroll
    for (int q = 0; q < 4; q++){
        float z0 = lky(bf2f_lo(av[q]) + bf2f_lo(rv[q]) + b1l[c0 + 2*q]);
        float z1 = lky(bf2f_hi(av[q]) + bf2f_hi(rv[q]) + b1l[c0 + 2*q + 1]);
        ov[q] = (unsigned)f2bf(z0) | ((unsigned)f2bf(z1) << 16);
    }
    uint4 o = {ov[0], ov[1], ov[2], ov[3]};
    zh[i] = o;
}

// ---------------- fp32 dual GEMM (head only): C = act(A1@W1 [+ A2@W2] + bias) ----------------
__global__ void __launch_bounds__(256) k_gemm(
        const float* __restrict__ A1, const float* __restrict__ A2,
        const float* __restrict__ W1, const float* __restrict__ W2,
        const float* __restrict__ bias, void* __restrict__ C,
        int M, int Nn, int Kd, int dual, int act, int obf){
    __shared__ float sA1[16*68], sB1[16*68], sA2[16*68], sB2[16*68];
    int tid = threadIdx.x;
    int m0 = blockIdx.x*64, n0 = blockIdx.y*64;
    int tx = tid & 15, ty = tid >> 4;
    int lr = tid >> 2, lk = (tid & 3)*4;
    int wk = tid >> 4, wn = (tid & 15)*4;
    float acc[4][4] = {};
    for (int k0 = 0; k0 < Kd; k0 += 16){
        float4 a1 = *(const float4*)&A1[(size_t)(m0+lr)*Kd + k0 + lk];
        float4 w1 = *(const float4*)&W1[(size_t)(k0+wk)*Nn + n0 + wn];
        sA1[(lk+0)*68+lr] = a1.x; sA1[(lk+1)*68+lr] = a1.y;
        sA1[(lk+2)*68+lr] = a1.z; sA1[(lk+3)*68+lr] = a1.w;
        *(float4*)&sB1[wk*68+wn] = w1;
        if (dual){
            float4 a2 = *(const float4*)&A2[(size_t)(m0+lr)*Kd + k0 + lk];
            float4 w2 = *(const float4*)&W2[(size_t)(k0+wk)*Nn + n0 + wn];
            sA2[(lk+0)*68+lr] = a2.x; sA2[(lk+1)*68+lr] = a2.y;
            sA2[(lk+2)*68+lr] = a2.z; sA2[(lk+3)*68+lr] = a2.w;
            *(float4*)&sB2[wk*68+wn] = w2;
        }
        __syncthreads();
        #pragma unroll
        for (int kk = 0; kk < 16; kk++){
            float4 av = *(const float4*)&sA1[kk*68 + ty*4];
            float4 bv = *(const float4*)&sB1[kk*68 + tx*4];
            float a[4] = {av.x, av.y, av.z, av.w};
            float b[4] = {bv.x, bv.y, bv.z, bv.w};
            #pragma unroll
            for (int i = 0; i < 4; i++)
                #pragma unroll
                for (int j = 0; j < 4; j++) acc[i][j] += a[i]*b[j];
            if (dual){
                float4 av2 = *(const float4*)&sA2[kk*68 + ty*4];
                float4 bv2 = *(const float4*)&sB2[kk*68 + tx*4];
                float a2[4] = {av2.x, av2.y, av2.z, av2.w};
                float b2[4] = {bv2.x, bv2.y, bv2.z, bv2.w};
                #pragma unroll
                for (int i = 0; i < 4; i++)
                    #pragma unroll
                    for (int j = 0; j < 4; j++) acc[i][j] += a2[i]*b2[j];
            }
        }
        __syncthreads();
    }
    float bb[4] = {0.f, 0.f, 0.f, 0.f};
    if (bias){
        #pragma unroll
        for (int j = 0; j < 4; j++) bb[j] = bias[n0 + tx*4 + j];
    }
    #pragma unroll
    for (int i = 0; i < 4; i++){
        float v0 = acc[i][0]+bb[0], v1 = acc[i][1]+bb[1], v2 = acc[i][2]+bb[2], v3 = acc[i][3]+bb[3];
        if (act){ v0 = lky(v0); v1 = lky(v1); v2 = lky(v2); v3 = lky(v3); }
        size_t idx = (size_t)(m0 + ty*4 + i)*Nn + n0 + tx*4;
        if (obf){
            ushort4 o = { f2bf(v0), f2bf(v1), f2bf(v2), f2bf(v3) };
            *(ushort4*)&((unsigned short*)C)[idx] = o;
        } else {
            float4 o = { v0, v1, v2, v3 };
            *(float4*)&((float*)C)[idx] = o;
        }
    }
}

// ---------------- fused: spre = lky(agg2 + r2 + b2l); s = softmax(spre@Wm + bm); ent; bf16 out ----------------
__global__ void __launch_bounds__(256) k_gemm_wm(
        const float* __restrict__ agg2, const float* __restrict__ r2,
        const float* __restrict__ b2l, const float* __restrict__ Wm,
        const float* __restrict__ bm,
        unsigned short* __restrict__ Sh, float* __restrict__ ent_acc){
    __shared__ float sA[16*68], sB[16*68];
    __shared__ float red[256];
    int tid = threadIdx.x;
    int m0 = blockIdx.x*64;
    int tx = tid & 15, ty = tid >> 4;
    int lr = tid >> 2, lk = (tid & 3)*4;
    int wk = tid >> 4, wn = (tid & 15)*4;
    float acc[4][4] = {};
    for (int k0 = 0; k0 < 64; k0 += 16){
        float4 a = *(const float4*)&agg2[(size_t)(m0+lr)*64 + k0 + lk];
        float4 r = *(const float4*)&r2[(size_t)(m0+lr)*64 + k0 + lk];
        sA[(lk+0)*68+lr] = lky(a.x + r.x + b2l[k0+lk+0]);
        sA[(lk+1)*68+lr] = lky(a.y + r.y + b2l[k0+lk+1]);
        sA[(lk+2)*68+lr] = lky(a.z + r.z + b2l[k0+lk+2]);
        sA[(lk+3)*68+lr] = lky(a.w + r.w + b2l[k0+lk+3]);
        *(float4*)&sB[wk*68+wn] = *(const float4*)&Wm[(size_t)(k0+wk)*64 + wn];
        __syncthreads();
        #pragma unroll
        for (int kk = 0; kk < 16; kk++){
            float4 av = *(const float4*)&sA[kk*68 + ty*4];
            float4 bv = *(const float4*)&sB[kk*68 + tx*4];
            float a4[4] = {av.x, av.y, av.z, av.w};
            float b4[4] = {bv.x, bv.y, bv.z, bv.w};
            #pragma unroll
            for (int i = 0; i < 4; i++)
                #pragma unroll
                for (int j = 0; j < 4; j++) acc[i][j] += a4[i]*b4[j];
        }
        __syncthreads();
    }
    float bb[4];
    #pragma unroll
    for (int j = 0; j < 4; j++) bb[j] = bm[tx*4 + j];
    float ent_local = 0.f;
    #pragma unroll
    for (int i = 0; i < 4; i++){
        float v[4];
        #pragma unroll
        for (int j = 0; j < 4; j++) v[j] = acc[i][j] + bb[j];
        float m = fmaxf(fmaxf(v[0], v[1]), fmaxf(v[2], v[3]));
        for (int o = 1; o < 16; o <<= 1) m = fmaxf(m, __shfl_xor(m, o));
        float e[4];
        float sm = 0.f;
        #pragma unroll
        for (int j = 0; j < 4; j++){ e[j] = __expf(v[j] - m); sm += e[j]; }
        for (int o = 1; o < 16; o <<= 1) sm += __shfl_xor(sm, o);
        float inv = 1.f/sm;
        float p[4];
        float w = 0.f;
        #pragma unroll
        for (int j = 0; j < 4; j++){
            p[j] = e[j]*inv;
            w += -p[j]*__logf(p[j] + 1e-15f);
        }
        for (int o = 1; o < 16; o <<= 1) w += __shfl_xor(w, o);
        if (tx == 0) ent_local += w;
        size_t idx = (size_t)(m0 + ty*4 + i)*64 + tx*4;
        ushort4 oh = { f2bf(p[0]), f2bf(p[1]), f2bf(p[2]), f2bf(p[3]) };
        *(ushort4*)&Sh[idx] = oh;
    }
    red[tid] = ent_local; __syncthreads();
    for (int o = 128; o; o >>= 1){ if (tid < o) red[tid] += red[tid+o]; __syncthreads(); }
    if (tid == 0) atomicAdd(ent_acc, red[0]);
}

// ---------------- fused MFMA: [pooled | adjp | gram] = s^T @ [z | t | s] per graph ----------------
__global__ void __launch_bounds__(1024) k_spmm(
        const unsigned short* __restrict__ Sh, const unsigned short* __restrict__ Zh,
        const unsigned short* __restrict__ Th,
        float* __restrict__ P, float* __restrict__ AP, float* __restrict__ GR,
        float* __restrict__ crossp, float* __restrict__ normgp){
    __shared__ unsigned short At[64*72];    // A^T: [m up to 64][k 64]
    __shared__ unsigned short Bt[256*72];   // B^T: [col 256][k 64]
    __shared__ float rtr[16], rsq[16];
    int b = blockIdx.x, tid = threadIdx.x;
    int w = tid >> 6, l = tid & 63;
    int lr = l & 15, lg = l >> 4;
    int mt = w & 3, ng = w >> 2;
    f32x4 acc[4];
    f32x4 zv = {0.f, 0.f, 0.f, 0.f};
    #pragma unroll
    for (int q = 0; q < 4; q++) acc[q] = zv;
    int gb = b*NPG;
    int sa_n = tid & 63, sa_c = (tid >> 6)*4;
    int sb_k = tid & 63, sb_g = tid >> 6;
    for (int n0 = 0; n0 < NPG; n0 += 64){
        ushort4 sv = *(const ushort4*)&Sh[(size_t)(gb+n0+sa_n)*64 + sa_c];
        At[(sa_c+0)*72 + sa_n] = sv.x;
        At[(sa_c+1)*72 + sa_n] = sv.y;
        At[(sa_c+2)*72 + sa_n] = sv.z;
        At[(sa_c+3)*72 + sa_n] = sv.w;
        {
            int R = gb + n0 + sb_k;
            const unsigned short* srcp;
            if (sb_g < 8)       srcp = &Zh[(size_t)R*128 + sb_g*16];
            else if (sb_g < 12) srcp = &Th[(size_t)R*64 + (sb_g-8)*16];
            else                srcp = &Sh[(size_t)R*64 + (sb_g-12)*16];
            ushort4 a0 = *(const ushort4*)(srcp);
            ushort4 a1 = *(const ushort4*)(srcp+4);
            ushort4 a2 = *(const ushort4*)(srcp+8);
            ushort4 a3 = *(const ushort4*)(srcp+12);
            int cb = sb_g*16;
            Bt[(cb+ 0)*72+sb_k]=a0.x; Bt[(cb+ 1)*72+sb_k]=a0.y; Bt[(cb+ 2)*72+sb_k]=a0.z; Bt[(cb+ 3)*72+sb_k]=a0.w;
            Bt[(cb+ 4)*72+sb_k]=a1.x; Bt[(cb+ 5)*72+sb_k]=a1.y; Bt[(cb+ 6)*72+sb_k]=a1.z; Bt[(cb+ 7)*72+sb_k]=a1.w;
            Bt[(cb+ 8)*72+sb_k]=a2.x; Bt[(cb+ 9)*72+sb_k]=a2.y; Bt[(cb+10)*72+sb_k]=a2.z; Bt[(cb+11)*72+sb_k]=a2.w;
            Bt[(cb+12)*72+sb_k]=a3.x; Bt[(cb+13)*72+sb_k]=a3.y; Bt[(cb+14)*72+sb_k]=a3.z; Bt[(cb+15)*72+sb_k]=a3.w;
        }
        __syncthreads();
        #pragma unroll
        for (int ks = 0; ks < 2; ks++){
            s16x8 af = *(const s16x8*)&At[(mt*16+lr)*72 + ks*32 + lg*8];
            #pragma unroll
            for (int q = 0; q < 4; q++){
                s16x8 bf = *(const s16x8*)&Bt[((ng*4+q)*16+lr)*72 + ks*32 + lg*8];
                acc[q] = __builtin_amdgcn_mfma_f32_16x16x32_bf16(af, bf, acc[q], 0, 0, 0);
            }
        }
        __syncthreads();
    }
    float tr = 0.f, sq = 0.f;
    #pragma unroll
    for (int q = 0; q < 4; q++){
        int col = (ng*4+q)*16 + lr;
        #pragma unroll
        for (int j = 0; j < 4; j++){
            int m = mt*16 + lg*4 + j;
            float v = acc[q][j];
            if (col < 128){
                P[((size_t)b*64+m)*128 + col] = v;
            } else if (col < 192){
                AP[((size_t)b*64+m)*64 + (col-128)] = v;
                if (col-128 == m) tr += v;
            } else {
                GR[((size_t)b*64+m)*64 + (col-192)] = v;
                sq += v*v;
            }
        }
    }
    for (int o = 32; o; o >>= 1){ tr += __shfl_xor(tr, o); sq += __shfl_xor(sq, o); }
    if (l == 0){ rtr[w] = tr; rsq[w] = sq; }
    __syncthreads();
    if (tid == 0){
        float str = 0.f, ssq = 0.f;
        for (int i = 0; i < 16; i++){ str += rtr[i]; ssq += rsq[i]; }
        atomicAdd(crossp, str);
        atomicAdd(normgp, ssq);
    }
}

// ---------------- head stage A: aggout[b] = (adjp[b] @ pooled[b]) / rowsum ----------------
__global__ void __launch_bounds__(256) k_heada(
        const float* __restrict__ AP, const float* __restrict__ P,
        float* __restrict__ aggout){
    __shared__ float sapT[64*65];
    __shared__ float sp[64*33];
    __shared__ float srs[64];
    int b = blockIdx.x, c0 = blockIdx.y*32;
    int tid = threadIdx.x;
    for (int i = tid; i < 4096; i += 256){
        int k = i >> 6, l = i & 63;
        sapT[l*65 + k] = AP[(size_t)b*4096 + i];
    }
    for (int i = tid; i < 2048; i += 256){
        int l = i >> 5, j = i & 31;
        sp[l*33 + j] = P[(size_t)b*8192 + l*128 + c0 + j];
    }
    __syncthreads();
    if (tid < 64){
        float s = 0.f;
        for (int l = 0; l < 64; l++) s += sapT[l*65 + tid];
        srs[tid] = fmaxf(s, 1.f);
    }
    __syncthreads();
    int k = tid & 63, jg = (tid >> 6)*8;
    float acc[8] = {};
    for (int l = 0; l < 64; l++){
        float a = sapT[l*65 + k];
        #pragma unroll
        for (int j = 0; j < 8; j++) acc[j] += a*sp[l*33 + jg + j];
    }
    float inv = 1.f/srs[k];
    #pragma unroll
    for (int j = 0; j < 8; j++)
        aggout[(size_t)b*8192 + k*128 + c0 + jg + j] = acc[j]*inv;
}

// ---------------- head stage C: hcacc[b,:] += h[b, chunk] @ Wc1[chunk, :] ----------------
__global__ void __launch_bounds__(256) k_head2(
        const float* __restrict__ hbuf, const float* __restrict__ Wc1,
        float* __restrict__ hcacc){
    __shared__ float sh[512];
    __shared__ float sred[256];
    int b = blockIdx.x >> 4, ch = blockIdx.x & 15;
    int tid = threadIdx.x;
    for (int i = tid; i < 512; i += 256) sh[i] = hbuf[(size_t)b*8192 + ch*512 + i];
    __syncthreads();
    int j = tid & 127, half = tid >> 7;
    float acc = 0.f;
    const float* W = Wc1 + (size_t)(ch*512 + half*256)*128;
    const float* hh = sh + half*256;
    for (int r = 0; r < 256; r++) acc += hh[r]*W[(size_t)r*128 + j];
    sred[tid] = acc; __syncthreads();
    if (tid < 128) atomicAdd(&hcacc[(size_t)b*128 + tid], sred[tid] + sred[tid+128]);
}

// ---------------- head stage D: logits ----------------
__global__ void k_head3(const float* __restrict__ hcacc, const float* __restrict__ bc1,
                        const float* __restrict__ Wc2, const float* __restrict__ bc2,
                        float* __restrict__ out){
    int b = blockIdx.x, t = threadIdx.x;   // 128 threads
    float hc = lky(hcacc[(size_t)b*128 + t] + bc1[t]);
    float p = hc*Wc2[t];
    for (int o = 32; o; o >>= 1) p += __shfl_xor(p, o);
    __shared__ float r2[2];
    if ((t & 63) == 0) r2[t >> 6] = p;
    __syncthreads();
    if (t == 0) out[b] = r2[0] + r2[1] + bc2[0];
}

__global__ void k_finalize(const unsigned int* __restrict__ a2,
                           const float* __restrict__ cross,
                           const float* __restrict__ normg,
                           const float* __restrict__ ent,
                           float* __restrict__ out){
    float ss = (float)(*a2) - 2.f*(*cross) + (*normg);
    if (ss < 0.f) ss = 0.f;
    float link = sqrtf(ss) / 67108864.f;     // a.size
    out[64] = link + (*ent)/(float)NT;
}

extern "C" void kernel_launch(void* const* d_in, const int* in_sizes, int n_in,
                              void* d_out, int out_size, void* d_ws, size_t ws_size,
                              hipStream_t stream){
    const float* x    = (const float*)d_in[0];
    const int*   ei   = (const int*)d_in[1];
    const int*   src  = ei;
    const int*   dst  = ei + ETOT;
    const float* W1l  = (const float*)d_in[5];
    const float* b1l  = (const float*)d_in[6];
    const float* W1r  = (const float*)d_in[7];
    const float* W2l  = (const float*)d_in[8];
    const float* b2l  = (const float*)d_in[9];
    const float* W2r  = (const float*)d_in[10];
    const float* Wm   = (const float*)d_in[11];
    const float* bm   = (const float*)d_in[12];
    const float* Wrel = (const float*)d_in[13];
    const float* Wroot= (const float*)d_in[14];
    const float* broot= (const float*)d_in[15];
    const float* Wc1  = (const float*)d_in[16];
    const float* bc1  = (const float*)d_in[17];
    const float* Wc2  = (const float*)d_in[18];
    const float* bc2  = (const float*)d_in[19];
    float* out = (float*)d_out;

    char* w = (char*)d_ws;
    size_t off = 0;
    auto take = [&](size_t bytes)->void*{
        void* p = w + off; off = (off + bytes + 255) & ~(size_t)255; return p;
    };
    const size_t MB = 1024*1024;
    // --- small zeroed zone ---
    int*   cnt_d  = (int*)take((size_t)NT*4);
    int*   cnt_s  = (int*)take((size_t)NT*4);
    int*   cur_d  = (int*)take((size_t)NT*4);
    int*   cur_s  = (int*)take((size_t)NT*4);
    float* hcacc  = (float*)take((size_t)BATCH*128*4);
    int*   tots   = (int*)take(2*64*4);
    float* accb   = (float*)take(64);
    size_t zero_small = off;
    // --- non-zeroed ---
    float* pooled = (float*)take((size_t)BATCH*64*128*4);
    float* adjp   = (float*)take((size_t)BATCH*64*64*4);
    float* gram   = (float*)take((size_t)BATCH*64*64*4);
    int*   ipd   = (int*)take((size_t)(NT+1)*4);
    int*   ips   = (int*)take((size_t)(NT+1)*4);
    int*   lst_d = (int*)take((size_t)ETOT*4);
    int*   lst_s = (int*)take((size_t)ETOT*4);
    char*  regA  = (char*)take(16*MB);   // agg2 (f32)
    char*  regB  = (char*)take(16*MB);   // y1h -> r2 -> th
    char*  regC  = (char*)take(16*MB);   // r1h -> [y2h | s2h]
    char*  regD  = (char*)take(16*MB);   // agg1h
    char*  regE  = (char*)take(16*MB);   // zh
    float* hbuf  = (float*)take((size_t)BATCH*8192*4);
    float* aggo  = (float*)take((size_t)BATCH*8192*4);

    unsigned short* y1h   = (unsigned short*)regB;
    float*          r2    = (float*)regB;
    unsigned short* th    = (unsigned short*)regB;
    unsigned short* r1h   = (unsigned short*)regC;
    unsigned short* y2h   = (unsigned short*)regC;
    unsigned short* s2h   = (unsigned short*)(regC + 8*MB);
    unsigned short* agg1h = (unsigned short*)regD;
    unsigned short* zh    = (unsigned short*)regE;
    float*          agg2  = (float*)regA;

    float* crossp = accb + 0;
    float* normgp = accb + 1;
    float* entp   = accb + 2;
    unsigned int* a2p = (unsigned int*)(accb + 3);

    hipMemsetAsync(d_ws, 0, zero_small, stream);

    // sum(a^2) via LDS nibble hist; pass 0 also produces CSR degree counts
    k_a2lds<<<dim3(BATCH, 4), 1024, 0, stream>>>(src, dst, a2p, cnt_d, cnt_s);

    // CSR build
    k_scan_local<<<dim3(64,2), 1024, 0, stream>>>(cnt_d, cnt_s, ipd, ips, tots);
    k_scan_add<<<dim3(64,2), 1024, 0, stream>>>(tots, ipd, ips);
    k_fill<<<ETOT/256, 256, 0, stream>>>(src, dst, ipd, ips, cur_d, cur_s, lst_d, lst_s);

    // SAGE layer 1 (GEMM-before-gather, MFMA): y1 = x@W1l (bf16), r1 = x@W1r (bf16)
    k_mfma2b<128,1,1><<<NT/64, 256, 0, stream>>>(x, W1l, W1r, y1h, r1h);
    k_aggh<32,1><<<NT/8, 256, 0, stream>>>(y1h, ipd, lst_d, agg1h, 1);     // D=128, XCD-swizzled
    k_fin1<<<NT*128/8/256, 256, 0, stream>>>((const uint4*)agg1h, (const uint4*)r1h, b1l, (uint4*)zh);

    // SAGE layer 2 (MFMA): y2 = z@W2l (bf16), r2 = z@W2r (f32)
    k_mfma2b<64,0,0><<<NT/64, 256, 0, stream>>>(zh, W2l, W2r, y2h, r2);
    k_aggh<16,0><<<NT/16, 256, 0, stream>>>(y2h, ipd, lst_d, agg2, 1);     // D=64, XCD-swizzled
    // fused: spre = lky(agg2+r2+b2l); s = softmax(spre@Wm+bm) -> s2h bf16; ent
    k_gemm_wm<<<NT/64, 256, 0, stream>>>(agg2, r2, b2l, Wm, bm, s2h, entp);

    // t = A @ s (bf16 out; overwrites regB which is dead after gemm_wm)
    k_aggh<16,1><<<NT/16, 256, 0, stream>>>(s2h, ips, lst_s, th, 0);       // D=64, XCD-swizzled

    // fused MFMA: pooled/adjp/gram + trace(cross) + ||gram||^2(normg)
    k_spmm<<<BATCH, 1024, 0, stream>>>(s2h, zh, th, pooled, adjp, gram, crossp, normgp);

    // head: A (agg), B (dual GEMM fp32), C (split-K), D (logits)
    k_heada<<<dim3(BATCH, 4), 256, 0, stream>>>(adjp, pooled, aggo);
    k_gemm<<<dim3(BATCH*64/64, 2), 256, 0, stream>>>(aggo, pooled, Wrel, Wroot, broot, hbuf, BATCH*64, 128, 128, 1, 1, 0);
    k_head2<<<BATCH*16, 256, 0, stream>>>(hbuf, Wc1, hcacc);
    k_head3<<<BATCH, 128, 0, stream>>>(hcacc, bc1, Wc2, bc2, out);
    k_finalize<<<1, 1, 0, stream>>>(a2p, crossp, normgp, entp, out);
}

// Round 9
// 363.762 us; speedup vs baseline: 9.4900x; 1.5866x over previous
//
#include <hip/hip_runtime.h>
#include <math.h>

#define BATCH 64
#define NPG 1024
#define NT (BATCH*NPG)        // 65536 nodes
#define EPER 32768
#define ETOT (BATCH*EPER)     // 2097152 edges

typedef __attribute__((ext_vector_type(4))) float f32x4;
typedef __attribute__((ext_vector_type(8))) short s16x8;

__device__ __forceinline__ float lky(float x){ return x > 0.f ? x : 0.01f*x; }
__device__ __forceinline__ unsigned short f2bf(float f){
    unsigned u = __float_as_uint(f);
    u = u + 0x7FFFu + ((u >> 16) & 1u);      // RNE
    return (unsigned short)(u >> 16);
}
__device__ __forceinline__ float bf2f_lo(unsigned v){ return __uint_as_float(v << 16); }
__device__ __forceinline__ float bf2f_hi(unsigned v){ return __uint_as_float(v & 0xFFFF0000u); }

// ---------------- sum(a^2) via per-graph LDS nibble histogram ----------------
__global__ void __launch_bounds__(1024) k_a2lds(const int* __restrict__ src, const int* __restrict__ dst,
                                                unsigned* __restrict__ acc_out){
    __shared__ unsigned nib[32768];   // 128 KB = 262144 nibble counters
    __shared__ unsigned red[16];
    int b = blockIdx.x, pass = blockIdx.y, tid = threadIdx.x;
    for (int i = tid; i < 32768; i += 1024) nib[i] = 0;
    __syncthreads();
    int base = b*EPER;
    for (int i = tid; i < EPER; i += 1024){
        unsigned key = (((unsigned)src[base+i] & 1023u) << 10) | ((unsigned)dst[base+i] & 1023u);
        if ((int)(key >> 18) == pass)
            atomicAdd(&nib[(key & 0x3FFFFu) >> 3], 1u << ((key & 7u)*4u));
    }
    __syncthreads();
    unsigned local = 0;
    for (int i = tid; i < 32768; i += 1024){
        unsigned w = nib[i];
        if (w){
            #pragma unroll
            for (int q = 0; q < 8; q++){ unsigned c = (w >> (4*q)) & 15u; local += c*c; }
        }
    }
    for (int o = 32; o; o >>= 1) local += __shfl_xor(local, o);
    if ((tid & 63) == 0) red[tid >> 6] = local;
    __syncthreads();
    if (tid == 0){
        unsigned s = 0;
        for (int q = 0; q < 16; q++) s += red[q];
        atomicAdd(acc_out, s);
    }
}

// ---------------- atomic-free CSR build: one block per (graph, direction) ----------------
// LDS-staged edges + LDS count/scan/cursor; u16 local-index adjacency lists.
__global__ void __launch_bounds__(1024) k_csr(const int* __restrict__ src, const int* __restrict__ dst,
                                              int* __restrict__ ipd, int* __restrict__ ips,
                                              unsigned short* __restrict__ lst_d,
                                              unsigned short* __restrict__ lst_s){
    __shared__ unsigned eds[EPER];    // 128 KB packed (s<<10)|d
    __shared__ int cnt[1024];
    __shared__ int buf[1024];
    int g = blockIdx.x, which = blockIdx.y, tid = threadIdx.x;
    cnt[tid] = 0;
    __syncthreads();
    int base = g*EPER;
    for (int i = tid; i < EPER; i += 1024){
        unsigned s = (unsigned)src[base+i] & 1023u;
        unsigned d = (unsigned)dst[base+i] & 1023u;
        eds[i] = (s << 10) | d;
        atomicAdd(&cnt[which ? s : d], 1);          // LDS atomic
    }
    __syncthreads();
    int v = cnt[tid];
    int x = v;
    buf[tid] = x; __syncthreads();
    for (int off = 1; off < 1024; off <<= 1){
        int t = (tid >= off) ? buf[tid - off] : 0;
        __syncthreads();
        x += t; buf[tid] = x; __syncthreads();
    }
    int excl = x - v;
    int* ip = which ? ips : ipd;
    ip[g*1024 + tid] = base + excl;
    if (g == 0 && tid == 0) ip[NT] = ETOT;
    cnt[tid] = excl;                                 // cursor
    __syncthreads();
    unsigned short* lst = which ? lst_s : lst_d;
    for (int i = tid; i < EPER; i += 1024){
        unsigned key = eds[i];
        unsigned d = key & 1023u, s = key >> 10;
        unsigned idx = which ? s : d;
        unsigned val = which ? d : s;
        int p = atomicAdd(&cnt[idx], 1);             // LDS atomic
        lst[base + p] = (unsigned short)val;
    }
}

// ---------------- bf16 segment gather, XCD-swizzled; G threads/node, 4 feats/thread ----------------
// feature dim D = 4*G. u16 local-index adjacency.
template<int G, int OBF>
__global__ void k_aggh(const unsigned short* __restrict__ X, const int* __restrict__ indptr,
                       const unsigned short* __restrict__ lst, void* __restrict__ out, int do_mean){
    constexpr int NPB = 256/G;        // nodes per block
    constexpr int BPG = NPG/NPB;      // blocks per graph
    int bid = blockIdx.x;
    int xcd = bid & 7, j = bid >> 3;
    int gi = j/BPG, chunk = j - gi*BPG;
    int graph = xcd + 8*gi;
    int node = graph*NPG + chunk*NPB + threadIdx.x/G;
    int g = threadIdx.x % G;
    int gbase = graph*NPG;
    int st = indptr[node], en = indptr[node+1];
    float a0 = 0.f, a1 = 0.f, a2 = 0.f, a3 = 0.f;
    const unsigned short* Xg = X + 4*g;
    #pragma unroll 2
    for (int e = st; e < en; e++){
        int nb = gbase + lst[e];
        uint2 v = *(const uint2*)&Xg[(size_t)nb*(4*G)];
        a0 += bf2f_lo(v.x); a1 += bf2f_hi(v.x);
        a2 += bf2f_lo(v.y); a3 += bf2f_hi(v.y);
    }
    if (do_mean){
        int dg = en - st;
        float inv = 1.f/(float)(dg > 1 ? dg : 1);
        a0 *= inv; a1 *= inv; a2 *= inv; a3 *= inv;
    }
    if (OBF){
        uint2 pk;
        pk.x = (unsigned)f2bf(a0) | ((unsigned)f2bf(a1) << 16);
        pk.y = (unsigned)f2bf(a2) | ((unsigned)f2bf(a3) << 16);
        ((uint2*)out)[(size_t)node*G + g] = pk;
    } else {
        float4 o = { a0, a1, a2, a3 };
        ((float4*)out)[(size_t)node*G + g] = o;
    }
}

// ---------------- MFMA dual-B GEMM: C1 = A@W1 (bf16), C2 = A@W2 (bf16 or f32); K=128 ----------------
template<int N, int AF32, int OBF2>
__global__ void __launch_bounds__(256) k_mfma2b(
        const void* __restrict__ Ain, const float* __restrict__ W1,
        const float* __restrict__ W2, unsigned short* __restrict__ C1,
        void* __restrict__ C2){
    __shared__ unsigned short ldsB[2*N*128];
    int tid = threadIdx.x;
    for (int i = tid; i < 128*N; i += 256){
        int k = i / N, n = i - k*N;
        int swz = (n*256 + 2*k) ^ ((n & 7) << 4);
        *(unsigned short*)((char*)ldsB + swz)          = f2bf(W1[i]);
        *(unsigned short*)((char*)ldsB + N*256 + swz)  = f2bf(W2[i]);
    }
    __syncthreads();
    int wave = tid >> 6, l = tid & 63;
    int lr = l & 15, lg = l >> 4;
    int arow = blockIdx.x*64 + wave*16 + lr;
    constexpr int NF = N/16;
    f32x4 acc1[NF], acc2[NF];
    f32x4 zv = {0.f, 0.f, 0.f, 0.f};
    #pragma unroll
    for (int nf = 0; nf < NF; nf++){ acc1[nf] = zv; acc2[nf] = zv; }
    const unsigned short* Ah = (const unsigned short*)Ain;
    const float* Af = (const float*)Ain;
    #pragma unroll
    for (int ks = 0; ks < 4; ks++){
        s16x8 af;
        if (AF32){
            const float* p = Af + (size_t)arow*128 + ks*32 + lg*8;
            float4 v0 = *(const float4*)p;
            float4 v1 = *(const float4*)(p + 4);
            af[0] = (short)f2bf(v0.x); af[1] = (short)f2bf(v0.y);
            af[2] = (short)f2bf(v0.z); af[3] = (short)f2bf(v0.w);
            af[4] = (short)f2bf(v1.x); af[5] = (short)f2bf(v1.y);
            af[6] = (short)f2bf(v1.z); af[7] = (short)f2bf(v1.w);
        } else {
            af = *(const s16x8*)(Ah + (size_t)arow*128 + ks*32 + lg*8);
        }
        #pragma unroll
        for (int nf = 0; nf < NF; nf++){
            int n = nf*16 + lr;
            int swz = (n*256 + ks*64 + lg*16) ^ ((n & 7) << 4);
            s16x8 b1 = *(const s16x8*)((const char*)ldsB + swz);
            s16x8 b2 = *(const s16x8*)((const char*)ldsB + N*256 + swz);
            acc1[nf] = __builtin_amdgcn_mfma_f32_16x16x32_bf16(af, b1, acc1[nf], 0, 0, 0);
            acc2[nf] = __builtin_amdgcn_mfma_f32_16x16x32_bf16(af, b2, acc2[nf], 0, 0, 0);
        }
    }
    int orow = blockIdx.x*64 + wave*16 + lg*4;
    #pragma unroll
    for (int nf = 0; nf < NF; nf++){
        int c = nf*16 + lr;
        #pragma unroll
        for (int j = 0; j < 4; j++){
            size_t idx = (size_t)(orow + j)*N + c;
            C1[idx] = f2bf(acc1[nf][j]);
            if (OBF2) ((unsigned short*)C2)[idx] = f2bf(acc2[nf][j]);
            else      ((float*)C2)[idx] = acc2[nf][j];
        }
    }
}

// ---------------- z = lky(agg1h + r1h + b1l) -> zh bf16 (8 elems/thread) ----------------
__global__ void k_fin1(const uint4* __restrict__ agg1h, const uint4* __restrict__ r1h,
                       const float* __restrict__ b1l, uint4* __restrict__ zh){
    size_t i = (size_t)blockIdx.x*256 + threadIdx.x;   // NT*128/8 items
    uint4 a = agg1h[i], r = r1h[i];
    int c0 = ((int)(i & 15))*8;
    unsigned av[4] = {a.x, a.y, a.z, a.w};
    unsigned rv[4] = {r.x, r.y, r.z, r.w};
    unsigned ov[4];
    #pragma unroll
    for (int q = 0; q < 4; q++){
        float z0 = lky(bf2f_lo(av[q]) + bf2f_lo(rv[q]) + b1l[c0 + 2*q]);
        float z1 = lky(bf2f_hi(av[q]) + bf2f_hi(rv[q]) + b1l[c0 + 2*q + 1]);
        ov[q] = (unsigned)f2bf(z0) | ((unsigned)f2bf(z1) << 16);
    }
    uint4 o = {ov[0], ov[1], ov[2], ov[3]};
    zh[i] = o;
}

// ---------------- fp32 dual GEMM (head only): C = act(A1@W1 [+ A2@W2] + bias) ----------------
__global__ void __launch_bounds__(256) k_gemm(
        const float* __restrict__ A1, const float* __restrict__ A2,
        const float* __restrict__ W1, const float* __restrict__ W2,
        const float* __restrict__ bias, void* __restrict__ C,
        int M, int Nn, int Kd, int dual, int act, int obf){
    __shared__ float sA1[16*68], sB1[16*68], sA2[16*68], sB2[16*68];
    int tid = threadIdx.x;
    int m0 = blockIdx.x*64, n0 = blockIdx.y*64;
    int tx = tid & 15, ty = tid >> 4;
    int lr = tid >> 2, lk = (tid & 3)*4;
    int wk = tid >> 4, wn = (tid & 15)*4;
    float acc[4][4] = {};
    for (int k0 = 0; k0 < Kd; k0 += 16){
        float4 a1 = *(const float4*)&A1[(size_t)(m0+lr)*Kd + k0 + lk];
        float4 w1 = *(const float4*)&W1[(size_t)(k0+wk)*Nn + n0 + wn];
        sA1[(lk+0)*68+lr] = a1.x; sA1[(lk+1)*68+lr] = a1.y;
        sA1[(lk+2)*68+lr] = a1.z; sA1[(lk+3)*68+lr] = a1.w;
        *(float4*)&sB1[wk*68+wn] = w1;
        if (dual){
            float4 a2 = *(const float4*)&A2[(size_t)(m0+lr)*Kd + k0 + lk];
            float4 w2 = *(const float4*)&W2[(size_t)(k0+wk)*Nn + n0 + wn];
            sA2[(lk+0)*68+lr] = a2.x; sA2[(lk+1)*68+lr] = a2.y;
            sA2[(lk+2)*68+lr] = a2.z; sA2[(lk+3)*68+lr] = a2.w;
            *(float4*)&sB2[wk*68+wn] = w2;
        }
        __syncthreads();
        #pragma unroll
        for (int kk = 0; kk < 16; kk++){
            float4 av = *(const float4*)&sA1[kk*68 + ty*4];
            float4 bv = *(const float4*)&sB1[kk*68 + tx*4];
            float a[4] = {av.x, av.y, av.z, av.w};
            float b[4] = {bv.x, bv.y, bv.z, bv.w};
            #pragma unroll
            for (int i = 0; i < 4; i++)
                #pragma unroll
                for (int j = 0; j < 4; j++) acc[i][j] += a[i]*b[j];
            if (dual){
                float4 av2 = *(const float4*)&sA2[kk*68 + ty*4];
                float4 bv2 = *(const float4*)&sB2[kk*68 + tx*4];
                float a2[4] = {av2.x, av2.y, av2.z, av2.w};
                float b2[4] = {bv2.x, bv2.y, bv2.z, bv2.w};
                #pragma unroll
                for (int i = 0; i < 4; i++)
                    #pragma unroll
                    for (int j = 0; j < 4; j++) acc[i][j] += a2[i]*b2[j];
            }
        }
        __syncthreads();
    }
    float bb[4] = {0.f, 0.f, 0.f, 0.f};
    if (bias){
        #pragma unroll
        for (int j = 0; j < 4; j++) bb[j] = bias[n0 + tx*4 + j];
    }
    #pragma unroll
    for (int i = 0; i < 4; i++){
        float v0 = acc[i][0]+bb[0], v1 = acc[i][1]+bb[1], v2 = acc[i][2]+bb[2], v3 = acc[i][3]+bb[3];
        if (act){ v0 = lky(v0); v1 = lky(v1); v2 = lky(v2); v3 = lky(v3); }
        size_t idx = (size_t)(m0 + ty*4 + i)*Nn + n0 + tx*4;
        if (obf){
            ushort4 o = { f2bf(v0), f2bf(v1), f2bf(v2), f2bf(v3) };
            *(ushort4*)&((unsigned short*)C)[idx] = o;
        } else {
            float4 o = { v0, v1, v2, v3 };
            *(float4*)&((float*)C)[idx] = o;
        }
    }
}

// ---------------- fused: spre = lky(agg2 + r2 + b2l); s = softmax(spre@Wm + bm); ent; bf16 out ----------------
__global__ void __launch_bounds__(256) k_gemm_wm(
        const float* __restrict__ agg2, const float* __restrict__ r2,
        const float* __restrict__ b2l, const float* __restrict__ Wm,
        const float* __restrict__ bm,
        unsigned short* __restrict__ Sh, float* __restrict__ ent_acc){
    __shared__ float sA[16*68], sB[16*68];
    __shared__ float red[256];
    int tid = threadIdx.x;
    int m0 = blockIdx.x*64;
    int tx = tid & 15, ty = tid >> 4;
    int lr = tid >> 2, lk = (tid & 3)*4;
    int wk = tid >> 4, wn = (tid & 15)*4;
    float acc[4][4] = {};
    for (int k0 = 0; k0 < 64; k0 += 16){
        float4 a = *(const float4*)&agg2[(size_t)(m0+lr)*64 + k0 + lk];
        float4 r = *(const float4*)&r2[(size_t)(m0+lr)*64 + k0 + lk];
        sA[(lk+0)*68+lr] = lky(a.x + r.x + b2l[k0+lk+0]);
        sA[(lk+1)*68+lr] = lky(a.y + r.y + b2l[k0+lk+1]);
        sA[(lk+2)*68+lr] = lky(a.z + r.z + b2l[k0+lk+2]);
        sA[(lk+3)*68+lr] = lky(a.w + r.w + b2l[k0+lk+3]);
        *(float4*)&sB[wk*68+wn] = *(const float4*)&Wm[(size_t)(k0+wk)*64 + wn];
        __syncthreads();
        #pragma unroll
        for (int kk = 0; kk < 16; kk++){
            float4 av = *(const float4*)&sA[kk*68 + ty*4];
            float4 bv = *(const float4*)&sB[kk*68 + tx*4];
            float a4[4] = {av.x, av.y, av.z, av.w};
            float b4[4] = {bv.x, bv.y, bv.z, bv.w};
            #pragma unroll
            for (int i = 0; i < 4; i++)
                #pragma unroll
                for (int j = 0; j < 4; j++) acc[i][j] += a4[i]*b4[j];
        }
        __syncthreads();
    }
    float bb[4];
    #pragma unroll
    for (int j = 0; j < 4; j++) bb[j] = bm[tx*4 + j];
    float ent_local = 0.f;
    #pragma unroll
    for (int i = 0; i < 4; i++){
        float v[4];
        #pragma unroll
        for (int j = 0; j < 4; j++) v[j] = acc[i][j] + bb[j];
        float m = fmaxf(fmaxf(v[0], v[1]), fmaxf(v[2], v[3]));
        for (int o = 1; o < 16; o <<= 1) m = fmaxf(m, __shfl_xor(m, o));
        float e[4];
        float sm = 0.f;
        #pragma unroll
        for (int j = 0; j < 4; j++){ e[j] = __expf(v[j] - m); sm += e[j]; }
        for (int o = 1; o < 16; o <<= 1) sm += __shfl_xor(sm, o);
        float inv = 1.f/sm;
        float p[4];
        float w = 0.f;
        #pragma unroll
        for (int j = 0; j < 4; j++){
            p[j] = e[j]*inv;
            w += -p[j]*__logf(p[j] + 1e-15f);
        }
        for (int o = 1; o < 16; o <<= 1) w += __shfl_xor(w, o);
        if (tx == 0) ent_local += w;
        size_t idx = (size_t)(m0 + ty*4 + i)*64 + tx*4;
        ushort4 oh = { f2bf(p[0]), f2bf(p[1]), f2bf(p[2]), f2bf(p[3]) };
        *(ushort4*)&Sh[idx] = oh;
    }
    red[tid] = ent_local; __syncthreads();
    for (int o = 128; o; o >>= 1){ if (tid < o) red[tid] += red[tid+o]; __syncthreads(); }
    if (tid == 0) atomicAdd(ent_acc, red[0]);
}

// ---------------- fused MFMA: [pooled | adjp | gram] = s^T @ [z | t | s] per graph ----------------
__global__ void __launch_bounds__(1024) k_spmm(
        const unsigned short* __restrict__ Sh, const unsigned short* __restrict__ Zh,
        const unsigned short* __restrict__ Th,
        float* __restrict__ P, float* __restrict__ AP, float* __restrict__ GR,
        float* __restrict__ crossp, float* __restrict__ normgp){
    __shared__ unsigned short At[64*72];    // A^T: [m up to 64][k 64]
    __shared__ unsigned short Bt[256*72];   // B^T: [col 256][k 64]
    __shared__ float rtr[16], rsq[16];
    int b = blockIdx.x, tid = threadIdx.x;
    int w = tid >> 6, l = tid & 63;
    int lr = l & 15, lg = l >> 4;
    int mt = w & 3, ng = w >> 2;
    f32x4 acc[4];
    f32x4 zv = {0.f, 0.f, 0.f, 0.f};
    #pragma unroll
    for (int q = 0; q < 4; q++) acc[q] = zv;
    int gb = b*NPG;
    int sa_n = tid & 63, sa_c = (tid >> 6)*4;
    int sb_k = tid & 63, sb_g = tid >> 6;
    for (int n0 = 0; n0 < NPG; n0 += 64){
        ushort4 sv = *(const ushort4*)&Sh[(size_t)(gb+n0+sa_n)*64 + sa_c];
        At[(sa_c+0)*72 + sa_n] = sv.x;
        At[(sa_c+1)*72 + sa_n] = sv.y;
        At[(sa_c+2)*72 + sa_n] = sv.z;
        At[(sa_c+3)*72 + sa_n] = sv.w;
        {
            int R = gb + n0 + sb_k;
            const unsigned short* srcp;
            if (sb_g < 8)       srcp = &Zh[(size_t)R*128 + sb_g*16];
            else if (sb_g < 12) srcp = &Th[(size_t)R*64 + (sb_g-8)*16];
            else                srcp = &Sh[(size_t)R*64 + (sb_g-12)*16];
            ushort4 a0 = *(const ushort4*)(srcp);
            ushort4 a1 = *(const ushort4*)(srcp+4);
            ushort4 a2 = *(const ushort4*)(srcp+8);
            ushort4 a3 = *(const ushort4*)(srcp+12);
            int cb = sb_g*16;
            Bt[(cb+ 0)*72+sb_k]=a0.x; Bt[(cb+ 1)*72+sb_k]=a0.y; Bt[(cb+ 2)*72+sb_k]=a0.z; Bt[(cb+ 3)*72+sb_k]=a0.w;
            Bt[(cb+ 4)*72+sb_k]=a1.x; Bt[(cb+ 5)*72+sb_k]=a1.y; Bt[(cb+ 6)*72+sb_k]=a1.z; Bt[(cb+ 7)*72+sb_k]=a1.w;
            Bt[(cb+ 8)*72+sb_k]=a2.x; Bt[(cb+ 9)*72+sb_k]=a2.y; Bt[(cb+10)*72+sb_k]=a2.z; Bt[(cb+11)*72+sb_k]=a2.w;
            Bt[(cb+12)*72+sb_k]=a3.x; Bt[(cb+13)*72+sb_k]=a3.y; Bt[(cb+14)*72+sb_k]=a3.z; Bt[(cb+15)*72+sb_k]=a3.w;
        }
        __syncthreads();
        #pragma unroll
        for (int ks = 0; ks < 2; ks++){
            s16x8 af = *(const s16x8*)&At[(mt*16+lr)*72 + ks*32 + lg*8];
            #pragma unroll
            for (int q = 0; q < 4; q++){
                s16x8 bf = *(const s16x8*)&Bt[((ng*4+q)*16+lr)*72 + ks*32 + lg*8];
                acc[q] = __builtin_amdgcn_mfma_f32_16x16x32_bf16(af, bf, acc[q], 0, 0, 0);
            }
        }
        __syncthreads();
    }
    float tr = 0.f, sq = 0.f;
    #pragma unroll
    for (int q = 0; q < 4; q++){
        int col = (ng*4+q)*16 + lr;
        #pragma unroll
        for (int j = 0; j < 4; j++){
            int m = mt*16 + lg*4 + j;
            float v = acc[q][j];
            if (col < 128){
                P[((size_t)b*64+m)*128 + col] = v;
            } else if (col < 192){
                AP[((size_t)b*64+m)*64 + (col-128)] = v;
                if (col-128 == m) tr += v;
            } else {
                GR[((size_t)b*64+m)*64 + (col-192)] = v;
                sq += v*v;
            }
        }
    }
    for (int o = 32; o; o >>= 1){ tr += __shfl_xor(tr, o); sq += __shfl_xor(sq, o); }
    if (l == 0){ rtr[w] = tr; rsq[w] = sq; }
    __syncthreads();
    if (tid == 0){
        float str = 0.f, ssq = 0.f;
        for (int i = 0; i < 16; i++){ str += rtr[i]; ssq += rsq[i]; }
        atomicAdd(crossp, str);
        atomicAdd(normgp, ssq);
    }
}

// ---------------- head stage A: aggout[b] = (adjp[b] @ pooled[b]) / rowsum ----------------
__global__ void __launch_bounds__(256) k_heada(
        const float* __restrict__ AP, const float* __restrict__ P,
        float* __restrict__ aggout){
    __shared__ float sapT[64*65];
    __shared__ float sp[64*33];
    __shared__ float srs[64];
    int b = blockIdx.x, c0 = blockIdx.y*32;
    int tid = threadIdx.x;
    for (int i = tid; i < 4096; i += 256){
        int k = i >> 6, l = i & 63;
        sapT[l*65 + k] = AP[(size_t)b*4096 + i];
    }
    for (int i = tid; i < 2048; i += 256){
        int l = i >> 5, j = i & 31;
        sp[l*33 + j] = P[(size_t)b*8192 + l*128 + c0 + j];
    }
    __syncthreads();
    if (tid < 64){
        float s = 0.f;
        for (int l = 0; l < 64; l++) s += sapT[l*65 + tid];
        srs[tid] = fmaxf(s, 1.f);
    }
    __syncthreads();
    int k = tid & 63, jg = (tid >> 6)*8;
    float acc[8] = {};
    for (int l = 0; l < 64; l++){
        float a = sapT[l*65 + k];
        #pragma unroll
        for (int j = 0; j < 8; j++) acc[j] += a*sp[l*33 + jg + j];
    }
    float inv = 1.f/srs[k];
    #pragma unroll
    for (int j = 0; j < 8; j++)
        aggout[(size_t)b*8192 + k*128 + c0 + jg + j] = acc[j]*inv;
}

// ---------------- head stage C: hcacc[b,:] += h[b, chunk] @ Wc1[chunk, :] ----------------
__global__ void __launch_bounds__(256) k_head2(
        const float* __restrict__ hbuf, const float* __restrict__ Wc1,
        float* __restrict__ hcacc){
    __shared__ float sh[512];
    __shared__ float sred[256];
    int b = blockIdx.x >> 4, ch = blockIdx.x & 15;
    int tid = threadIdx.x;
    for (int i = tid; i < 512; i += 256) sh[i] = hbuf[(size_t)b*8192 + ch*512 + i];
    __syncthreads();
    int j = tid & 127, half = tid >> 7;
    float acc = 0.f;
    const float* W = Wc1 + (size_t)(ch*512 + half*256)*128;
    const float* hh = sh + half*256;
    for (int r = 0; r < 256; r++) acc += hh[r]*W[(size_t)r*128 + j];
    sred[tid] = acc; __syncthreads();
    if (tid < 128) atomicAdd(&hcacc[(size_t)b*128 + tid], sred[tid] + sred[tid+128]);
}

// ---------------- head stage D: logits ----------------
__global__ void k_head3(const float* __restrict__ hcacc, const float* __restrict__ bc1,
                        const float* __restrict__ Wc2, const float* __restrict__ bc2,
                        float* __restrict__ out){
    int b = blockIdx.x, t = threadIdx.x;   // 128 threads
    float hc = lky(hcacc[(size_t)b*128 + t] + bc1[t]);
    float p = hc*Wc2[t];
    for (int o = 32; o; o >>= 1) p += __shfl_xor(p, o);
    __shared__ float r2[2];
    if ((t & 63) == 0) r2[t >> 6] = p;
    __syncthreads();
    if (t == 0) out[b] = r2[0] + r2[1] + bc2[0];
}

__global__ void k_finalize(const unsigned int* __restrict__ a2,
                           const float* __restrict__ cross,
                           const float* __restrict__ normg,
                           const float* __restrict__ ent,
                           float* __restrict__ out){
    float ss = (float)(*a2) - 2.f*(*cross) + (*normg);
    if (ss < 0.f) ss = 0.f;
    float link = sqrtf(ss) / 67108864.f;     // a.size
    out[64] = link + (*ent)/(float)NT;
}

extern "C" void kernel_launch(void* const* d_in, const int* in_sizes, int n_in,
                              void* d_out, int out_size, void* d_ws, size_t ws_size,
                              hipStream_t stream){
    const float* x    = (const float*)d_in[0];
    const int*   ei   = (const int*)d_in[1];
    const int*   src  = ei;
    const int*   dst  = ei + ETOT;
    const float* W1l  = (const float*)d_in[5];
    const float* b1l  = (const float*)d_in[6];
    const float* W1r  = (const float*)d_in[7];
    const float* W2l  = (const float*)d_in[8];
    const float* b2l  = (const float*)d_in[9];
    const float* W2r  = (const float*)d_in[10];
    const float* Wm   = (const float*)d_in[11];
    const float* bm   = (const float*)d_in[12];
    const float* Wrel = (const float*)d_in[13];
    const float* Wroot= (const float*)d_in[14];
    const float* broot= (const float*)d_in[15];
    const float* Wc1  = (const float*)d_in[16];
    const float* bc1  = (const float*)d_in[17];
    const float* Wc2  = (const float*)d_in[18];
    const float* bc2  = (const float*)d_in[19];
    float* out = (float*)d_out;

    char* w = (char*)d_ws;
    size_t off = 0;
    auto take = [&](size_t bytes)->void*{
        void* p = w + off; off = (off + bytes + 255) & ~(size_t)255; return p;
    };
    const size_t MB = 1024*1024;
    // --- small zeroed zone ---
    float* hcacc  = (float*)take((size_t)BATCH*128*4);
    float* accb   = (float*)take(64);
    size_t zero_small = off;
    // --- non-zeroed ---
    float* pooled = (float*)take((size_t)BATCH*64*128*4);
    float* adjp   = (float*)take((size_t)BATCH*64*64*4);
    float* gram   = (float*)take((size_t)BATCH*64*64*4);
    int*   ipd   = (int*)take((size_t)(NT+1)*4);
    int*   ips   = (int*)take((size_t)(NT+1)*4);
    unsigned short* lst_d = (unsigned short*)take((size_t)ETOT*2);
    unsigned short* lst_s = (unsigned short*)take((size_t)ETOT*2);
    char*  regA  = (char*)take(16*MB);   // agg2 (f32)
    char*  regB  = (char*)take(16*MB);   // y1h -> r2 -> th
    char*  regC  = (char*)take(16*MB);   // r1h -> [y2h | s2h]
    char*  regD  = (char*)take(16*MB);   // agg1h
    char*  regE  = (char*)take(16*MB);   // zh
    float* hbuf  = (float*)take((size_t)BATCH*8192*4);
    float* aggo  = (float*)take((size_t)BATCH*8192*4);

    unsigned short* y1h   = (unsigned short*)regB;
    float*          r2    = (float*)regB;
    unsigned short* th    = (unsigned short*)regB;
    unsigned short* r1h   = (unsigned short*)regC;
    unsigned short* y2h   = (unsigned short*)regC;
    unsigned short* s2h   = (unsigned short*)(regC + 8*MB);
    unsigned short* agg1h = (unsigned short*)regD;
    unsigned short* zh    = (unsigned short*)regE;
    float*          agg2  = (float*)regA;

    float* crossp = accb + 0;
    float* normgp = accb + 1;
    float* entp   = accb + 2;
    unsigned int* a2p = (unsigned int*)(accb + 3);

    hipMemsetAsync(d_ws, 0, zero_small, stream);

    // sum(a^2) via LDS nibble hist (no global atomics on counts anymore)
    k_a2lds<<<dim3(BATCH, 4), 1024, 0, stream>>>(src, dst, a2p);

    // atomic-free CSR build (per-graph LDS count/scan/scatter, u16 lists)
    k_csr<<<dim3(BATCH, 2), 1024, 0, stream>>>(src, dst, ipd, ips, lst_d, lst_s);

    // SAGE layer 1 (GEMM-before-gather, MFMA): y1 = x@W1l (bf16), r1 = x@W1r (bf16)
    k_mfma2b<128,1,1><<<NT/64, 256, 0, stream>>>(x, W1l, W1r, y1h, r1h);
    k_aggh<32,1><<<NT/8, 256, 0, stream>>>(y1h, ipd, lst_d, agg1h, 1);     // D=128, XCD-swizzled
    k_fin1<<<NT*128/8/256, 256, 0, stream>>>((const uint4*)agg1h, (const uint4*)r1h, b1l, (uint4*)zh);

    // SAGE layer 2 (MFMA): y2 = z@W2l (bf16), r2 = z@W2r (f32)
    k_mfma2b<64,0,0><<<NT/64, 256, 0, stream>>>(zh, W2l, W2r, y2h, r2);
    k_aggh<16,0><<<NT/16, 256, 0, stream>>>(y2h, ipd, lst_d, agg2, 1);     // D=64, XCD-swizzled
    // fused: spre = lky(agg2+r2+b2l); s = softmax(spre@Wm+bm) -> s2h bf16; ent
    k_gemm_wm<<<NT/64, 256, 0, stream>>>(agg2, r2, b2l, Wm, bm, s2h, entp);

    // t = A @ s (bf16 out; overwrites regB which is dead after gemm_wm)
    k_aggh<16,1><<<NT/16, 256, 0, stream>>>(s2h, ips, lst_s, th, 0);       // D=64, XCD-swizzled

    // fused MFMA: pooled/adjp/gram + trace(cross) + ||gram||^2(normg)
    k_spmm<<<BATCH, 1024, 0, stream>>>(s2h, zh, th, pooled, adjp, gram, crossp, normgp);

    // head: A (agg), B (dual GEMM fp32), C (split-K), D (logits)
    k_heada<<<dim3(BATCH, 4), 256, 0, stream>>>(adjp, pooled, aggo);
    k_gemm<<<dim3(BATCH*64/64, 2), 256, 0, stream>>>(aggo, pooled, Wrel, Wroot, broot, hbuf, BATCH*64, 128, 128, 1, 1, 0);
    k_head2<<<BATCH*16, 256, 0, stream>>>(hbuf, Wc1, hcacc);
    k_head3<<<BATCH, 128, 0, stream>>>(hcacc, bc1, Wc2, bc2, out);
    k_finalize<<<1, 1, 0, stream>>>(a2p, crossp, normgp, entp, out);
}

// Round 10
// 335.619 us; speedup vs baseline: 10.2858x; 1.0839x over previous
//
#include <hip/hip_runtime.h>
#include <math.h>

#define BATCH 64
#define NPG 1024
#define NT (BATCH*NPG)        // 65536 nodes
#define EPER 32768
#define ETOT (BATCH*EPER)     // 2097152 edges

typedef __attribute__((ext_vector_type(4))) float f32x4;
typedef __attribute__((ext_vector_type(8))) short s16x8;

__device__ __forceinline__ float lky(float x){ return x > 0.f ? x : 0.01f*x; }
__device__ __forceinline__ unsigned short f2bf(float f){
    unsigned u = __float_as_uint(f);
    u = u + 0x7FFFu + ((u >> 16) & 1u);      // RNE
    return (unsigned short)(u >> 16);
}
__device__ __forceinline__ float bf2f_lo(unsigned v){ return __uint_as_float(v << 16); }
__device__ __forceinline__ float bf2f_hi(unsigned v){ return __uint_as_float(v & 0xFFFF0000u); }

// ---------------- weight prep: f32 [k][n] -> bf16 [n][k] (transposed) ----------------
// wt layout: [0:16384] W1l^T, [16384:32768] W1r^T, [32768:40960] W2l^T, [40960:49152] W2r^T
__global__ void k_wprep(const float* __restrict__ W1l, const float* __restrict__ W1r,
                        const float* __restrict__ W2l, const float* __restrict__ W2r,
                        unsigned short* __restrict__ wt){
    int i = blockIdx.x*256 + threadIdx.x;   // 0..49151
    if (i < 16384){ int k = i >> 7, n = i & 127; wt[n*128 + k] = f2bf(W1l[i]); }
    else if (i < 32768){ int j = i - 16384; int k = j >> 7, n = j & 127; wt[16384 + n*128 + k] = f2bf(W1r[j]); }
    else if (i < 40960){ int j = i - 32768; int k = j >> 6, n = j & 63; wt[32768 + n*128 + k] = f2bf(W2l[j]); }
    else if (i < 49152){ int j = i - 40960; int k = j >> 6, n = j & 63; wt[40960 + n*128 + k] = f2bf(W2r[j]); }
}

// ---------------- sum(a^2) via per-graph LDS nibble histogram ----------------
__global__ void __launch_bounds__(1024) k_a2lds(const int* __restrict__ src, const int* __restrict__ dst,
                                                unsigned* __restrict__ acc_out){
    __shared__ unsigned nib[32768];   // 128 KB = 262144 nibble counters
    __shared__ unsigned red[16];
    int b = blockIdx.x, pass = blockIdx.y, tid = threadIdx.x;
    for (int i = tid; i < 32768; i += 1024) nib[i] = 0;
    __syncthreads();
    int base = b*EPER;
    for (int i = tid; i < EPER; i += 1024){
        unsigned key = (((unsigned)src[base+i] & 1023u) << 10) | ((unsigned)dst[base+i] & 1023u);
        if ((int)(key >> 18) == pass)
            atomicAdd(&nib[(key & 0x3FFFFu) >> 3], 1u << ((key & 7u)*4u));
    }
    __syncthreads();
    unsigned local = 0;
    for (int i = tid; i < 32768; i += 1024){
        unsigned w = nib[i];
        if (w){
            #pragma unroll
            for (int q = 0; q < 8; q++){ unsigned c = (w >> (4*q)) & 15u; local += c*c; }
        }
    }
    for (int o = 32; o; o >>= 1) local += __shfl_xor(local, o);
    if ((tid & 63) == 0) red[tid >> 6] = local;
    __syncthreads();
    if (tid == 0){
        unsigned s = 0;
        for (int q = 0; q < 16; q++) s += red[q];
        atomicAdd(acc_out, s);
    }
}

// ---------------- atomic-free CSR build: one block per (graph, direction) ----------------
__global__ void __launch_bounds__(1024) k_csr(const int* __restrict__ src, const int* __restrict__ dst,
                                              int* __restrict__ ipd, int* __restrict__ ips,
                                              unsigned short* __restrict__ lst_d,
                                              unsigned short* __restrict__ lst_s){
    __shared__ unsigned eds[EPER];    // 128 KB packed (s<<10)|d
    __shared__ int cnt[1024];
    __shared__ int buf[1024];
    int g = blockIdx.x, which = blockIdx.y, tid = threadIdx.x;
    cnt[tid] = 0;
    __syncthreads();
    int base = g*EPER;
    for (int i = tid; i < EPER; i += 1024){
        unsigned s = (unsigned)src[base+i] & 1023u;
        unsigned d = (unsigned)dst[base+i] & 1023u;
        eds[i] = (s << 10) | d;
        atomicAdd(&cnt[which ? s : d], 1);          // LDS atomic
    }
    __syncthreads();
    int v = cnt[tid];
    int x = v;
    buf[tid] = x; __syncthreads();
    for (int off = 1; off < 1024; off <<= 1){
        int t = (tid >= off) ? buf[tid - off] : 0;
        __syncthreads();
        x += t; buf[tid] = x; __syncthreads();
    }
    int excl = x - v;
    int* ip = which ? ips : ipd;
    ip[g*1024 + tid] = base + excl;
    if (g == 0 && tid == 0) ip[NT] = ETOT;
    cnt[tid] = excl;                                 // cursor
    __syncthreads();
    unsigned short* lst = which ? lst_s : lst_d;
    for (int i = tid; i < EPER; i += 1024){
        unsigned key = eds[i];
        unsigned d = key & 1023u, s = key >> 10;
        unsigned idx = which ? s : d;
        unsigned val = which ? d : s;
        int p = atomicAdd(&cnt[idx], 1);             // LDS atomic
        lst[base + p] = (unsigned short)val;
    }
}

// ---------------- bf16 segment gather, XCD-swizzled, 4-deep MLP ----------------
// D = 4*G. MODE: 0 = f32 out, 1 = bf16 out, 2 = bf16 out + fused z=lky(agg+R+bias)
template<int G, int MODE>
__global__ void k_aggh(const unsigned short* __restrict__ X, const int* __restrict__ indptr,
                       const unsigned short* __restrict__ lst,
                       const unsigned short* __restrict__ R, const float* __restrict__ bias,
                       void* __restrict__ out, int do_mean){
    constexpr int NPB = 256/G;        // nodes per block
    constexpr int BPG = NPG/NPB;      // blocks per graph
    int bid = blockIdx.x;
    int xcd = bid & 7, j = bid >> 3;
    int gi = j/BPG, chunk = j - gi*BPG;
    int graph = xcd + 8*gi;
    int node = graph*NPG + chunk*NPB + threadIdx.x/G;
    int g = threadIdx.x % G;
    int gbase = graph*NPG;
    int st = indptr[node], en = indptr[node+1];
    float a0 = 0.f, a1 = 0.f, a2 = 0.f, a3 = 0.f;
    const unsigned short* Xg = X + 4*g;
    int e = st;
    for (; e + 4 <= en; e += 4){
        int nb0 = gbase + lst[e+0];
        int nb1 = gbase + lst[e+1];
        int nb2 = gbase + lst[e+2];
        int nb3 = gbase + lst[e+3];
        uint2 v0 = *(const uint2*)&Xg[(size_t)nb0*(4*G)];
        uint2 v1 = *(const uint2*)&Xg[(size_t)nb1*(4*G)];
        uint2 v2 = *(const uint2*)&Xg[(size_t)nb2*(4*G)];
        uint2 v3 = *(const uint2*)&Xg[(size_t)nb3*(4*G)];
        a0 += bf2f_lo(v0.x) + bf2f_lo(v1.x) + bf2f_lo(v2.x) + bf2f_lo(v3.x);
        a1 += bf2f_hi(v0.x) + bf2f_hi(v1.x) + bf2f_hi(v2.x) + bf2f_hi(v3.x);
        a2 += bf2f_lo(v0.y) + bf2f_lo(v1.y) + bf2f_lo(v2.y) + bf2f_lo(v3.y);
        a3 += bf2f_hi(v0.y) + bf2f_hi(v1.y) + bf2f_hi(v2.y) + bf2f_hi(v3.y);
    }
    for (; e < en; e++){
        int nb = gbase + lst[e];
        uint2 v = *(const uint2*)&Xg[(size_t)nb*(4*G)];
        a0 += bf2f_lo(v.x); a1 += bf2f_hi(v.x);
        a2 += bf2f_lo(v.y); a3 += bf2f_hi(v.y);
    }
    if (do_mean){
        int dg = en - st;
        float inv = 1.f/(float)(dg > 1 ? dg : 1);
        a0 *= inv; a1 *= inv; a2 *= inv; a3 *= inv;
    }
    if (MODE == 2){
        uint2 r = *(const uint2*)&R[(size_t)node*(4*G) + 4*g];
        a0 = lky(a0 + bf2f_lo(r.x) + bias[4*g + 0]);
        a1 = lky(a1 + bf2f_hi(r.x) + bias[4*g + 1]);
        a2 = lky(a2 + bf2f_lo(r.y) + bias[4*g + 2]);
        a3 = lky(a3 + bf2f_hi(r.y) + bias[4*g + 3]);
    }
    if (MODE >= 1){
        uint2 pk;
        pk.x = (unsigned)f2bf(a0) | ((unsigned)f2bf(a1) << 16);
        pk.y = (unsigned)f2bf(a2) | ((unsigned)f2bf(a3) << 16);
        ((uint2*)out)[(size_t)node*G + g] = pk;
    } else {
        float4 o = { a0, a1, a2, a3 };
        ((float4*)out)[(size_t)node*G + g] = o;
    }
}

// ---------------- MFMA dual-B GEMM v2: pre-transposed bf16 weights, 512 thr, 256 rows/block ----------------
// C1 = A@W1 (bf16), C2 = A@W2 (bf16). K=128. Wt: bf16 [n][128].
template<int N, int AF32>
__global__ void __launch_bounds__(512) k_mfma2b(
        const void* __restrict__ Ain, const unsigned short* __restrict__ Wt1,
        const unsigned short* __restrict__ Wt2, unsigned short* __restrict__ C1,
        unsigned short* __restrict__ C2){
    __shared__ unsigned short ldsB[2*N*128];
    int tid = threadIdx.x;
    // stage: lanes traverse k contiguously (conflict-free 4-B writes), coalesced global reads
    for (int i = tid; i < N*64; i += 512){
        int n = i >> 6, kk = i & 63;
        int swz = (n*256 + 4*kk) ^ ((n & 7) << 4);
        *(unsigned*)((char*)ldsB + swz)         = ((const unsigned*)Wt1)[i];
        *(unsigned*)((char*)ldsB + N*256 + swz) = ((const unsigned*)Wt2)[i];
    }
    __syncthreads();
    int wave = tid >> 6, l = tid & 63;
    int lr = l & 15, lg = l >> 4;
    constexpr int NF = N/16;
    const unsigned short* Ah = (const unsigned short*)Ain;
    const float* Af = (const float*)Ain;
    #pragma unroll 1
    for (int mc = 0; mc < 2; mc++){
        int arow = blockIdx.x*256 + mc*128 + wave*16 + lr;
        f32x4 acc1[NF], acc2[NF];
        f32x4 zv = {0.f, 0.f, 0.f, 0.f};
        #pragma unroll
        for (int nf = 0; nf < NF; nf++){ acc1[nf] = zv; acc2[nf] = zv; }
        #pragma unroll
        for (int ks = 0; ks < 4; ks++){
            s16x8 af;
            if (AF32){
                const float* p = Af + (size_t)arow*128 + ks*32 + lg*8;
                float4 v0 = *(const float4*)p;
                float4 v1 = *(const float4*)(p + 4);
                af[0] = (short)f2bf(v0.x); af[1] = (short)f2bf(v0.y);
                af[2] = (short)f2bf(v0.z); af[3] = (short)f2bf(v0.w);
                af[4] = (short)f2bf(v1.x); af[5] = (short)f2bf(v1.y);
                af[6] = (short)f2bf(v1.z); af[7] = (short)f2bf(v1.w);
            } else {
                af = *(const s16x8*)(Ah + (size_t)arow*128 + ks*32 + lg*8);
            }
            #pragma unroll
            for (int nf = 0; nf < NF; nf++){
                int n = nf*16 + lr;
                int swz = (n*256 + ks*64 + lg*16) ^ ((n & 7) << 4);
                s16x8 b1 = *(const s16x8*)((const char*)ldsB + swz);
                s16x8 b2 = *(const s16x8*)((const char*)ldsB + N*256 + swz);
                acc1[nf] = __builtin_amdgcn_mfma_f32_16x16x32_bf16(af, b1, acc1[nf], 0, 0, 0);
                acc2[nf] = __builtin_amdgcn_mfma_f32_16x16x32_bf16(af, b2, acc2[nf], 0, 0, 0);
            }
        }
        int orow = blockIdx.x*256 + mc*128 + wave*16 + lg*4;
        #pragma unroll
        for (int nf = 0; nf < NF; nf++){
            int c = nf*16 + lr;
            #pragma unroll
            for (int j = 0; j < 4; j++){
                size_t idx = (size_t)(orow + j)*N + c;
                C1[idx] = f2bf(acc1[nf][j]);
                C2[idx] = f2bf(acc2[nf][j]);
            }
        }
    }
}

// ---------------- fp32 dual GEMM (head only): C = act(A1@W1 [+ A2@W2] + bias) ----------------
__global__ void __launch_bounds__(256) k_gemm(
        const float* __restrict__ A1, const float* __restrict__ A2,
        const float* __restrict__ W1, const float* __restrict__ W2,
        const float* __restrict__ bias, void* __restrict__ C,
        int M, int Nn, int Kd, int dual, int act, int obf){
    __shared__ float sA1[16*68], sB1[16*68], sA2[16*68], sB2[16*68];
    int tid = threadIdx.x;
    int m0 = blockIdx.x*64, n0 = blockIdx.y*64;
    int tx = tid & 15, ty = tid >> 4;
    int lr = tid >> 2, lk = (tid & 3)*4;
    int wk = tid >> 4, wn = (tid & 15)*4;
    float acc[4][4] = {};
    for (int k0 = 0; k0 < Kd; k0 += 16){
        float4 a1 = *(const float4*)&A1[(size_t)(m0+lr)*Kd + k0 + lk];
        float4 w1 = *(const float4*)&W1[(size_t)(k0+wk)*Nn + n0 + wn];
        sA1[(lk+0)*68+lr] = a1.x; sA1[(lk+1)*68+lr] = a1.y;
        sA1[(lk+2)*68+lr] = a1.z; sA1[(lk+3)*68+lr] = a1.w;
        *(float4*)&sB1[wk*68+wn] = w1;
        if (dual){
            float4 a2 = *(const float4*)&A2[(size_t)(m0+lr)*Kd + k0 + lk];
            float4 w2 = *(const float4*)&W2[(size_t)(k0+wk)*Nn + n0 + wn];
            sA2[(lk+0)*68+lr] = a2.x; sA2[(lk+1)*68+lr] = a2.y;
            sA2[(lk+2)*68+lr] = a2.z; sA2[(lk+3)*68+lr] = a2.w;
            *(float4*)&sB2[wk*68+wn] = w2;
        }
        __syncthreads();
        #pragma unroll
        for (int kk = 0; kk < 16; kk++){
            float4 av = *(const float4*)&sA1[kk*68 + ty*4];
            float4 bv = *(const float4*)&sB1[kk*68 + tx*4];
            float a[4] = {av.x, av.y, av.z, av.w};
            float b[4] = {bv.x, bv.y, bv.z, bv.w};
            #pragma unroll
            for (int i = 0; i < 4; i++)
                #pragma unroll
                for (int j = 0; j < 4; j++) acc[i][j] += a[i]*b[j];
            if (dual){
                float4 av2 = *(const float4*)&sA2[kk*68 + ty*4];
                float4 bv2 = *(const float4*)&sB2[kk*68 + tx*4];
                float a2[4] = {av2.x, av2.y, av2.z, av2.w};
                float b2[4] = {bv2.x, bv2.y, bv2.z, bv2.w};
                #pragma unroll
                for (int i = 0; i < 4; i++)
                    #pragma unroll
                    for (int j = 0; j < 4; j++) acc[i][j] += a2[i]*b2[j];
            }
        }
        __syncthreads();
    }
    float bb[4] = {0.f, 0.f, 0.f, 0.f};
    if (bias){
        #pragma unroll
        for (int j = 0; j < 4; j++) bb[j] = bias[n0 + tx*4 + j];
    }
    #pragma unroll
    for (int i = 0; i < 4; i++){
        float v0 = acc[i][0]+bb[0], v1 = acc[i][1]+bb[1], v2 = acc[i][2]+bb[2], v3 = acc[i][3]+bb[3];
        if (act){ v0 = lky(v0); v1 = lky(v1); v2 = lky(v2); v3 = lky(v3); }
        size_t idx = (size_t)(m0 + ty*4 + i)*Nn + n0 + tx*4;
        if (obf){
            ushort4 o = { f2bf(v0), f2bf(v1), f2bf(v2), f2bf(v3) };
            *(ushort4*)&((unsigned short*)C)[idx] = o;
        } else {
            float4 o = { v0, v1, v2, v3 };
            *(float4*)&((float*)C)[idx] = o;
        }
    }
}

// ---------------- fused: spre = lky(agg2h + r2h + b2l); s = softmax(spre@Wm + bm); ent; bf16 out ----------------
__global__ void __launch_bounds__(256) k_gemm_wm(
        const unsigned short* __restrict__ agg2h, const unsigned short* __restrict__ r2h,
        const float* __restrict__ b2l, const float* __restrict__ Wm,
        const float* __restrict__ bm,
        unsigned short* __restrict__ Sh, float* __restrict__ ent_acc){
    __shared__ float sA[16*68], sB[16*68];
    __shared__ float red[256];
    int tid = threadIdx.x;
    int m0 = blockIdx.x*64;
    int tx = tid & 15, ty = tid >> 4;
    int lr = tid >> 2, lk = (tid & 3)*4;
    int wk = tid >> 4, wn = (tid & 15)*4;
    float acc[4][4] = {};
    for (int k0 = 0; k0 < 64; k0 += 16){
        uint2 a = *(const uint2*)&agg2h[(size_t)(m0+lr)*64 + k0 + lk];
        uint2 r = *(const uint2*)&r2h[(size_t)(m0+lr)*64 + k0 + lk];
        sA[(lk+0)*68+lr] = lky(bf2f_lo(a.x) + bf2f_lo(r.x) + b2l[k0+lk+0]);
        sA[(lk+1)*68+lr] = lky(bf2f_hi(a.x) + bf2f_hi(r.x) + b2l[k0+lk+1]);
        sA[(lk+2)*68+lr] = lky(bf2f_lo(a.y) + bf2f_lo(r.y) + b2l[k0+lk+2]);
        sA[(lk+3)*68+lr] = lky(bf2f_hi(a.y) + bf2f_hi(r.y) + b2l[k0+lk+3]);
        *(float4*)&sB[wk*68+wn] = *(const float4*)&Wm[(size_t)(k0+wk)*64 + wn];
        __syncthreads();
        #pragma unroll
        for (int kk = 0; kk < 16; kk++){
            float4 av = *(const float4*)&sA[kk*68 + ty*4];
            float4 bv = *(const float4*)&sB[kk*68 + tx*4];
            float a4[4] = {av.x, av.y, av.z, av.w};
            float b4[4] = {bv.x, bv.y, bv.z, bv.w};
            #pragma unroll
            for (int i = 0; i < 4; i++)
                #pragma unroll
                for (int j = 0; j < 4; j++) acc[i][j] += a4[i]*b4[j];
        }
        __syncthreads();
    }
    float bb[4];
    #pragma unroll
    for (int j = 0; j < 4; j++) bb[j] = bm[tx*4 + j];
    float ent_local = 0.f;
    #pragma unroll
    for (int i = 0; i < 4; i++){
        float v[4];
        #pragma unroll
        for (int j = 0; j < 4; j++) v[j] = acc[i][j] + bb[j];
        float m = fmaxf(fmaxf(v[0], v[1]), fmaxf(v[2], v[3]));
        for (int o = 1; o < 16; o <<= 1) m = fmaxf(m, __shfl_xor(m, o));
        float e[4];
        float sm = 0.f;
        #pragma unroll
        for (int j = 0; j < 4; j++){ e[j] = __expf(v[j] - m); sm += e[j]; }
        for (int o = 1; o < 16; o <<= 1) sm += __shfl_xor(sm, o);
        float inv = 1.f/sm;
        float p[4];
        float w = 0.f;
        #pragma unroll
        for (int j = 0; j < 4; j++){
            p[j] = e[j]*inv;
            w += -p[j]*__logf(p[j] + 1e-15f);
        }
        for (int o = 1; o < 16; o <<= 1) w += __shfl_xor(w, o);
        if (tx == 0) ent_local += w;
        size_t idx = (size_t)(m0 + ty*4 + i)*64 + tx*4;
        ushort4 oh = { f2bf(p[0]), f2bf(p[1]), f2bf(p[2]), f2bf(p[3]) };
        *(ushort4*)&Sh[idx] = oh;
    }
    red[tid] = ent_local; __syncthreads();
    for (int o = 128; o; o >>= 1){ if (tid < o) red[tid] += red[tid+o]; __syncthreads(); }
    if (tid == 0) atomicAdd(ent_acc, red[0]);
}

// ---------------- fused MFMA: [pooled | adjp | gram] = s^T @ [z | t | s] per graph ----------------
__global__ void __launch_bounds__(1024) k_spmm(
        const unsigned short* __restrict__ Sh, const unsigned short* __restrict__ Zh,
        const unsigned short* __restrict__ Th,
        float* __restrict__ P, float* __restrict__ AP, float* __restrict__ GR,
        float* __restrict__ crossp, float* __restrict__ normgp){
    __shared__ unsigned short At[64*72];    // A^T: [m up to 64][k 64]
    __shared__ unsigned short Bt[256*72];   // B^T: [col 256][k 64]
    __shared__ float rtr[16], rsq[16];
    int b = blockIdx.x, tid = threadIdx.x;
    int w = tid >> 6, l = tid & 63;
    int lr = l & 15, lg = l >> 4;
    int mt = w & 3, ng = w >> 2;
    f32x4 acc[4];
    f32x4 zv = {0.f, 0.f, 0.f, 0.f};
    #pragma unroll
    for (int q = 0; q < 4; q++) acc[q] = zv;
    int gb = b*NPG;
    int sa_n = tid & 63, sa_c = (tid >> 6)*4;
    int sb_k = tid & 63, sb_g = tid >> 6;
    for (int n0 = 0; n0 < NPG; n0 += 64){
        ushort4 sv = *(const ushort4*)&Sh[(size_t)(gb+n0+sa_n)*64 + sa_c];
        At[(sa_c+0)*72 + sa_n] = sv.x;
        At[(sa_c+1)*72 + sa_n] = sv.y;
        At[(sa_c+2)*72 + sa_n] = sv.z;
        At[(sa_c+3)*72 + sa_n] = sv.w;
        {
            int R = gb + n0 + sb_k;
            const unsigned short* srcp;
            if (sb_g < 8)       srcp = &Zh[(size_t)R*128 + sb_g*16];
            else if (sb_g < 12) srcp = &Th[(size_t)R*64 + (sb_g-8)*16];
            else                srcp = &Sh[(size_t)R*64 + (sb_g-12)*16];
            ushort4 a0 = *(const ushort4*)(srcp);
            ushort4 a1 = *(const ushort4*)(srcp+4);
            ushort4 a2 = *(const ushort4*)(srcp+8);
            ushort4 a3 = *(const ushort4*)(srcp+12);
            int cb = sb_g*16;
            Bt[(cb+ 0)*72+sb_k]=a0.x; Bt[(cb+ 1)*72+sb_k]=a0.y; Bt[(cb+ 2)*72+sb_k]=a0.z; Bt[(cb+ 3)*72+sb_k]=a0.w;
            Bt[(cb+ 4)*72+sb_k]=a1.x; Bt[(cb+ 5)*72+sb_k]=a1.y; Bt[(cb+ 6)*72+sb_k]=a1.z; Bt[(cb+ 7)*72+sb_k]=a1.w;
            Bt[(cb+ 8)*72+sb_k]=a2.x; Bt[(cb+ 9)*72+sb_k]=a2.y; Bt[(cb+10)*72+sb_k]=a2.z; Bt[(cb+11)*72+sb_k]=a2.w;
            Bt[(cb+12)*72+sb_k]=a3.x; Bt[(cb+13)*72+sb_k]=a3.y; Bt[(cb+14)*72+sb_k]=a3.z; Bt[(cb+15)*72+sb_k]=a3.w;
        }
        __syncthreads();
        #pragma unroll
        for (int ks = 0; ks < 2; ks++){
            s16x8 af = *(const s16x8*)&At[(mt*16+lr)*72 + ks*32 + lg*8];
            #pragma unroll
            for (int q = 0; q < 4; q++){
                s16x8 bf = *(const s16x8*)&Bt[((ng*4+q)*16+lr)*72 + ks*32 + lg*8];
                acc[q] = __builtin_amdgcn_mfma_f32_16x16x32_bf16(af, bf, acc[q], 0, 0, 0);
            }
        }
        __syncthreads();
    }
    float tr = 0.f, sq = 0.f;
    #pragma unroll
    for (int q = 0; q < 4; q++){
        int col = (ng*4+q)*16 + lr;
        #pragma unroll
        for (int j = 0; j < 4; j++){
            int m = mt*16 + lg*4 + j;
            float v = acc[q][j];
            if (col < 128){
                P[((size_t)b*64+m)*128 + col] = v;
            } else if (col < 192){
                AP[((size_t)b*64+m)*64 + (col-128)] = v;
                if (col-128 == m) tr += v;
            } else {
                GR[((size_t)b*64+m)*64 + (col-192)] = v;
                sq += v*v;
            }
        }
    }
    for (int o = 32; o; o >>= 1){ tr += __shfl_xor(tr, o); sq += __shfl_xor(sq, o); }
    if (l == 0){ rtr[w] = tr; rsq[w] = sq; }
    __syncthreads();
    if (tid == 0){
        float str = 0.f, ssq = 0.f;
        for (int i = 0; i < 16; i++){ str += rtr[i]; ssq += rsq[i]; }
        atomicAdd(crossp, str);
        atomicAdd(normgp, ssq);
    }
}

// ---------------- head stage A: aggout[b] = (adjp[b] @ pooled[b]) / rowsum ----------------
__global__ void __launch_bounds__(256) k_heada(
        const float* __restrict__ AP, const float* __restrict__ P,
        float* __restrict__ aggout){
    __shared__ float sapT[64*65];
    __shared__ float sp[64*33];
    __shared__ float srs[64];
    int b = blockIdx.x, c0 = blockIdx.y*32;
    int tid = threadIdx.x;
    for (int i = tid; i < 4096; i += 256){
        int k = i >> 6, l = i & 63;
        sapT[l*65 + k] = AP[(size_t)b*4096 + i];
    }
    for (int i = tid; i < 2048; i += 256){
        int l = i >> 5, j = i & 31;
        sp[l*33 + j] = P[(size_t)b*8192 + l*128 + c0 + j];
    }
    __syncthreads();
    if (tid < 64){
        float s = 0.f;
        for (int l = 0; l < 64; l++) s += sapT[l*65 + tid];
        srs[tid] = fmaxf(s, 1.f);
    }
    __syncthreads();
    int k = tid & 63, jg = (tid >> 6)*8;
    float acc[8] = {};
    for (int l = 0; l < 64; l++){
        float a = sapT[l*65 + k];
        #pragma unroll
        for (int j = 0; j < 8; j++) acc[j] += a*sp[l*33 + jg + j];
    }
    float inv = 1.f/srs[k];
    #pragma unroll
    for (int j = 0; j < 8; j++)
        aggout[(size_t)b*8192 + k*128 + c0 + jg + j] = acc[j]*inv;
}

// ---------------- head stage C: hcacc[b,:] += h[b, chunk] @ Wc1[chunk, :] ----------------
__global__ void __launch_bounds__(256) k_head2(
        const float* __restrict__ hbuf, const float* __restrict__ Wc1,
        float* __restrict__ hcacc){
    __shared__ float sh[512];
    __shared__ float sred[256];
    int b = blockIdx.x >> 4, ch = blockIdx.x & 15;
    int tid = threadIdx.x;
    for (int i = tid; i < 512; i += 256) sh[i] = hbuf[(size_t)b*8192 + ch*512 + i];
    __syncthreads();
    int j = tid & 127, half = tid >> 7;
    float acc = 0.f;
    const float* W = Wc1 + (size_t)(ch*512 + half*256)*128;
    const float* hh = sh + half*256;
    for (int r = 0; r < 256; r++) acc += hh[r]*W[(size_t)r*128 + j];
    sred[tid] = acc; __syncthreads();
    if (tid < 128) atomicAdd(&hcacc[(size_t)b*128 + tid], sred[tid] + sred[tid+128]);
}

// ---------------- head stage D: logits ----------------
__global__ void k_head3(const float* __restrict__ hcacc, const float* __restrict__ bc1,
                        const float* __restrict__ Wc2, const float* __restrict__ bc2,
                        float* __restrict__ out){
    int b = blockIdx.x, t = threadIdx.x;   // 128 threads
    float hc = lky(hcacc[(size_t)b*128 + t] + bc1[t]);
    float p = hc*Wc2[t];
    for (int o = 32; o; o >>= 1) p += __shfl_xor(p, o);
    __shared__ float r2[2];
    if ((t & 63) == 0) r2[t >> 6] = p;
    __syncthreads();
    if (t == 0) out[b] = r2[0] + r2[1] + bc2[0];
}

__global__ void k_finalize(const unsigned int* __restrict__ a2,
                           const float* __restrict__ cross,
                           const float* __restrict__ normg,
                           const float* __restrict__ ent,
                           float* __restrict__ out){
    float ss = (float)(*a2) - 2.f*(*cross) + (*normg);
    if (ss < 0.f) ss = 0.f;
    float link = sqrtf(ss) / 67108864.f;     // a.size
    out[64] = link + (*ent)/(float)NT;
}

extern "C" void kernel_launch(void* const* d_in, const int* in_sizes, int n_in,
                              void* d_out, int out_size, void* d_ws, size_t ws_size,
                              hipStream_t stream){
    const float* x    = (const float*)d_in[0];
    const int*   ei   = (const int*)d_in[1];
    const int*   src  = ei;
    const int*   dst  = ei + ETOT;
    const float* W1l  = (const float*)d_in[5];
    const float* b1l  = (const float*)d_in[6];
    const float* W1r  = (const float*)d_in[7];
    const float* W2l  = (const float*)d_in[8];
    const float* b2l  = (const float*)d_in[9];
    const float* W2r  = (const float*)d_in[10];
    const float* Wm   = (const float*)d_in[11];
    const float* bm   = (const float*)d_in[12];
    const float* Wrel = (const float*)d_in[13];
    const float* Wroot= (const float*)d_in[14];
    const float* broot= (const float*)d_in[15];
    const float* Wc1  = (const float*)d_in[16];
    const float* bc1  = (const float*)d_in[17];
    const float* Wc2  = (const float*)d_in[18];
    const float* bc2  = (const float*)d_in[19];
    float* out = (float*)d_out;

    char* w = (char*)d_ws;
    size_t off = 0;
    auto take = [&](size_t bytes)->void*{
        void* p = w + off; off = (off + bytes + 255) & ~(size_t)255; return p;
    };
    const size_t MB = 1024*1024;
    // --- small zeroed zone ---
    float* hcacc  = (float*)take((size_t)BATCH*128*4);
    float* accb   = (float*)take(64);
    size_t zero_small = off;
    // --- non-zeroed ---
    unsigned short* wt = (unsigned short*)take((size_t)49152*2);
    float* pooled = (float*)take((size_t)BATCH*64*128*4);
    float* adjp   = (float*)take((size_t)BATCH*64*64*4);
    float* gram   = (float*)take((size_t)BATCH*64*64*4);
    int*   ipd   = (int*)take((size_t)(NT+1)*4);
    int*   ips   = (int*)take((size_t)(NT+1)*4);
    unsigned short* lst_d = (unsigned short*)take((size_t)ETOT*2);
    unsigned short* lst_s = (unsigned short*)take((size_t)ETOT*2);
    char*  regA  = (char*)take(16*MB);   // agg2h (bf16, 8 MB)
    char*  regB  = (char*)take(16*MB);   // y1h (16 MB) -> th (8 MB)
    char*  regC  = (char*)take(16*MB);   // r1h (16 MB) -> [y2h 8MB | s2h 8MB]
    char*  regD  = (char*)take(16*MB);   // r2h (8 MB)
    char*  regE  = (char*)take(16*MB);   // zh (16 MB)
    float* hbuf  = (float*)take((size_t)BATCH*8192*4);
    float* aggo  = (float*)take((size_t)BATCH*8192*4);

    unsigned short* y1h   = (unsigned short*)regB;
    unsigned short* th    = (unsigned short*)regB;
    unsigned short* r1h   = (unsigned short*)regC;
    unsigned short* y2h   = (unsigned short*)regC;
    unsigned short* s2h   = (unsigned short*)(regC + 8*MB);
    unsigned short* r2h   = (unsigned short*)regD;
    unsigned short* zh    = (unsigned short*)regE;
    unsigned short* agg2h = (unsigned short*)regA;

    float* crossp = accb + 0;
    float* normgp = accb + 1;
    float* entp   = accb + 2;
    unsigned int* a2p = (unsigned int*)(accb + 3);

    hipMemsetAsync(d_ws, 0, zero_small, stream);

    // weight transpose+cast (one-time, ~98 KB)
    k_wprep<<<192, 256, 0, stream>>>(W1l, W1r, W2l, W2r, wt);

    // sum(a^2) via LDS nibble hist
    k_a2lds<<<dim3(BATCH, 4), 1024, 0, stream>>>(src, dst, a2p);

    // atomic-free CSR build (per-graph LDS count/scan/scatter, u16 lists)
    k_csr<<<dim3(BATCH, 2), 1024, 0, stream>>>(src, dst, ipd, ips, lst_d, lst_s);

    // SAGE layer 1 (GEMM-before-gather, MFMA): y1 = x@W1l, r1 = x@W1r (bf16)
    k_mfma2b<128,1><<<NT/256, 512, 0, stream>>>(x, wt, wt + 16384, y1h, r1h);
    // gather + fused fin1: zh = lky(mean_agg(y1) + r1 + b1l), bf16
    k_aggh<32,2><<<NT/8, 256, 0, stream>>>(y1h, ipd, lst_d, r1h, b1l, zh, 1);

    // SAGE layer 2 (MFMA): y2 = z@W2l (bf16), r2 = z@W2r (bf16)
    k_mfma2b<64,0><<<NT/256, 512, 0, stream>>>(zh, wt + 32768, wt + 40960, y2h, r2h);
    k_aggh<16,1><<<NT/16, 256, 0, stream>>>(y2h, ipd, lst_d, nullptr, nullptr, agg2h, 1);
    // fused: spre = lky(agg2+r2+b2l); s = softmax(spre@Wm+bm) -> s2h bf16; ent
    k_gemm_wm<<<NT/64, 256, 0, stream>>>(agg2h, r2h, b2l, Wm, bm, s2h, entp);

    // t = A @ s (bf16 out)
    k_aggh<16,1><<<NT/16, 256, 0, stream>>>(s2h, ips, lst_s, nullptr, nullptr, th, 0);

    // fused MFMA: pooled/adjp/gram + trace(cross) + ||gram||^2(normg)
    k_spmm<<<BATCH, 1024, 0, stream>>>(s2h, zh, th, pooled, adjp, gram, crossp, normgp);

    // head: A (agg), B (dual GEMM fp32), C (split-K), D (logits)
    k_heada<<<dim3(BATCH, 4), 256, 0, stream>>>(adjp, pooled, aggo);
    k_gemm<<<dim3(BATCH*64/64, 2), 256, 0, stream>>>(aggo, pooled, Wrel, Wroot, broot, hbuf, BATCH*64, 128, 128, 1, 1, 0);
    k_head2<<<BATCH*16, 256, 0, stream>>>(hbuf, Wc1, hcacc);
    k_head3<<<BATCH, 128, 0, stream>>>(hcacc, bc1, Wc2, bc2, out);
    k_finalize<<<1, 1, 0, stream>>>(a2p, crossp, normgp, entp, out);
}

// Round 11
// 321.694 us; speedup vs baseline: 10.7310x; 1.0433x over previous
//
#include <hip/hip_runtime.h>
#include <math.h>

#define BATCH 64
#define NPG 1024
#define NT (BATCH*NPG)        // 65536 nodes
#define EPER 32768
#define ETOT (BATCH*EPER)     // 2097152 edges

typedef __attribute__((ext_vector_type(4))) float f32x4;
typedef __attribute__((ext_vector_type(8))) short s16x8;

__device__ __forceinline__ float lky(float x){ return x > 0.f ? x : 0.01f*x; }
__device__ __forceinline__ unsigned short f2bf(float f){
    unsigned u = __float_as_uint(f);
    u = u + 0x7FFFu + ((u >> 16) & 1u);      // RNE
    return (unsigned short)(u >> 16);
}
__device__ __forceinline__ float bf2f_lo(unsigned v){ return __uint_as_float(v << 16); }
__device__ __forceinline__ float bf2f_hi(unsigned v){ return __uint_as_float(v & 0xFFFF0000u); }

// ---------------- weight prep: f32 [k][n] -> bf16 [n][k] (transposed) ----------------
__global__ void k_wprep(const float* __restrict__ W1l, const float* __restrict__ W1r,
                        const float* __restrict__ W2l, const float* __restrict__ W2r,
                        unsigned short* __restrict__ wt){
    int i = blockIdx.x*256 + threadIdx.x;   // 0..49151
    if (i < 16384){ int k = i >> 7, n = i & 127; wt[n*128 + k] = f2bf(W1l[i]); }
    else if (i < 32768){ int j = i - 16384; int k = j >> 7, n = j & 127; wt[16384 + n*128 + k] = f2bf(W1r[j]); }
    else if (i < 40960){ int j = i - 32768; int k = j >> 6, n = j & 63; wt[32768 + n*128 + k] = f2bf(W2l[j]); }
    else if (i < 49152){ int j = i - 40960; int k = j >> 6, n = j & 63; wt[40960 + n*128 + k] = f2bf(W2r[j]); }
}

// ---------------- sum(a^2) via per-graph LDS nibble histogram ----------------
__global__ void __launch_bounds__(1024) k_a2lds(const int* __restrict__ src, const int* __restrict__ dst,
                                                unsigned* __restrict__ acc_out){
    __shared__ unsigned nib[32768];   // 128 KB = 262144 nibble counters
    __shared__ unsigned red[16];
    int b = blockIdx.x, pass = blockIdx.y, tid = threadIdx.x;
    for (int i = tid; i < 32768; i += 1024) nib[i] = 0;
    __syncthreads();
    int base = b*EPER;
    for (int i = tid; i < EPER; i += 1024){
        unsigned key = (((unsigned)src[base+i] & 1023u) << 10) | ((unsigned)dst[base+i] & 1023u);
        if ((int)(key >> 18) == pass)
            atomicAdd(&nib[(key & 0x3FFFFu) >> 3], 1u << ((key & 7u)*4u));
    }
    __syncthreads();
    unsigned local = 0;
    for (int i = tid; i < 32768; i += 1024){
        unsigned w = nib[i];
        if (w){
            #pragma unroll
            for (int q = 0; q < 8; q++){ unsigned c = (w >> (4*q)) & 15u; local += c*c; }
        }
    }
    for (int o = 32; o; o >>= 1) local += __shfl_xor(local, o);
    if ((tid & 63) == 0) red[tid >> 6] = local;
    __syncthreads();
    if (tid == 0){
        unsigned s = 0;
        for (int q = 0; q < 16; q++) s += red[q];
        atomicAdd(acc_out, s);
    }
}

// ---------------- atomic-free CSR build: one block per (graph, direction) ----------------
__global__ void __launch_bounds__(1024) k_csr(const int* __restrict__ src, const int* __restrict__ dst,
                                              int* __restrict__ ipd, int* __restrict__ ips,
                                              unsigned short* __restrict__ lst_d,
                                              unsigned short* __restrict__ lst_s){
    __shared__ unsigned eds[EPER];    // 128 KB packed (s<<10)|d
    __shared__ int cnt[1024];
    __shared__ int buf[1024];
    int g = blockIdx.x, which = blockIdx.y, tid = threadIdx.x;
    cnt[tid] = 0;
    __syncthreads();
    int base = g*EPER;
    for (int i = tid; i < EPER; i += 1024){
        unsigned s = (unsigned)src[base+i] & 1023u;
        unsigned d = (unsigned)dst[base+i] & 1023u;
        eds[i] = (s << 10) | d;
        atomicAdd(&cnt[which ? s : d], 1);          // LDS atomic
    }
    __syncthreads();
    int v = cnt[tid];
    int x = v;
    buf[tid] = x; __syncthreads();
    for (int off = 1; off < 1024; off <<= 1){
        int t = (tid >= off) ? buf[tid - off] : 0;
        __syncthreads();
        x += t; buf[tid] = x; __syncthreads();
    }
    int excl = x - v;
    int* ip = which ? ips : ipd;
    ip[g*1024 + tid] = base + excl;
    if (g == 0 && tid == 0) ip[NT] = ETOT;
    cnt[tid] = excl;                                 // cursor
    __syncthreads();
    unsigned short* lst = which ? lst_s : lst_d;
    for (int i = tid; i < EPER; i += 1024){
        unsigned key = eds[i];
        unsigned d = key & 1023u, s = key >> 10;
        unsigned idx = which ? s : d;
        unsigned val = which ? d : s;
        int p = atomicAdd(&cnt[idx], 1);             // LDS atomic
        lst[base + p] = (unsigned short)val;
    }
}

// ---------------- LDS-staged bf16 gather ----------------
// One block = (graph, part), 1024 thr. Stages 64 features x 1024 rows in LDS (136B stride),
// then 16 thr/node consume edges from LDS. TD = row stride (128 or 64).
// MODE: 0 = sum, bf16 out; 1 = mean, bf16 out; 2 = mean + fused z=lky(agg+R+bias), bf16 out.
// TD=128: part = (half<<1)|nodehalf, 512 nodes/block. TD=64: part = node quarter, 256 nodes/block.
template<int MODE, int TD>
__global__ void __launch_bounds__(1024) k_aggl(
        const unsigned short* __restrict__ X, const int* __restrict__ indptr,
        const unsigned short* __restrict__ lst,
        const unsigned short* __restrict__ R, const float* __restrict__ bias,
        unsigned short* __restrict__ out){
    __shared__ uint2 tab[1024*17];    // 139,264 B: 1024 rows x (64 bf16 + 8B pad)
    int bid = blockIdx.x;             // 256 blocks: 64 graphs x 4 parts
    int xcd = bid & 7, j = bid >> 3;
    int gi = j >> 2, part = j & 3;
    int graph = xcd + 8*gi;
    int half, nbase_loc, nchunks;
    if (TD == 128){ half = part >> 1; nbase_loc = (part & 1)*512; nchunks = 8; }
    else          { half = 0;         nbase_loc = part*256;       nchunks = 4; }
    int foff = half*64;
    int tid = threadIdx.x;
    int gb = graph*NPG;
    // stage 64 features of all 1024 rows (uint2 = 4 bf16 per chunk)
    for (int i = tid; i < 16384; i += 1024){
        int row = i >> 4, q = i & 15;
        tab[row*17 + q] = *(const uint2*)&X[(size_t)(gb+row)*TD + foff + q*4];
    }
    __syncthreads();
    int g = tid & 15;
    for (int c = 0; c < nchunks; c++){
        int node = gb + nbase_loc + c*64 + (tid >> 4);
        int st = indptr[node], en = indptr[node+1];
        float a0 = 0.f, a1 = 0.f, a2 = 0.f, a3 = 0.f;
        int e = st;
        for (; e + 4 <= en; e += 4){
            int r0 = lst[e+0], r1 = lst[e+1], r2 = lst[e+2], r3 = lst[e+3];
            uint2 v0 = tab[r0*17 + g];
            uint2 v1 = tab[r1*17 + g];
            uint2 v2 = tab[r2*17 + g];
            uint2 v3 = tab[r3*17 + g];
            a0 += bf2f_lo(v0.x) + bf2f_lo(v1.x) + bf2f_lo(v2.x) + bf2f_lo(v3.x);
            a1 += bf2f_hi(v0.x) + bf2f_hi(v1.x) + bf2f_hi(v2.x) + bf2f_hi(v3.x);
            a2 += bf2f_lo(v0.y) + bf2f_lo(v1.y) + bf2f_lo(v2.y) + bf2f_lo(v3.y);
            a3 += bf2f_hi(v0.y) + bf2f_hi(v1.y) + bf2f_hi(v2.y) + bf2f_hi(v3.y);
        }
        for (; e < en; e++){
            uint2 v = tab[lst[e]*17 + g];
            a0 += bf2f_lo(v.x); a1 += bf2f_hi(v.x);
            a2 += bf2f_lo(v.y); a3 += bf2f_hi(v.y);
        }
        if (MODE >= 1){
            int dg = en - st;
            float inv = 1.f/(float)(dg > 1 ? dg : 1);
            a0 *= inv; a1 *= inv; a2 *= inv; a3 *= inv;
        }
        if (MODE == 2){
            uint2 r = *(const uint2*)&R[(size_t)node*TD + foff + 4*g];
            a0 = lky(a0 + bf2f_lo(r.x) + bias[foff + 4*g + 0]);
            a1 = lky(a1 + bf2f_hi(r.x) + bias[foff + 4*g + 1]);
            a2 = lky(a2 + bf2f_lo(r.y) + bias[foff + 4*g + 2]);
            a3 = lky(a3 + bf2f_hi(r.y) + bias[foff + 4*g + 3]);
        }
        uint2 pk;
        pk.x = (unsigned)f2bf(a0) | ((unsigned)f2bf(a1) << 16);
        pk.y = (unsigned)f2bf(a2) | ((unsigned)f2bf(a3) << 16);
        *(uint2*)&out[(size_t)node*TD + foff + 4*g] = pk;
    }
}

// ---------------- MFMA dual-B GEMM v2: pre-transposed bf16 weights, 512 thr, 256 rows/block ----------------
template<int N, int AF32>
__global__ void __launch_bounds__(512) k_mfma2b(
        const void* __restrict__ Ain, const unsigned short* __restrict__ Wt1,
        const unsigned short* __restrict__ Wt2, unsigned short* __restrict__ C1,
        unsigned short* __restrict__ C2){
    __shared__ unsigned short ldsB[2*N*128];
    int tid = threadIdx.x;
    for (int i = tid; i < N*64; i += 512){
        int n = i >> 6, kk = i & 63;
        int swz = (n*256 + 4*kk) ^ ((n & 7) << 4);
        *(unsigned*)((char*)ldsB + swz)         = ((const unsigned*)Wt1)[i];
        *(unsigned*)((char*)ldsB + N*256 + swz) = ((const unsigned*)Wt2)[i];
    }
    __syncthreads();
    int wave = tid >> 6, l = tid & 63;
    int lr = l & 15, lg = l >> 4;
    constexpr int NF = N/16;
    const unsigned short* Ah = (const unsigned short*)Ain;
    const float* Af = (const float*)Ain;
    #pragma unroll 1
    for (int mc = 0; mc < 2; mc++){
        int arow = blockIdx.x*256 + mc*128 + wave*16 + lr;
        f32x4 acc1[NF], acc2[NF];
        f32x4 zv = {0.f, 0.f, 0.f, 0.f};
        #pragma unroll
        for (int nf = 0; nf < NF; nf++){ acc1[nf] = zv; acc2[nf] = zv; }
        #pragma unroll
        for (int ks = 0; ks < 4; ks++){
            s16x8 af;
            if (AF32){
                const float* p = Af + (size_t)arow*128 + ks*32 + lg*8;
                float4 v0 = *(const float4*)p;
                float4 v1 = *(const float4*)(p + 4);
                af[0] = (short)f2bf(v0.x); af[1] = (short)f2bf(v0.y);
                af[2] = (short)f2bf(v0.z); af[3] = (short)f2bf(v0.w);
                af[4] = (short)f2bf(v1.x); af[5] = (short)f2bf(v1.y);
                af[6] = (short)f2bf(v1.z); af[7] = (short)f2bf(v1.w);
            } else {
                af = *(const s16x8*)(Ah + (size_t)arow*128 + ks*32 + lg*8);
            }
            #pragma unroll
            for (int nf = 0; nf < NF; nf++){
                int n = nf*16 + lr;
                int swz = (n*256 + ks*64 + lg*16) ^ ((n & 7) << 4);
                s16x8 b1 = *(const s16x8*)((const char*)ldsB + swz);
                s16x8 b2 = *(const s16x8*)((const char*)ldsB + N*256 + swz);
                acc1[nf] = __builtin_amdgcn_mfma_f32_16x16x32_bf16(af, b1, acc1[nf], 0, 0, 0);
                acc2[nf] = __builtin_amdgcn_mfma_f32_16x16x32_bf16(af, b2, acc2[nf], 0, 0, 0);
            }
        }
        int orow = blockIdx.x*256 + mc*128 + wave*16 + lg*4;
        #pragma unroll
        for (int nf = 0; nf < NF; nf++){
            int c = nf*16 + lr;
            #pragma unroll
            for (int j = 0; j < 4; j++){
                size_t idx = (size_t)(orow + j)*N + c;
                C1[idx] = f2bf(acc1[nf][j]);
                C2[idx] = f2bf(acc2[nf][j]);
            }
        }
    }
}

// ---------------- fp32 dual GEMM (head only): C = act(A1@W1 [+ A2@W2] + bias) ----------------
__global__ void __launch_bounds__(256) k_gemm(
        const float* __restrict__ A1, const float* __restrict__ A2,
        const float* __restrict__ W1, const float* __restrict__ W2,
        const float* __restrict__ bias, void* __restrict__ C,
        int M, int Nn, int Kd, int dual, int act, int obf){
    __shared__ float sA1[16*68], sB1[16*68], sA2[16*68], sB2[16*68];
    int tid = threadIdx.x;
    int m0 = blockIdx.x*64, n0 = blockIdx.y*64;
    int tx = tid & 15, ty = tid >> 4;
    int lr = tid >> 2, lk = (tid & 3)*4;
    int wk = tid >> 4, wn = (tid & 15)*4;
    float acc[4][4] = {};
    for (int k0 = 0; k0 < Kd; k0 += 16){
        float4 a1 = *(const float4*)&A1[(size_t)(m0+lr)*Kd + k0 + lk];
        float4 w1 = *(const float4*)&W1[(size_t)(k0+wk)*Nn + n0 + wn];
        sA1[(lk+0)*68+lr] = a1.x; sA1[(lk+1)*68+lr] = a1.y;
        sA1[(lk+2)*68+lr] = a1.z; sA1[(lk+3)*68+lr] = a1.w;
        *(float4*)&sB1[wk*68+wn] = w1;
        if (dual){
            float4 a2 = *(const float4*)&A2[(size_t)(m0+lr)*Kd + k0 + lk];
            float4 w2 = *(const float4*)&W2[(size_t)(k0+wk)*Nn + n0 + wn];
            sA2[(lk+0)*68+lr] = a2.x; sA2[(lk+1)*68+lr] = a2.y;
            sA2[(lk+2)*68+lr] = a2.z; sA2[(lk+3)*68+lr] = a2.w;
            *(float4*)&sB2[wk*68+wn] = w2;
        }
        __syncthreads();
        #pragma unroll
        for (int kk = 0; kk < 16; kk++){
            float4 av = *(const float4*)&sA1[kk*68 + ty*4];
            float4 bv = *(const float4*)&sB1[kk*68 + tx*4];
            float a[4] = {av.x, av.y, av.z, av.w};
            float b[4] = {bv.x, bv.y, bv.z, bv.w};
            #pragma unroll
            for (int i = 0; i < 4; i++)
                #pragma unroll
                for (int j = 0; j < 4; j++) acc[i][j] += a[i]*b[j];
            if (dual){
                float4 av2 = *(const float4*)&sA2[kk*68 + ty*4];
                float4 bv2 = *(const float4*)&sB2[kk*68 + tx*4];
                float a2[4] = {av2.x, av2.y, av2.z, av2.w};
                float b2[4] = {bv2.x, bv2.y, bv2.z, bv2.w};
                #pragma unroll
                for (int i = 0; i < 4; i++)
                    #pragma unroll
                    for (int j = 0; j < 4; j++) acc[i][j] += a2[i]*b2[j];
            }
        }
        __syncthreads();
    }
    float bb[4] = {0.f, 0.f, 0.f, 0.f};
    if (bias){
        #pragma unroll
        for (int j = 0; j < 4; j++) bb[j] = bias[n0 + tx*4 + j];
    }
    #pragma unroll
    for (int i = 0; i < 4; i++){
        float v0 = acc[i][0]+bb[0], v1 = acc[i][1]+bb[1], v2 = acc[i][2]+bb[2], v3 = acc[i][3]+bb[3];
        if (act){ v0 = lky(v0); v1 = lky(v1); v2 = lky(v2); v3 = lky(v3); }
        size_t idx = (size_t)(m0 + ty*4 + i)*Nn + n0 + tx*4;
        if (obf){
            ushort4 o = { f2bf(v0), f2bf(v1), f2bf(v2), f2bf(v3) };
            *(ushort4*)&((unsigned short*)C)[idx] = o;
        } else {
            float4 o = { v0, v1, v2, v3 };
            *(float4*)&((float*)C)[idx] = o;
        }
    }
}

// ---------------- fused: spre = lky(agg2h + r2h + b2l); s = softmax(spre@Wm + bm); ent; bf16 out ----------------
__global__ void __launch_bounds__(256) k_gemm_wm(
        const unsigned short* __restrict__ agg2h, const unsigned short* __restrict__ r2h,
        const float* __restrict__ b2l, const float* __restrict__ Wm,
        const float* __restrict__ bm,
        unsigned short* __restrict__ Sh, float* __restrict__ ent_acc){
    __shared__ float sA[16*68], sB[16*68];
    __shared__ float red[256];
    int tid = threadIdx.x;
    int m0 = blockIdx.x*64;
    int tx = tid & 15, ty = tid >> 4;
    int lr = tid >> 2, lk = (tid & 3)*4;
    int wk = tid >> 4, wn = (tid & 15)*4;
    float acc[4][4] = {};
    for (int k0 = 0; k0 < 64; k0 += 16){
        uint2 a = *(const uint2*)&agg2h[(size_t)(m0+lr)*64 + k0 + lk];
        uint2 r = *(const uint2*)&r2h[(size_t)(m0+lr)*64 + k0 + lk];
        sA[(lk+0)*68+lr] = lky(bf2f_lo(a.x) + bf2f_lo(r.x) + b2l[k0+lk+0]);
        sA[(lk+1)*68+lr] = lky(bf2f_hi(a.x) + bf2f_hi(r.x) + b2l[k0+lk+1]);
        sA[(lk+2)*68+lr] = lky(bf2f_lo(a.y) + bf2f_lo(r.y) + b2l[k0+lk+2]);
        sA[(lk+3)*68+lr] = lky(bf2f_hi(a.y) + bf2f_hi(r.y) + b2l[k0+lk+3]);
        *(float4*)&sB[wk*68+wn] = *(const float4*)&Wm[(size_t)(k0+wk)*64 + wn];
        __syncthreads();
        #pragma unroll
        for (int kk = 0; kk < 16; kk++){
            float4 av = *(const float4*)&sA[kk*68 + ty*4];
            float4 bv = *(const float4*)&sB[kk*68 + tx*4];
            float a4[4] = {av.x, av.y, av.z, av.w};
            float b4[4] = {bv.x, bv.y, bv.z, bv.w};
            #pragma unroll
            for (int i = 0; i < 4; i++)
                #pragma unroll
                for (int j = 0; j < 4; j++) acc[i][j] += a4[i]*b4[j];
        }
        __syncthreads();
    }
    float bb[4];
    #pragma unroll
    for (int j = 0; j < 4; j++) bb[j] = bm[tx*4 + j];
    float ent_local = 0.f;
    #pragma unroll
    for (int i = 0; i < 4; i++){
        float v[4];
        #pragma unroll
        for (int j = 0; j < 4; j++) v[j] = acc[i][j] + bb[j];
        float m = fmaxf(fmaxf(v[0], v[1]), fmaxf(v[2], v[3]));
        for (int o = 1; o < 16; o <<= 1) m = fmaxf(m, __shfl_xor(m, o));
        float e[4];
        float sm = 0.f;
        #pragma unroll
        for (int j = 0; j < 4; j++){ e[j] = __expf(v[j] - m); sm += e[j]; }
        for (int o = 1; o < 16; o <<= 1) sm += __shfl_xor(sm, o);
        float inv = 1.f/sm;
        float p[4];
        float w = 0.f;
        #pragma unroll
        for (int j = 0; j < 4; j++){
            p[j] = e[j]*inv;
            w += -p[j]*__logf(p[j] + 1e-15f);
        }
        for (int o = 1; o < 16; o <<= 1) w += __shfl_xor(w, o);
        if (tx == 0) ent_local += w;
        size_t idx = (size_t)(m0 + ty*4 + i)*64 + tx*4;
        ushort4 oh = { f2bf(p[0]), f2bf(p[1]), f2bf(p[2]), f2bf(p[3]) };
        *(ushort4*)&Sh[idx] = oh;
    }
    red[tid] = ent_local; __syncthreads();
    for (int o = 128; o; o >>= 1){ if (tid < o) red[tid] += red[tid+o]; __syncthreads(); }
    if (tid == 0) atomicAdd(ent_acc, red[0]);
}

// ---------------- fused MFMA: [pooled | adjp | gram] = s^T @ [z | t | s] per graph ----------------
__global__ void __launch_bounds__(1024) k_spmm(
        const unsigned short* __restrict__ Sh, const unsigned short* __restrict__ Zh,
        const unsigned short* __restrict__ Th,
        float* __restrict__ P, float* __restrict__ AP, float* __restrict__ GR,
        float* __restrict__ crossp, float* __restrict__ normgp){
    __shared__ unsigned short At[64*72];    // A^T: [m up to 64][k 64]
    __shared__ unsigned short Bt[256*72];   // B^T: [col 256][k 64]
    __shared__ float rtr[16], rsq[16];
    int b = blockIdx.x, tid = threadIdx.x;
    int w = tid >> 6, l = tid & 63;
    int lr = l & 15, lg = l >> 4;
    int mt = w & 3, ng = w >> 2;
    f32x4 acc[4];
    f32x4 zv = {0.f, 0.f, 0.f, 0.f};
    #pragma unroll
    for (int q = 0; q < 4; q++) acc[q] = zv;
    int gb = b*NPG;
    int sa_n = tid & 63, sa_c = (tid >> 6)*4;
    int sb_k = tid & 63, sb_g = tid >> 6;
    for (int n0 = 0; n0 < NPG; n0 += 64){
        ushort4 sv = *(const ushort4*)&Sh[(size_t)(gb+n0+sa_n)*64 + sa_c];
        At[(sa_c+0)*72 + sa_n] = sv.x;
        At[(sa_c+1)*72 + sa_n] = sv.y;
        At[(sa_c+2)*72 + sa_n] = sv.z;
        At[(sa_c+3)*72 + sa_n] = sv.w;
        {
            int R = gb + n0 + sb_k;
            const unsigned short* srcp;
            if (sb_g < 8)       srcp = &Zh[(size_t)R*128 + sb_g*16];
            else if (sb_g < 12) srcp = &Th[(size_t)R*64 + (sb_g-8)*16];
            else                srcp = &Sh[(size_t)R*64 + (sb_g-12)*16];
            ushort4 a0 = *(const ushort4*)(srcp);
            ushort4 a1 = *(const ushort4*)(srcp+4);
            ushort4 a2 = *(const ushort4*)(srcp+8);
            ushort4 a3 = *(const ushort4*)(srcp+12);
            int cb = sb_g*16;
            Bt[(cb+ 0)*72+sb_k]=a0.x; Bt[(cb+ 1)*72+sb_k]=a0.y; Bt[(cb+ 2)*72+sb_k]=a0.z; Bt[(cb+ 3)*72+sb_k]=a0.w;
            Bt[(cb+ 4)*72+sb_k]=a1.x; Bt[(cb+ 5)*72+sb_k]=a1.y; Bt[(cb+ 6)*72+sb_k]=a1.z; Bt[(cb+ 7)*72+sb_k]=a1.w;
            Bt[(cb+ 8)*72+sb_k]=a2.x; Bt[(cb+ 9)*72+sb_k]=a2.y; Bt[(cb+10)*72+sb_k]=a2.z; Bt[(cb+11)*72+sb_k]=a2.w;
            Bt[(cb+12)*72+sb_k]=a3.x; Bt[(cb+13)*72+sb_k]=a3.y; Bt[(cb+14)*72+sb_k]=a3.z; Bt[(cb+15)*72+sb_k]=a3.w;
        }
        __syncthreads();
        #pragma unroll
        for (int ks = 0; ks < 2; ks++){
            s16x8 af = *(const s16x8*)&At[(mt*16+lr)*72 + ks*32 + lg*8];
            #pragma unroll
            for (int q = 0; q < 4; q++){
                s16x8 bf = *(const s16x8*)&Bt[((ng*4+q)*16+lr)*72 + ks*32 + lg*8];
                acc[q] = __builtin_amdgcn_mfma_f32_16x16x32_bf16(af, bf, acc[q], 0, 0, 0);
            }
        }
        __syncthreads();
    }
    float tr = 0.f, sq = 0.f;
    #pragma unroll
    for (int q = 0; q < 4; q++){
        int col = (ng*4+q)*16 + lr;
        #pragma unroll
        for (int j = 0; j < 4; j++){
            int m = mt*16 + lg*4 + j;
            float v = acc[q][j];
            if (col < 128){
                P[((size_t)b*64+m)*128 + col] = v;
            } else if (col < 192){
                AP[((size_t)b*64+m)*64 + (col-128)] = v;
                if (col-128 == m) tr += v;
            } else {
                GR[((size_t)b*64+m)*64 + (col-192)] = v;
                sq += v*v;
            }
        }
    }
    for (int o = 32; o; o >>= 1){ tr += __shfl_xor(tr, o); sq += __shfl_xor(sq, o); }
    if (l == 0){ rtr[w] = tr; rsq[w] = sq; }
    __syncthreads();
    if (tid == 0){
        float str = 0.f, ssq = 0.f;
        for (int i = 0; i < 16; i++){ str += rtr[i]; ssq += rsq[i]; }
        atomicAdd(crossp, str);
        atomicAdd(normgp, ssq);
    }
}

// ---------------- head stage A: aggout[b] = (adjp[b] @ pooled[b]) / rowsum ----------------
__global__ void __launch_bounds__(256) k_heada(
        const float* __restrict__ AP, const float* __restrict__ P,
        float* __restrict__ aggout){
    __shared__ float sapT[64*65];
    __shared__ float sp[64*33];
    __shared__ float srs[64];
    int b = blockIdx.x, c0 = blockIdx.y*32;
    int tid = threadIdx.x;
    for (int i = tid; i < 4096; i += 256){
        int k = i >> 6, l = i & 63;
        sapT[l*65 + k] = AP[(size_t)b*4096 + i];
    }
    for (int i = tid; i < 2048; i += 256){
        int l = i >> 5, j = i & 31;
        sp[l*33 + j] = P[(size_t)b*8192 + l*128 + c0 + j];
    }
    __syncthreads();
    if (tid < 64){
        float s = 0.f;
        for (int l = 0; l < 64; l++) s += sapT[l*65 + tid];
        srs[tid] = fmaxf(s, 1.f);
    }
    __syncthreads();
    int k = tid & 63, jg = (tid >> 6)*8;
    float acc[8] = {};
    for (int l = 0; l < 64; l++){
        float a = sapT[l*65 + k];
        #pragma unroll
        for (int j = 0; j < 8; j++) acc[j] += a*sp[l*33 + jg + j];
    }
    float inv = 1.f/srs[k];
    #pragma unroll
    for (int j = 0; j < 8; j++)
        aggout[(size_t)b*8192 + k*128 + c0 + jg + j] = acc[j]*inv;
}

// ---------------- head stage C: hcacc[b,:] += h[b, chunk] @ Wc1[chunk, :] ----------------
__global__ void __launch_bounds__(256) k_head2(
        const float* __restrict__ hbuf, const float* __restrict__ Wc1,
        float* __restrict__ hcacc){
    __shared__ float sh[512];
    __shared__ float sred[256];
    int b = blockIdx.x >> 4, ch = blockIdx.x & 15;
    int tid = threadIdx.x;
    for (int i = tid; i < 512; i += 256) sh[i] = hbuf[(size_t)b*8192 + ch*512 + i];
    __syncthreads();
    int j = tid & 127, half = tid >> 7;
    float acc = 0.f;
    const float* W = Wc1 + (size_t)(ch*512 + half*256)*128;
    const float* hh = sh + half*256;
    for (int r = 0; r < 256; r++) acc += hh[r]*W[(size_t)r*128 + j];
    sred[tid] = acc; __syncthreads();
    if (tid < 128) atomicAdd(&hcacc[(size_t)b*128 + tid], sred[tid] + sred[tid+128]);
}

// ---------------- head stage D: logits ----------------
__global__ void k_head3(const float* __restrict__ hcacc, const float* __restrict__ bc1,
                        const float* __restrict__ Wc2, const float* __restrict__ bc2,
                        float* __restrict__ out){
    int b = blockIdx.x, t = threadIdx.x;   // 128 threads
    float hc = lky(hcacc[(size_t)b*128 + t] + bc1[t]);
    float p = hc*Wc2[t];
    for (int o = 32; o; o >>= 1) p += __shfl_xor(p, o);
    __shared__ float r2[2];
    if ((t & 63) == 0) r2[t >> 6] = p;
    __syncthreads();
    if (t == 0) out[b] = r2[0] + r2[1] + bc2[0];
}

__global__ void k_finalize(const unsigned int* __restrict__ a2,
                           const float* __restrict__ cross,
                           const float* __restrict__ normg,
                           const float* __restrict__ ent,
                           float* __restrict__ out){
    float ss = (float)(*a2) - 2.f*(*cross) + (*normg);
    if (ss < 0.f) ss = 0.f;
    float link = sqrtf(ss) / 67108864.f;     // a.size
    out[64] = link + (*ent)/(float)NT;
}

extern "C" void kernel_launch(void* const* d_in, const int* in_sizes, int n_in,
                              void* d_out, int out_size, void* d_ws, size_t ws_size,
                              hipStream_t stream){
    const float* x    = (const float*)d_in[0];
    const int*   ei   = (const int*)d_in[1];
    const int*   src  = ei;
    const int*   dst  = ei + ETOT;
    const float* W1l  = (const float*)d_in[5];
    const float* b1l  = (const float*)d_in[6];
    const float* W1r  = (const float*)d_in[7];
    const float* W2l  = (const float*)d_in[8];
    const float* b2l  = (const float*)d_in[9];
    const float* W2r  = (const float*)d_in[10];
    const float* Wm   = (const float*)d_in[11];
    const float* bm   = (const float*)d_in[12];
    const float* Wrel = (const float*)d_in[13];
    const float* Wroot= (const float*)d_in[14];
    const float* broot= (const float*)d_in[15];
    const float* Wc1  = (const float*)d_in[16];
    const float* bc1  = (const float*)d_in[17];
    const float* Wc2  = (const float*)d_in[18];
    const float* bc2  = (const float*)d_in[19];
    float* out = (float*)d_out;

    char* w = (char*)d_ws;
    size_t off = 0;
    auto take = [&](size_t bytes)->void*{
        void* p = w + off; off = (off + bytes + 255) & ~(size_t)255; return p;
    };
    const size_t MB = 1024*1024;
    // --- small zeroed zone ---
    float* hcacc  = (float*)take((size_t)BATCH*128*4);
    float* accb   = (float*)take(64);
    size_t zero_small = off;
    // --- non-zeroed ---
    unsigned short* wt = (unsigned short*)take((size_t)49152*2);
    float* pooled = (float*)take((size_t)BATCH*64*128*4);
    float* adjp   = (float*)take((size_t)BATCH*64*64*4);
    float* gram   = (float*)take((size_t)BATCH*64*64*4);
    int*   ipd   = (int*)take((size_t)(NT+1)*4);
    int*   ips   = (int*)take((size_t)(NT+1)*4);
    unsigned short* lst_d = (unsigned short*)take((size_t)ETOT*2);
    unsigned short* lst_s = (unsigned short*)take((size_t)ETOT*2);
    char*  regA  = (char*)take(16*MB);   // agg2h (bf16, 8 MB)
    char*  regB  = (char*)take(16*MB);   // y1h (16 MB) -> th (8 MB)
    char*  regC  = (char*)take(16*MB);   // r1h (16 MB) -> [y2h 8MB | s2h 8MB]
    char*  regD  = (char*)take(16*MB);   // r2h (8 MB)
    char*  regE  = (char*)take(16*MB);   // zh (16 MB)
    float* hbuf  = (float*)take((size_t)BATCH*8192*4);
    float* aggo  = (float*)take((size_t)BATCH*8192*4);

    unsigned short* y1h   = (unsigned short*)regB;
    unsigned short* th    = (unsigned short*)regB;
    unsigned short* r1h   = (unsigned short*)regC;
    unsigned short* y2h   = (unsigned short*)regC;
    unsigned short* s2h   = (unsigned short*)(regC + 8*MB);
    unsigned short* r2h   = (unsigned short*)regD;
    unsigned short* zh    = (unsigned short*)regE;
    unsigned short* agg2h = (unsigned short*)regA;

    float* crossp = accb + 0;
    float* normgp = accb + 1;
    float* entp   = accb + 2;
    unsigned int* a2p = (unsigned int*)(accb + 3);

    hipMemsetAsync(d_ws, 0, zero_small, stream);

    // weight transpose+cast (one-time, ~98 KB)
    k_wprep<<<192, 256, 0, stream>>>(W1l, W1r, W2l, W2r, wt);

    // sum(a^2) via LDS nibble hist
    k_a2lds<<<dim3(BATCH, 4), 1024, 0, stream>>>(src, dst, a2p);

    // atomic-free CSR build (per-graph LDS count/scan/scatter, u16 lists)
    k_csr<<<dim3(BATCH, 2), 1024, 0, stream>>>(src, dst, ipd, ips, lst_d, lst_s);

    // SAGE layer 1 (GEMM-before-gather, MFMA): y1 = x@W1l, r1 = x@W1r (bf16)
    k_mfma2b<128,1><<<NT/256, 512, 0, stream>>>(x, wt, wt + 16384, y1h, r1h);
    // LDS-staged gather + fused fin1: zh = lky(mean_agg(y1) + r1 + b1l), bf16
    k_aggl<2,128><<<256, 1024, 0, stream>>>(y1h, ipd, lst_d, r1h, b1l, zh);

    // SAGE layer 2 (MFMA): y2 = z@W2l (bf16), r2 = z@W2r (bf16)
    k_mfma2b<64,0><<<NT/256, 512, 0, stream>>>(zh, wt + 32768, wt + 40960, y2h, r2h);
    k_aggl<1,64><<<256, 1024, 0, stream>>>(y2h, ipd, lst_d, nullptr, nullptr, agg2h);
    // fused: spre = lky(agg2+r2+b2l); s = softmax(spre@Wm+bm) -> s2h bf16; ent
    k_gemm_wm<<<NT/64, 256, 0, stream>>>(agg2h, r2h, b2l, Wm, bm, s2h, entp);

    // t = A @ s (bf16 out)
    k_aggl<0,64><<<256, 1024, 0, stream>>>(s2h, ips, lst_s, nullptr, nullptr, th);

    // fused MFMA: pooled/adjp/gram + trace(cross) + ||gram||^2(normg)
    k_spmm<<<BATCH, 1024, 0, stream>>>(s2h, zh, th, pooled, adjp, gram, crossp, normgp);

    // head: A (agg), B (dual GEMM fp32), C (split-K), D (logits)
    k_heada<<<dim3(BATCH, 4), 256, 0, stream>>>(adjp, pooled, aggo);
    k_gemm<<<dim3(BATCH*64/64, 2), 256, 0, stream>>>(aggo, pooled, Wrel, Wroot, broot, hbuf, BATCH*64, 128, 128, 1, 1, 0);
    k_head2<<<BATCH*16, 256, 0, stream>>>(hbuf, Wc1, hcacc);
    k_head3<<<BATCH, 128, 0, stream>>>(hcacc, bc1, Wc2, bc2, out);
    k_finalize<<<1, 1, 0, stream>>>(a2p, crossp, normgp, entp, out);
}

// Round 12
// 306.945 us; speedup vs baseline: 11.2467x; 1.0481x over previous
//
#include <hip/hip_runtime.h>
#include <math.h>

#define BATCH 64
#define NPG 1024
#define NT (BATCH*NPG)        // 65536 nodes
#define EPER 32768
#define ETOT (BATCH*EPER)     // 2097152 edges

typedef __attribute__((ext_vector_type(4))) float f32x4;
typedef __attribute__((ext_vector_type(8))) short s16x8;

__device__ __forceinline__ float lky(float x){ return x > 0.f ? x : 0.01f*x; }
__device__ __forceinline__ unsigned short f2bf(float f){
    unsigned u = __float_as_uint(f);
    u = u + 0x7FFFu + ((u >> 16) & 1u);      // RNE
    return (unsigned short)(u >> 16);
}
__device__ __forceinline__ float bf2f_lo(unsigned v){ return __uint_as_float(v << 16); }
__device__ __forceinline__ float bf2f_hi(unsigned v){ return __uint_as_float(v & 0xFFFF0000u); }

// ---------------- fp32 -> bf16 cast (vectorized, coalesced) ----------------
__global__ void k_castx(const float* __restrict__ in, unsigned short* __restrict__ out, int n4){
    int i = blockIdx.x*256 + threadIdx.x;
    if (i < n4){
        float4 v = ((const float4*)in)[i];
        ushort4 o = { f2bf(v.x), f2bf(v.y), f2bf(v.z), f2bf(v.w) };
        ((ushort4*)out)[i] = o;
    }
}

// ---------------- weight prep: f32 [k][n] -> bf16 [n][k] (transposed) ----------------
__global__ void k_wprep(const float* __restrict__ W1l, const float* __restrict__ W1r,
                        const float* __restrict__ W2l, const float* __restrict__ W2r,
                        unsigned short* __restrict__ wt){
    int i = blockIdx.x*256 + threadIdx.x;   // 0..49151
    if (i < 16384){ int k = i >> 7, n = i & 127; wt[n*128 + k] = f2bf(W1l[i]); }
    else if (i < 32768){ int j = i - 16384; int k = j >> 7, n = j & 127; wt[16384 + n*128 + k] = f2bf(W1r[j]); }
    else if (i < 40960){ int j = i - 32768; int k = j >> 6, n = j & 63; wt[32768 + n*128 + k] = f2bf(W2l[j]); }
    else if (i < 49152){ int j = i - 40960; int k = j >> 6, n = j & 63; wt[40960 + n*128 + k] = f2bf(W2r[j]); }
}

// ---------------- sum(a^2) via per-graph LDS nibble histogram ----------------
__global__ void __launch_bounds__(1024) k_a2lds(const int* __restrict__ src, const int* __restrict__ dst,
                                                unsigned* __restrict__ acc_out){
    __shared__ unsigned nib[32768];   // 128 KB = 262144 nibble counters
    __shared__ unsigned red[16];
    int b = blockIdx.x, pass = blockIdx.y, tid = threadIdx.x;
    for (int i = tid; i < 32768; i += 1024) nib[i] = 0;
    __syncthreads();
    int base = b*EPER;
    for (int i = tid; i < EPER; i += 1024){
        unsigned key = (((unsigned)src[base+i] & 1023u) << 10) | ((unsigned)dst[base+i] & 1023u);
        if ((int)(key >> 18) == pass)
            atomicAdd(&nib[(key & 0x3FFFFu) >> 3], 1u << ((key & 7u)*4u));
    }
    __syncthreads();
    unsigned local = 0;
    for (int i = tid; i < 32768; i += 1024){
        unsigned w = nib[i];
        if (w){
            #pragma unroll
            for (int q = 0; q < 8; q++){ unsigned c = (w >> (4*q)) & 15u; local += c*c; }
        }
    }
    for (int o = 32; o; o >>= 1) local += __shfl_xor(local, o);
    if ((tid & 63) == 0) red[tid >> 6] = local;
    __syncthreads();
    if (tid == 0){
        unsigned s = 0;
        for (int q = 0; q < 16; q++) s += red[q];
        atomicAdd(acc_out, s);
    }
}

// ---------------- atomic-free CSR build: one block per (graph, direction) ----------------
__global__ void __launch_bounds__(1024) k_csr(const int* __restrict__ src, const int* __restrict__ dst,
                                              int* __restrict__ ipd, int* __restrict__ ips,
                                              unsigned short* __restrict__ lst_d,
                                              unsigned short* __restrict__ lst_s){
    __shared__ unsigned eds[EPER];    // 128 KB packed (s<<10)|d
    __shared__ int cnt[1024];
    __shared__ int buf[1024];
    int g = blockIdx.x, which = blockIdx.y, tid = threadIdx.x;
    cnt[tid] = 0;
    __syncthreads();
    int base = g*EPER;
    for (int i = tid; i < EPER; i += 1024){
        unsigned s = (unsigned)src[base+i] & 1023u;
        unsigned d = (unsigned)dst[base+i] & 1023u;
        eds[i] = (s << 10) | d;
        atomicAdd(&cnt[which ? s : d], 1);          // LDS atomic
    }
    __syncthreads();
    int v = cnt[tid];
    int x = v;
    buf[tid] = x; __syncthreads();
    for (int off = 1; off < 1024; off <<= 1){
        int t = (tid >= off) ? buf[tid - off] : 0;
        __syncthreads();
        x += t; buf[tid] = x; __syncthreads();
    }
    int excl = x - v;
    int* ip = which ? ips : ipd;
    ip[g*1024 + tid] = base + excl;
    if (g == 0 && tid == 0) ip[NT] = ETOT;
    cnt[tid] = excl;                                 // cursor
    __syncthreads();
    unsigned short* lst = which ? lst_s : lst_d;
    for (int i = tid; i < EPER; i += 1024){
        unsigned key = eds[i];
        unsigned d = key & 1023u, s = key >> 10;
        unsigned idx = which ? s : d;
        unsigned val = which ? d : s;
        int p = atomicAdd(&cnt[idx], 1);             // LDS atomic
        lst[base + p] = (unsigned short)val;
    }
}

// ---------------- LDS-staged bf16 gather ----------------
// One block = (graph, part), 1024 thr. TD = row stride (128 or 64).
// MODE: 0 = sum; 1 = mean; 2 = mean + fused z=lky(agg+R+bias). bf16 out.
template<int MODE, int TD>
__global__ void __launch_bounds__(1024) k_aggl(
        const unsigned short* __restrict__ X, const int* __restrict__ indptr,
        const unsigned short* __restrict__ lst,
        const unsigned short* __restrict__ R, const float* __restrict__ bias,
        unsigned short* __restrict__ out){
    __shared__ uint2 tab[1024*17];    // 139,264 B: 1024 rows x (64 bf16 + 8B pad)
    int bid = blockIdx.x;             // 256 blocks: 64 graphs x 4 parts
    int xcd = bid & 7, j = bid >> 3;
    int gi = j >> 2, part = j & 3;
    int graph = xcd + 8*gi;
    int half, nbase_loc, nchunks;
    if (TD == 128){ half = part >> 1; nbase_loc = (part & 1)*512; nchunks = 8; }
    else          { half = 0;         nbase_loc = part*256;       nchunks = 4; }
    int foff = half*64;
    int tid = threadIdx.x;
    int gb = graph*NPG;
    for (int i = tid; i < 16384; i += 1024){
        int row = i >> 4, q = i & 15;
        tab[row*17 + q] = *(const uint2*)&X[(size_t)(gb+row)*TD + foff + q*4];
    }
    __syncthreads();
    int g = tid & 15;
    for (int c = 0; c < nchunks; c++){
        int node = gb + nbase_loc + c*64 + (tid >> 4);
        int st = indptr[node], en = indptr[node+1];
        float a0 = 0.f, a1 = 0.f, a2 = 0.f, a3 = 0.f;
        int e = st;
        for (; e + 4 <= en; e += 4){
            int r0 = lst[e+0], r1 = lst[e+1], r2 = lst[e+2], r3 = lst[e+3];
            uint2 v0 = tab[r0*17 + g];
            uint2 v1 = tab[r1*17 + g];
            uint2 v2 = tab[r2*17 + g];
            uint2 v3 = tab[r3*17 + g];
            a0 += bf2f_lo(v0.x) + bf2f_lo(v1.x) + bf2f_lo(v2.x) + bf2f_lo(v3.x);
            a1 += bf2f_hi(v0.x) + bf2f_hi(v1.x) + bf2f_hi(v2.x) + bf2f_hi(v3.x);
            a2 += bf2f_lo(v0.y) + bf2f_lo(v1.y) + bf2f_lo(v2.y) + bf2f_lo(v3.y);
            a3 += bf2f_hi(v0.y) + bf2f_hi(v1.y) + bf2f_hi(v2.y) + bf2f_hi(v3.y);
        }
        for (; e < en; e++){
            uint2 v = tab[lst[e]*17 + g];
            a0 += bf2f_lo(v.x); a1 += bf2f_hi(v.x);
            a2 += bf2f_lo(v.y); a3 += bf2f_hi(v.y);
        }
        if (MODE >= 1){
            int dg = en - st;
            float inv = 1.f/(float)(dg > 1 ? dg : 1);
            a0 *= inv; a1 *= inv; a2 *= inv; a3 *= inv;
        }
        if (MODE == 2){
            uint2 r = *(const uint2*)&R[(size_t)node*TD + foff + 4*g];
            a0 = lky(a0 + bf2f_lo(r.x) + bias[foff + 4*g + 0]);
            a1 = lky(a1 + bf2f_hi(r.x) + bias[foff + 4*g + 1]);
            a2 = lky(a2 + bf2f_lo(r.y) + bias[foff + 4*g + 2]);
            a3 = lky(a3 + bf2f_hi(r.y) + bias[foff + 4*g + 3]);
        }
        uint2 pk;
        pk.x = (unsigned)f2bf(a0) | ((unsigned)f2bf(a1) << 16);
        pk.y = (unsigned)f2bf(a2) | ((unsigned)f2bf(a3) << 16);
        *(uint2*)&out[(size_t)node*TD + foff + 4*g] = pk;
    }
}

// ---------------- MFMA dual-B GEMM v3: bf16 A, pre-transposed bf16 weights ----------------
// 512 thr, 128 rows/block, grid NT/128 = 512 (2 blocks/CU). C1 = A@W1, C2 = A@W2 (bf16).
template<int N>
__global__ void __launch_bounds__(512) k_mfma2b(
        const unsigned short* __restrict__ Ah, const unsigned short* __restrict__ Wt1,
        const unsigned short* __restrict__ Wt2, unsigned short* __restrict__ C1,
        unsigned short* __restrict__ C2){
    __shared__ unsigned short ldsB[2*N*128];
    int tid = threadIdx.x;
    for (int i = tid; i < N*64; i += 512){
        int n = i >> 6, kk = i & 63;
        int swz = (n*256 + 4*kk) ^ ((n & 7) << 4);
        *(unsigned*)((char*)ldsB + swz)         = ((const unsigned*)Wt1)[i];
        *(unsigned*)((char*)ldsB + N*256 + swz) = ((const unsigned*)Wt2)[i];
    }
    __syncthreads();
    int wave = tid >> 6, l = tid & 63;
    int lr = l & 15, lg = l >> 4;
    constexpr int NF = N/16;
    int arow = blockIdx.x*128 + wave*16 + lr;
    f32x4 acc1[NF], acc2[NF];
    f32x4 zv = {0.f, 0.f, 0.f, 0.f};
    #pragma unroll
    for (int nf = 0; nf < NF; nf++){ acc1[nf] = zv; acc2[nf] = zv; }
    #pragma unroll
    for (int ks = 0; ks < 4; ks++){
        s16x8 af = *(const s16x8*)(Ah + (size_t)arow*128 + ks*32 + lg*8);
        #pragma unroll
        for (int nf = 0; nf < NF; nf++){
            int n = nf*16 + lr;
            int swz = (n*256 + ks*64 + lg*16) ^ ((n & 7) << 4);
            s16x8 b1 = *(const s16x8*)((const char*)ldsB + swz);
            s16x8 b2 = *(const s16x8*)((const char*)ldsB + N*256 + swz);
            acc1[nf] = __builtin_amdgcn_mfma_f32_16x16x32_bf16(af, b1, acc1[nf], 0, 0, 0);
            acc2[nf] = __builtin_amdgcn_mfma_f32_16x16x32_bf16(af, b2, acc2[nf], 0, 0, 0);
        }
    }
    int orow = blockIdx.x*128 + wave*16 + lg*4;
    #pragma unroll
    for (int nf = 0; nf < NF; nf++){
        int c = nf*16 + lr;
        #pragma unroll
        for (int j = 0; j < 4; j++){
            size_t idx = (size_t)(orow + j)*N + c;
            C1[idx] = f2bf(acc1[nf][j]);
            C2[idx] = f2bf(acc2[nf][j]);
        }
    }
}

// ---------------- fp32 dual GEMM (head only): C = act(A1@W1 [+ A2@W2] + bias) ----------------
__global__ void __launch_bounds__(256) k_gemm(
        const float* __restrict__ A1, const float* __restrict__ A2,
        const float* __restrict__ W1, const float* __restrict__ W2,
        const float* __restrict__ bias, void* __restrict__ C,
        int M, int Nn, int Kd, int dual, int act, int obf){
    __shared__ float sA1[16*68], sB1[16*68], sA2[16*68], sB2[16*68];
    int tid = threadIdx.x;
    int m0 = blockIdx.x*64, n0 = blockIdx.y*64;
    int tx = tid & 15, ty = tid >> 4;
    int lr = tid >> 2, lk = (tid & 3)*4;
    int wk = tid >> 4, wn = (tid & 15)*4;
    float acc[4][4] = {};
    for (int k0 = 0; k0 < Kd; k0 += 16){
        float4 a1 = *(const float4*)&A1[(size_t)(m0+lr)*Kd + k0 + lk];
        float4 w1 = *(const float4*)&W1[(size_t)(k0+wk)*Nn + n0 + wn];
        sA1[(lk+0)*68+lr] = a1.x; sA1[(lk+1)*68+lr] = a1.y;
        sA1[(lk+2)*68+lr] = a1.z; sA1[(lk+3)*68+lr] = a1.w;
        *(float4*)&sB1[wk*68+wn] = w1;
        if (dual){
            float4 a2 = *(const float4*)&A2[(size_t)(m0+lr)*Kd + k0 + lk];
            float4 w2 = *(const float4*)&W2[(size_t)(k0+wk)*Nn + n0 + wn];
            sA2[(lk+0)*68+lr] = a2.x; sA2[(lk+1)*68+lr] = a2.y;
            sA2[(lk+2)*68+lr] = a2.z; sA2[(lk+3)*68+lr] = a2.w;
            *(float4*)&sB2[wk*68+wn] = w2;
        }
        __syncthreads();
        #pragma unroll
        for (int kk = 0; kk < 16; kk++){
            float4 av = *(const float4*)&sA1[kk*68 + ty*4];
            float4 bv = *(const float4*)&sB1[kk*68 + tx*4];
            float a[4] = {av.x, av.y, av.z, av.w};
            float b[4] = {bv.x, bv.y, bv.z, bv.w};
            #pragma unroll
            for (int i = 0; i < 4; i++)
                #pragma unroll
                for (int j = 0; j < 4; j++) acc[i][j] += a[i]*b[j];
            if (dual){
                float4 av2 = *(const float4*)&sA2[kk*68 + ty*4];
                float4 bv2 = *(const float4*)&sB2[kk*68 + tx*4];
                float a2[4] = {av2.x, av2.y, av2.z, av2.w};
                float b2[4] = {bv2.x, bv2.y, bv2.z, bv2.w};
                #pragma unroll
                for (int i = 0; i < 4; i++)
                    #pragma unroll
                    for (int j = 0; j < 4; j++) acc[i][j] += a2[i]*b2[j];
            }
        }
        __syncthreads();
    }
    float bb[4] = {0.f, 0.f, 0.f, 0.f};
    if (bias){
        #pragma unroll
        for (int j = 0; j < 4; j++) bb[j] = bias[n0 + tx*4 + j];
    }
    #pragma unroll
    for (int i = 0; i < 4; i++){
        float v0 = acc[i][0]+bb[0], v1 = acc[i][1]+bb[1], v2 = acc[i][2]+bb[2], v3 = acc[i][3]+bb[3];
        if (act){ v0 = lky(v0); v1 = lky(v1); v2 = lky(v2); v3 = lky(v3); }
        size_t idx = (size_t)(m0 + ty*4 + i)*Nn + n0 + tx*4;
        if (obf){
            ushort4 o = { f2bf(v0), f2bf(v1), f2bf(v2), f2bf(v3) };
            *(ushort4*)&((unsigned short*)C)[idx] = o;
        } else {
            float4 o = { v0, v1, v2, v3 };
            *(float4*)&((float*)C)[idx] = o;
        }
    }
}

// ---------------- fused: spre = lky(agg2h + r2h + b2l); s = softmax(spre@Wm + bm); ent; bf16 out ----------------
__global__ void __launch_bounds__(256) k_gemm_wm(
        const unsigned short* __restrict__ agg2h, const unsigned short* __restrict__ r2h,
        const float* __restrict__ b2l, const float* __restrict__ Wm,
        const float* __restrict__ bm,
        unsigned short* __restrict__ Sh, float* __restrict__ ent_acc){
    __shared__ float sA[16*68], sB[16*68];
    __shared__ float red[256];
    int tid = threadIdx.x;
    int m0 = blockIdx.x*64;
    int tx = tid & 15, ty = tid >> 4;
    int lr = tid >> 2, lk = (tid & 3)*4;
    int wk = tid >> 4, wn = (tid & 15)*4;
    float acc[4][4] = {};
    for (int k0 = 0; k0 < 64; k0 += 16){
        uint2 a = *(const uint2*)&agg2h[(size_t)(m0+lr)*64 + k0 + lk];
        uint2 r = *(const uint2*)&r2h[(size_t)(m0+lr)*64 + k0 + lk];
        sA[(lk+0)*68+lr] = lky(bf2f_lo(a.x) + bf2f_lo(r.x) + b2l[k0+lk+0]);
        sA[(lk+1)*68+lr] = lky(bf2f_hi(a.x) + bf2f_hi(r.x) + b2l[k0+lk+1]);
        sA[(lk+2)*68+lr] = lky(bf2f_lo(a.y) + bf2f_lo(r.y) + b2l[k0+lk+2]);
        sA[(lk+3)*68+lr] = lky(bf2f_hi(a.y) + bf2f_hi(r.y) + b2l[k0+lk+3]);
        *(float4*)&sB[wk*68+wn] = *(const float4*)&Wm[(size_t)(k0+wk)*64 + wn];
        __syncthreads();
        #pragma unroll
        for (int kk = 0; kk < 16; kk++){
            float4 av = *(const float4*)&sA[kk*68 + ty*4];
            float4 bv = *(const float4*)&sB[kk*68 + tx*4];
            float a4[4] = {av.x, av.y, av.z, av.w};
            float b4[4] = {bv.x, bv.y, bv.z, bv.w};
            #pragma unroll
            for (int i = 0; i < 4; i++)
                #pragma unroll
                for (int j = 0; j < 4; j++) acc[i][j] += a4[i]*b4[j];
        }
        __syncthreads();
    }
    float bb[4];
    #pragma unroll
    for (int j = 0; j < 4; j++) bb[j] = bm[tx*4 + j];
    float ent_local = 0.f;
    #pragma unroll
    for (int i = 0; i < 4; i++){
        float v[4];
        #pragma unroll
        for (int j = 0; j < 4; j++) v[j] = acc[i][j] + bb[j];
        float m = fmaxf(fmaxf(v[0], v[1]), fmaxf(v[2], v[3]));
        for (int o = 1; o < 16; o <<= 1) m = fmaxf(m, __shfl_xor(m, o));
        float e[4];
        float sm = 0.f;
        #pragma unroll
        for (int j = 0; j < 4; j++){ e[j] = __expf(v[j] - m); sm += e[j]; }
        for (int o = 1; o < 16; o <<= 1) sm += __shfl_xor(sm, o);
        float inv = 1.f/sm;
        float p[4];
        float w = 0.f;
        #pragma unroll
        for (int j = 0; j < 4; j++){
            p[j] = e[j]*inv;
            w += -p[j]*__logf(p[j] + 1e-15f);
        }
        for (int o = 1; o < 16; o <<= 1) w += __shfl_xor(w, o);
        if (tx == 0) ent_local += w;
        size_t idx = (size_t)(m0 + ty*4 + i)*64 + tx*4;
        ushort4 oh = { f2bf(p[0]), f2bf(p[1]), f2bf(p[2]), f2bf(p[3]) };
        *(ushort4*)&Sh[idx] = oh;
    }
    red[tid] = ent_local; __syncthreads();
    for (int o = 128; o; o >>= 1){ if (tid < o) red[tid] += red[tid+o]; __syncthreads(); }
    if (tid == 0) atomicAdd(ent_acc, red[0]);
}

// ---------------- fused MFMA: [pooled | adjp | gram] = s^T @ [z | t | s] per graph ----------------
__global__ void __launch_bounds__(1024) k_spmm(
        const unsigned short* __restrict__ Sh, const unsigned short* __restrict__ Zh,
        const unsigned short* __restrict__ Th,
        float* __restrict__ P, float* __restrict__ AP, float* __restrict__ GR,
        float* __restrict__ crossp, float* __restrict__ normgp){
    __shared__ unsigned short At[64*72];    // A^T: [m up to 64][k 64]
    __shared__ unsigned short Bt[256*72];   // B^T: [col 256][k 64]
    __shared__ float rtr[16], rsq[16];
    int b = blockIdx.x, tid = threadIdx.x;
    int w = tid >> 6, l = tid & 63;
    int lr = l & 15, lg = l >> 4;
    int mt = w & 3, ng = w >> 2;
    f32x4 acc[4];
    f32x4 zv = {0.f, 0.f, 0.f, 0.f};
    #pragma unroll
    for (int q = 0; q < 4; q++) acc[q] = zv;
    int gb = b*NPG;
    int sa_n = tid & 63, sa_c = (tid >> 6)*4;
    int sb_k = tid & 63, sb_g = tid >> 6;
    for (int n0 = 0; n0 < NPG; n0 += 64){
        ushort4 sv = *(const ushort4*)&Sh[(size_t)(gb+n0+sa_n)*64 + sa_c];
        At[(sa_c+0)*72 + sa_n] = sv.x;
        At[(sa_c+1)*72 + sa_n] = sv.y;
        At[(sa_c+2)*72 + sa_n] = sv.z;
        At[(sa_c+3)*72 + sa_n] = sv.w;
        {
            int R = gb + n0 + sb_k;
            const unsigned short* srcp;
            if (sb_g < 8)       srcp = &Zh[(size_t)R*128 + sb_g*16];
            else if (sb_g < 12) srcp = &Th[(size_t)R*64 + (sb_g-8)*16];
            else                srcp = &Sh[(size_t)R*64 + (sb_g-12)*16];
            ushort4 a0 = *(const ushort4*)(srcp);
            ushort4 a1 = *(const ushort4*)(srcp+4);
            ushort4 a2 = *(const ushort4*)(srcp+8);
            ushort4 a3 = *(const ushort4*)(srcp+12);
            int cb = sb_g*16;
            Bt[(cb+ 0)*72+sb_k]=a0.x; Bt[(cb+ 1)*72+sb_k]=a0.y; Bt[(cb+ 2)*72+sb_k]=a0.z; Bt[(cb+ 3)*72+sb_k]=a0.w;
            Bt[(cb+ 4)*72+sb_k]=a1.x; Bt[(cb+ 5)*72+sb_k]=a1.y; Bt[(cb+ 6)*72+sb_k]=a1.z; Bt[(cb+ 7)*72+sb_k]=a1.w;
            Bt[(cb+ 8)*72+sb_k]=a2.x; Bt[(cb+ 9)*72+sb_k]=a2.y; Bt[(cb+10)*72+sb_k]=a2.z; Bt[(cb+11)*72+sb_k]=a2.w;
            Bt[(cb+12)*72+sb_k]=a3.x; Bt[(cb+13)*72+sb_k]=a3.y; Bt[(cb+14)*72+sb_k]=a3.z; Bt[(cb+15)*72+sb_k]=a3.w;
        }
        __syncthreads();
        #pragma unroll
        for (int ks = 0; ks < 2; ks++){
            s16x8 af = *(const s16x8*)&At[(mt*16+lr)*72 + ks*32 + lg*8];
            #pragma unroll
            for (int q = 0; q < 4; q++){
                s16x8 bf = *(const s16x8*)&Bt[((ng*4+q)*16+lr)*72 + ks*32 + lg*8];
                acc[q] = __builtin_amdgcn_mfma_f32_16x16x32_bf16(af, bf, acc[q], 0, 0, 0);
            }
        }
        __syncthreads();
    }
    float tr = 0.f, sq = 0.f;
    #pragma unroll
    for (int q = 0; q < 4; q++){
        int col = (ng*4+q)*16 + lr;
        #pragma unroll
        for (int j = 0; j < 4; j++){
            int m = mt*16 + lg*4 + j;
            float v = acc[q][j];
            if (col < 128){
                P[((size_t)b*64+m)*128 + col] = v;
            } else if (col < 192){
                AP[((size_t)b*64+m)*64 + (col-128)] = v;
                if (col-128 == m) tr += v;
            } else {
                GR[((size_t)b*64+m)*64 + (col-192)] = v;
                sq += v*v;
            }
        }
    }
    for (int o = 32; o; o >>= 1){ tr += __shfl_xor(tr, o); sq += __shfl_xor(sq, o); }
    if (l == 0){ rtr[w] = tr; rsq[w] = sq; }
    __syncthreads();
    if (tid == 0){
        float str = 0.f, ssq = 0.f;
        for (int i = 0; i < 16; i++){ str += rtr[i]; ssq += rsq[i]; }
        atomicAdd(crossp, str);
        atomicAdd(normgp, ssq);
    }
}

// ---------------- head stage A: aggout[b] = (adjp[b] @ pooled[b]) / rowsum ----------------
__global__ void __launch_bounds__(256) k_heada(
        const float* __restrict__ AP, const float* __restrict__ P,
        float* __restrict__ aggout){
    __shared__ float sapT[64*65];
    __shared__ float sp[64*33];
    __shared__ float srs[64];
    int b = blockIdx.x, c0 = blockIdx.y*32;
    int tid = threadIdx.x;
    for (int i = tid; i < 4096; i += 256){
        int k = i >> 6, l = i & 63;
        sapT[l*65 + k] = AP[(size_t)b*4096 + i];
    }
    for (int i = tid; i < 2048; i += 256){
        int l = i >> 5, j = i & 31;
        sp[l*33 + j] = P[(size_t)b*8192 + l*128 + c0 + j];
    }
    __syncthreads();
    if (tid < 64){
        float s = 0.f;
        for (int l = 0; l < 64; l++) s += sapT[l*65 + tid];
        srs[tid] = fmaxf(s, 1.f);
    }
    __syncthreads();
    int k = tid & 63, jg = (tid >> 6)*8;
    float acc[8] = {};
    for (int l = 0; l < 64; l++){
        float a = sapT[l*65 + k];
        #pragma unroll
        for (int j = 0; j < 8; j++) acc[j] += a*sp[l*33 + jg + j];
    }
    float inv = 1.f/srs[k];
    #pragma unroll
    for (int j = 0; j < 8; j++)
        aggout[(size_t)b*8192 + k*128 + c0 + jg + j] = acc[j]*inv;
}

// ---------------- head stage C: hcacc[b,:] += h[b, chunk] @ Wc1[chunk, :] ----------------
__global__ void __launch_bounds__(256) k_head2(
        const float* __restrict__ hbuf, const float* __restrict__ Wc1,
        float* __restrict__ hcacc){
    __shared__ float sh[512];
    __shared__ float sred[256];
    int b = blockIdx.x >> 4, ch = blockIdx.x & 15;
    int tid = threadIdx.x;
    for (int i = tid; i < 512; i += 256) sh[i] = hbuf[(size_t)b*8192 + ch*512 + i];
    __syncthreads();
    int j = tid & 127, half = tid >> 7;
    float acc = 0.f;
    const float* W = Wc1 + (size_t)(ch*512 + half*256)*128;
    const float* hh = sh + half*256;
    for (int r = 0; r < 256; r++) acc += hh[r]*W[(size_t)r*128 + j];
    sred[tid] = acc; __syncthreads();
    if (tid < 128) atomicAdd(&hcacc[(size_t)b*128 + tid], sred[tid] + sred[tid+128]);
}

// ---------------- head stage D: logits ----------------
__global__ void k_head3(const float* __restrict__ hcacc, const float* __restrict__ bc1,
                        const float* __restrict__ Wc2, const float* __restrict__ bc2,
                        float* __restrict__ out){
    int b = blockIdx.x, t = threadIdx.x;   // 128 threads
    float hc = lky(hcacc[(size_t)b*128 + t] + bc1[t]);
    float p = hc*Wc2[t];
    for (int o = 32; o; o >>= 1) p += __shfl_xor(p, o);
    __shared__ float r2[2];
    if ((t & 63) == 0) r2[t >> 6] = p;
    __syncthreads();
    if (t == 0) out[b] = r2[0] + r2[1] + bc2[0];
}

__global__ void k_finalize(const unsigned int* __restrict__ a2,
                           const float* __restrict__ cross,
                           const float* __restrict__ normg,
                           const float* __restrict__ ent,
                           float* __restrict__ out){
    float ss = (float)(*a2) - 2.f*(*cross) + (*normg);
    if (ss < 0.f) ss = 0.f;
    float link = sqrtf(ss) / 67108864.f;     // a.size
    out[64] = link + (*ent)/(float)NT;
}

extern "C" void kernel_launch(void* const* d_in, const int* in_sizes, int n_in,
                              void* d_out, int out_size, void* d_ws, size_t ws_size,
                              hipStream_t stream){
    const float* x    = (const float*)d_in[0];
    const int*   ei   = (const int*)d_in[1];
    const int*   src  = ei;
    const int*   dst  = ei + ETOT;
    const float* W1l  = (const float*)d_in[5];
    const float* b1l  = (const float*)d_in[6];
    const float* W1r  = (const float*)d_in[7];
    const float* W2l  = (const float*)d_in[8];
    const float* b2l  = (const float*)d_in[9];
    const float* W2r  = (const float*)d_in[10];
    const float* Wm   = (const float*)d_in[11];
    const float* bm   = (const float*)d_in[12];
    const float* Wrel = (const float*)d_in[13];
    const float* Wroot= (const float*)d_in[14];
    const float* broot= (const float*)d_in[15];
    const float* Wc1  = (const float*)d_in[16];
    const float* bc1  = (const float*)d_in[17];
    const float* Wc2  = (const float*)d_in[18];
    const float* bc2  = (const float*)d_in[19];
    float* out = (float*)d_out;

    char* w = (char*)d_ws;
    size_t off = 0;
    auto take = [&](size_t bytes)->void*{
        void* p = w + off; off = (off + bytes + 255) & ~(size_t)255; return p;
    };
    const size_t MB = 1024*1024;
    // --- small zeroed zone ---
    float* hcacc  = (float*)take((size_t)BATCH*128*4);
    float* accb   = (float*)take(64);
    size_t zero_small = off;
    // --- non-zeroed ---
    unsigned short* wt = (unsigned short*)take((size_t)49152*2);
    float* pooled = (float*)take((size_t)BATCH*64*128*4);
    float* adjp   = (float*)take((size_t)BATCH*64*64*4);
    float* gram   = (float*)take((size_t)BATCH*64*64*4);
    int*   ipd   = (int*)take((size_t)(NT+1)*4);
    int*   ips   = (int*)take((size_t)(NT+1)*4);
    unsigned short* lst_d = (unsigned short*)take((size_t)ETOT*2);
    unsigned short* lst_s = (unsigned short*)take((size_t)ETOT*2);
    char*  regA  = (char*)take(16*MB);   // agg2h (bf16, 8 MB)
    char*  regB  = (char*)take(16*MB);   // y1h (16 MB) -> th (8 MB)
    char*  regC  = (char*)take(16*MB);   // r1h (16 MB) -> [y2h 8MB | s2h 8MB]
    char*  regD  = (char*)take(16*MB);   // r2h (8 MB)
    char*  regE  = (char*)take(16*MB);   // xh (16 MB) -> zh (16 MB)
    float* hbuf  = (float*)take((size_t)BATCH*8192*4);
    float* aggo  = (float*)take((size_t)BATCH*8192*4);

    unsigned short* y1h   = (unsigned short*)regB;
    unsigned short* th    = (unsigned short*)regB;
    unsigned short* r1h   = (unsigned short*)regC;
    unsigned short* y2h   = (unsigned short*)regC;
    unsigned short* s2h   = (unsigned short*)(regC + 8*MB);
    unsigned short* r2h   = (unsigned short*)regD;
    unsigned short* xh    = (unsigned short*)regE;
    unsigned short* zh    = (unsigned short*)regE;   // overwrites xh (dead after layer-1 GEMM)
    unsigned short* agg2h = (unsigned short*)regA;

    float* crossp = accb + 0;
    float* normgp = accb + 1;
    float* entp   = accb + 2;
    unsigned int* a2p = (unsigned int*)(accb + 3);

    hipMemsetAsync(d_ws, 0, zero_small, stream);

    // weight transpose+cast (one-time, ~98 KB) + x -> bf16
    k_wprep<<<192, 256, 0, stream>>>(W1l, W1r, W2l, W2r, wt);
    k_castx<<<NT*128/4/256, 256, 0, stream>>>(x, xh, NT*128/4);

    // sum(a^2) via LDS nibble hist
    k_a2lds<<<dim3(BATCH, 4), 1024, 0, stream>>>(src, dst, a2p);

    // atomic-free CSR build (per-graph LDS count/scan/scatter, u16 lists)
    k_csr<<<dim3(BATCH, 2), 1024, 0, stream>>>(src, dst, ipd, ips, lst_d, lst_s);

    // SAGE layer 1 (GEMM-before-gather, MFMA): y1 = x@W1l, r1 = x@W1r (bf16)
    k_mfma2b<128><<<NT/128, 512, 0, stream>>>(xh, wt, wt + 16384, y1h, r1h);
    // LDS-staged gather + fused fin1: zh = lky(mean_agg(y1) + r1 + b1l), bf16
    k_aggl<2,128><<<256, 1024, 0, stream>>>(y1h, ipd, lst_d, r1h, b1l, zh);

    // SAGE layer 2 (MFMA): y2 = z@W2l (bf16), r2 = z@W2r (bf16)
    k_mfma2b<64><<<NT/128, 512, 0, stream>>>(zh, wt + 32768, wt + 40960, y2h, r2h);
    k_aggl<1,64><<<256, 1024, 0, stream>>>(y2h, ipd, lst_d, nullptr, nullptr, agg2h);
    // fused: spre = lky(agg2+r2+b2l); s = softmax(spre@Wm+bm) -> s2h bf16; ent
    k_gemm_wm<<<NT/64, 256, 0, stream>>>(agg2h, r2h, b2l, Wm, bm, s2h, entp);

    // t = A @ s (bf16 out)
    k_aggl<0,64><<<256, 1024, 0, stream>>>(s2h, ips, lst_s, nullptr, nullptr, th);

    // fused MFMA: pooled/adjp/gram + trace(cross) + ||gram||^2(normg)
    k_spmm<<<BATCH, 1024, 0, stream>>>(s2h, zh, th, pooled, adjp, gram, crossp, normgp);

    // head: A (agg), B (dual GEMM fp32), C (split-K), D (logits)
    k_heada<<<dim3(BATCH, 4), 256, 0, stream>>>(adjp, pooled, aggo);
    k_gemm<<<dim3(BATCH*64/64, 2), 256, 0, stream>>>(aggo, pooled, Wrel, Wroot, broot, hbuf, BATCH*64, 128, 128, 1, 1, 0);
    k_head2<<<BATCH*16, 256, 0, stream>>>(hbuf, Wc1, hcacc);
    k_head3<<<BATCH, 128, 0, stream>>>(hcacc, bc1, Wc2, bc2, out);
    k_finalize<<<1, 1, 0, stream>>>(a2p, crossp, normgp, entp, out);
}